// Round 1
// baseline (6519.929 us; speedup 1.0000x reference)
//
#include <hip/hip_runtime.h>

#define NN 10000
#define NE 64000
#define INV_SQM 0.17677669529663687f   // 1/sqrt(32)
#define INV_MUL 0.03125f               // 1/32

// ---------- Clebsch-Gordan sparse tables ----------
// PATHS_FULL = [(0,0,0),(0,1,1),(0,2,2),(1,0,1),(1,1,0),(1,1,2),(1,2,1),
//               (2,0,2),(2,1,1),(2,2,0),(2,2,2)]
// nnz entries per path, sorted by output index k (PKo gives per-k offsets).
__constant__ int P_IP[11] = {0,0,0,1,1,1,1,2,2,2,2};
__constant__ int P_JP[11] = {0,1,2,0,1,1,2,0,1,2,2};
__constant__ int P_KP[11] = {0,1,2,1,0,2,1,2,1,0,2};
__constant__ int PKo[11][6] = {
  {0,1,1,1,1,1},{1,2,3,4,4,4},{4,5,6,7,8,9},{9,10,11,12,12,12},
  {12,15,15,15,15,15},{15,17,19,22,24,26},{26,30,34,37,37,37},
  {37,38,39,40,41,42},{42,46,50,53,53,53},{53,58,58,58,58,58},
  {58,62,68,73,79,83}};
__constant__ int DLT[3]  = {1,3,5};
__constant__ int OFFT[3] = {0,32,128};
__constant__ unsigned char NZ_I[83] = {
  0,
  0,0,0,
  0,0,0,0,0,
  0,1,2,
  0,1,2,
  0,1,1,2,0,1,2,0,2,0,1,
  1,0,2,0,0,2,1,1,1,2,0,
  0,1,2,3,4,
  0,2,3,4,0,1,2,4,1,2,3,
  0,1,2,3,4,
  0,2,1,3,0,3,1,2,1,4,0,1,2,3,4,0,1,2,3,3,4,1,2,4,3};
__constant__ unsigned char NZ_J[83] = {
  0,
  0,1,2,
  0,1,2,3,4,
  0,0,0,
  0,1,2,
  1,0,2,1,0,1,2,2,0,0,1,
  0,2,3,4,0,1,2,4,1,2,3,
  0,0,0,0,0,
  1,0,2,0,0,2,1,1,1,2,0,
  0,1,2,3,4,
  2,0,3,1,3,0,2,1,4,1,0,1,2,3,4,1,0,3,2,4,3,1,4,2,3};
__constant__ float NZ_V[83] = {
  1.0f,
  0.57735027f,0.57735027f,0.57735027f,
  0.44721360f,0.44721360f,0.44721360f,0.44721360f,0.44721360f,
  0.57735027f,0.57735027f,0.57735027f,
  0.57735027f,0.57735027f,0.57735027f,
  0.31622777f,0.31622777f,0.31622777f,0.31622777f,-0.18257419f,-0.18257419f,
  0.36514837f,0.31622777f,0.31622777f,0.31622777f,-0.31622777f,
  0.31622777f,-0.18257419f,0.31622777f,0.31622777f,0.31622777f,0.31622777f,
  -0.18257419f,-0.31622777f,0.31622777f,0.36514837f,0.31622777f,
  0.44721360f,0.44721360f,0.44721360f,0.44721360f,0.44721360f,
  0.31622777f,-0.18257419f,0.31622777f,0.31622777f,0.31622777f,0.31622777f,
  -0.18257419f,-0.31622777f,0.31622777f,0.36514837f,0.31622777f,
  0.44721360f,0.44721360f,0.44721360f,0.44721360f,0.44721360f,
  -0.23904572f,-0.23904572f,0.20702483f,0.20702483f,
  0.20702483f,0.20702483f,0.11952286f,0.11952286f,-0.20702483f,-0.20702483f,
  -0.23904572f,0.11952286f,0.23904572f,0.11952286f,-0.23904572f,
  0.20702483f,0.20702483f,0.11952286f,0.11952286f,0.20702483f,0.20702483f,
  -0.20702483f,-0.23904572f,-0.23904572f,0.20702483f};
__constant__ int PL_O2[3]  = {1,2,6};       // O2_UVW paths within PATHS_FULL
__constant__ int PL_UVU[5] = {0,4,5,9,10};  // O2_UVU paths within PATHS_FULL

// ---------- h = nf@emb_w/SQM ; selfc = nf@self_w/SQM ----------
__global__ __launch_bounds__(256) void k_embed(const float* __restrict__ nf,
    const float* __restrict__ emb_w, const float* __restrict__ self_w,
    float* __restrict__ h, float* __restrict__ selfc)
{
  __shared__ float We[1024], Wsf[1024];
  int tid = threadIdx.x;
  for (int i = tid; i < 1024; i += 256) { We[i] = emb_w[i]; Wsf[i] = self_w[i]; }
  __syncthreads();
  int z = blockIdx.x * 8 + (tid >> 5);
  int u = tid & 31;
  if (z >= NN) return;
  const float* row = nf + z * 32;
  float ah = 0.f, as = 0.f;
  #pragma unroll 8
  for (int v = 0; v < 32; ++v) {
    float xv = row[v];
    ah += xv * We[(v << 5) + u];
    as += xv * Wsf[(v << 5) + u];
  }
  h[(z << 5) + u]     = ah * INV_SQM;
  selfc[(z << 5) + u] = as * INV_SQM;
}

// ---------- per-edge radial MLP -> rf[64] ----------
__global__ __launch_bounds__(256) void k_radial(
    const float* __restrict__ re, const float* __restrict__ ea,
    const float* __restrict__ w1, const float* __restrict__ b1,
    const float* __restrict__ w2, const float* __restrict__ b2,
    const float* __restrict__ w3, const float* __restrict__ b3,
    float* __restrict__ rf)
{
  __shared__ float W1[24 * 64];
  __shared__ float W2[64 * 64];
  __shared__ float W3[64 * 64];
  __shared__ float rin[4][24];
  __shared__ float t1[4][65], t2[4][65];
  int t = threadIdx.x;
  for (int i = t; i < 24 * 64; i += 256) W1[i] = w1[i];
  for (int i = t; i < 4096; i += 256) { W2[i] = w2[i]; W3[i] = w3[i]; }
  int e0 = blockIdx.x * 4;
  if (t < 96) {
    int el = t / 24, i = t - el * 24;
    int e = e0 + el;
    rin[el][i] = (i < 8) ? re[e * 8 + i] : ea[e * 16 + (i - 8)];
  }
  __syncthreads();
  int el = t >> 6, o = t & 63;
  int e = e0 + el;
  float acc = b1[o];
  #pragma unroll 8
  for (int i = 0; i < 24; ++i) acc += rin[el][i] * W1[i * 64 + o];
  acc = acc / (1.f + __expf(-acc));
  t1[el][o] = acc;
  __syncthreads();
  acc = b2[o];
  #pragma unroll 8
  for (int c = 0; c < 64; ++c) acc += t1[el][c] * W2[(c << 6) + o];
  acc = acc / (1.f + __expf(-acc));
  t2[el][o] = acc;
  __syncthreads();
  acc = b3[o];
  #pragma unroll 8
  for (int c = 0; c < 64; ++c) acc += t2[el][c] * W3[(c << 6) + o];
  rf[e * 64 + o] = acc;
}

// ---------- edge kernel: tpw = rf@a_w + a_b (fused), mixed = h_src . tpw,
//            messages scattered to a[dst] via atomics; cnt counts. ----------
// 64 edges/block; thread = (w = tid&31, eg = tid>>5 -> 8 edges).
__global__ __launch_bounds__(256) void k_edge(
    const float* __restrict__ rf, const float* __restrict__ h,
    const int* __restrict__ ei, const float* __restrict__ sh,
    const float* __restrict__ a_w, const float* __restrict__ a_b,
    float* __restrict__ aout, float* __restrict__ cnt)
{
  __shared__ __align__(16) float rf_t[64 * 72];   // [c][e], stride 72
  __shared__ __align__(16) float aw_s[64 * 128];  // [c][w][q]
  __shared__ __align__(16) float hs[64 * 32];     // [e][u]
  __shared__ float sh_s[64 * 9];
  __shared__ float ab_s[128];
  __shared__ int dst_s[64];

  int tid = threadIdx.x;
  int e0 = blockIdx.x * 64;
  for (int idx = tid; idx < 64 * 64; idx += 256) {
    int e = idx >> 6, c = idx & 63;
    rf_t[c * 72 + e] = rf[(e0 + e) * 64 + c];
  }
  for (int idx = tid; idx < 64 * 32; idx += 256) {
    int e = idx >> 5, u = idx & 31;
    hs[(e << 5) + u] = h[ei[e0 + e] * 32 + u];
  }
  if (tid < 64) dst_s[tid] = ei[NE + e0 + tid];
  for (int idx = tid; idx < 64 * 9; idx += 256) {
    int e = idx / 9, i = idx - e * 9;
    sh_s[idx] = sh[(e0 + e) * 9 + i];
  }

  int w = tid & 31, eg = tid >> 5;
  int ebase = eg * 8;
  float macc[8][3];
  #pragma unroll
  for (int e = 0; e < 8; ++e)
    #pragma unroll
    for (int l = 0; l < 3; ++l) macc[e][l] = 0.f;

  #pragma unroll
  for (int l = 0; l < 3; ++l) {
    for (int ch8 = 0; ch8 < 8; ++ch8) {
      int cb = (l * 8 + ch8) * 128;
      __syncthreads();
      for (int idx = tid; idx < 8192; idx += 256) {
        int c = idx >> 7, cl = idx & 127;
        aw_s[(c << 7) + ((cl & 31) << 2) + (cl >> 5)] = a_w[c * 3072 + cb + cl];
      }
      if (tid < 128) ab_s[tid] = a_b[cb + tid];
      __syncthreads();
      float C[8][4];
      #pragma unroll
      for (int e = 0; e < 8; ++e)
        #pragma unroll
        for (int q = 0; q < 4; ++q) C[e][q] = 0.f;
      for (int c = 0; c < 64; ++c) {
        const float4 a4 = *(const float4*)&aw_s[(c << 7) + (w << 2)];
        const float4 r0 = *(const float4*)&rf_t[c * 72 + ebase];
        const float4 r1 = *(const float4*)&rf_t[c * 72 + ebase + 4];
        float ar[8] = {r0.x, r0.y, r0.z, r0.w, r1.x, r1.y, r1.z, r1.w};
        float aq[4] = {a4.x, a4.y, a4.z, a4.w};
        #pragma unroll
        for (int e = 0; e < 8; ++e)
          #pragma unroll
          for (int q = 0; q < 4; ++q) C[e][q] += ar[e] * aq[q];
      }
      #pragma unroll
      for (int q = 0; q < 4; ++q) {
        float bq = ab_s[(q << 5) + w];
        #pragma unroll
        for (int e = 0; e < 8; ++e) {
          float hv = hs[((ebase + e) << 5) + ch8 * 4 + q];
          macc[e][l] += hv * (C[e][q] + bq);
        }
      }
    }
  }

  if (tid < 64) atomicAdd(&cnt[dst_s[tid]], 1.0f);
  #pragma unroll
  for (int e = 0; e < 8; ++e) {
    int eG = ebase + e;
    float* arow = aout + dst_s[eG] * 288;
    float m0 = macc[e][0] * INV_SQM;
    float m1 = macc[e][1] * INV_SQM;
    float m2 = macc[e][2] * INV_SQM;
    atomicAdd(&arow[w], m0 * sh_s[eG * 9 + 0]);
    #pragma unroll
    for (int i = 0; i < 3; ++i)
      atomicAdd(&arow[32 + w * 3 + i], m1 * sh_s[eG * 9 + 1 + i] * 0.57735027f);
    #pragma unroll
    for (int i = 0; i < 5; ++i)
      atomicAdd(&arow[128 + w * 5 + i], m2 * sh_s[eG * 9 + 4 + i] * 0.44721360f);
  }
}

// ---------- a /= max(cnt,1) ----------
__global__ __launch_bounds__(256) void k_div(float* __restrict__ a, const float* __restrict__ cnt)
{
  int z = blockIdx.x;
  float inv = 1.0f / fmaxf(cnt[z], 1.0f);
  for (int c = threadIdx.x; c < 288; c += 256) a[z * 288 + c] *= inv;
}

// ---------- generic uvw pairwise TP: out[z] = scale * sum_paths einsum ----------
// 16 nodes/block; thread = (wg=tid&7 -> 4 w's, zA=(tid>>3)&15, dup=tid>>7 splits v).
__global__ __launch_bounds__(256) void k_pairwise(
    const float* __restrict__ x, const float* __restrict__ y,
    const float* __restrict__ W, float* __restrict__ out,
    int npaths, int use_o2, float scale)
{
  __shared__ __align__(16) float x_t[16 * 288];
  __shared__ __align__(16) float y_t[16 * 288];
  __shared__ __align__(16) float W_u[1024];       // [v][w]
  __shared__ __align__(16) float T_u[16 * 32 * 8]; // [z][v][k pad 8]

  int tid = threadIdx.x;
  int z0 = blockIdx.x * 16;
  for (int idx = tid; idx < 16 * 72; idx += 256) {
    int r = idx / 72, f = idx - r * 72;
    *(float4*)&x_t[r * 288 + f * 4] = *(const float4*)&x[(z0 + r) * 288 + f * 4];
    *(float4*)&y_t[r * 288 + f * 4] = *(const float4*)&y[(z0 + r) * 288 + f * 4];
  }
  int wg = tid & 7;
  int zA = (tid >> 3) & 15;
  int dup = tid >> 7;
  int vT = tid & 31, zqT = tid >> 5;

  float acc[4][9];
  #pragma unroll
  for (int q = 0; q < 4; ++q)
    #pragma unroll
    for (int s = 0; s < 9; ++s) acc[q][s] = 0.f;

  for (int p = 0; p < npaths; ++p) {
    int pi = use_o2 ? PL_O2[p] : p;
    const float* Wb = W + p * 32768;
    int ip = P_IP[pi], jp = P_JP[pi], kp = P_KP[pi];
    int di = DLT[ip], dj = DLT[jp];
    int xb0 = OFFT[ip], yb0 = OFFT[jp];
    for (int u = 0; u < 32; ++u) {
      __syncthreads();
      *(float4*)&W_u[tid << 2] = *(const float4*)&Wb[(u << 10) + (tid << 2)];
      #pragma unroll
      for (int zz = 0; zz < 2; ++zz) {
        int z = zqT + (zz << 3);
        const float* xr = &x_t[z * 288 + xb0 + u * di];
        const float* yr = &y_t[z * 288 + yb0 + vT * dj];
        float* Tp = &T_u[((z << 5) + vT) << 3];
        if (kp == 0) {
          float t0 = 0.f;
          for (int n = PKo[pi][0]; n < PKo[pi][1]; ++n) t0 += xr[NZ_I[n]] * yr[NZ_J[n]] * NZ_V[n];
          Tp[0] = t0;
        } else if (kp == 1) {
          float t0 = 0.f, t1 = 0.f, t2 = 0.f;
          for (int n = PKo[pi][0]; n < PKo[pi][1]; ++n) t0 += xr[NZ_I[n]] * yr[NZ_J[n]] * NZ_V[n];
          for (int n = PKo[pi][1]; n < PKo[pi][2]; ++n) t1 += xr[NZ_I[n]] * yr[NZ_J[n]] * NZ_V[n];
          for (int n = PKo[pi][2]; n < PKo[pi][3]; ++n) t2 += xr[NZ_I[n]] * yr[NZ_J[n]] * NZ_V[n];
          Tp[0] = t0; Tp[1] = t1; Tp[2] = t2;
        } else {
          float t0 = 0.f, t1 = 0.f, t2 = 0.f, t3 = 0.f, t4 = 0.f;
          for (int n = PKo[pi][0]; n < PKo[pi][1]; ++n) t0 += xr[NZ_I[n]] * yr[NZ_J[n]] * NZ_V[n];
          for (int n = PKo[pi][1]; n < PKo[pi][2]; ++n) t1 += xr[NZ_I[n]] * yr[NZ_J[n]] * NZ_V[n];
          for (int n = PKo[pi][2]; n < PKo[pi][3]; ++n) t2 += xr[NZ_I[n]] * yr[NZ_J[n]] * NZ_V[n];
          for (int n = PKo[pi][3]; n < PKo[pi][4]; ++n) t3 += xr[NZ_I[n]] * yr[NZ_J[n]] * NZ_V[n];
          for (int n = PKo[pi][4]; n < PKo[pi][5]; ++n) t4 += xr[NZ_I[n]] * yr[NZ_J[n]] * NZ_V[n];
          Tp[0] = t0; Tp[1] = t1; Tp[2] = t2; Tp[3] = t3; Tp[4] = t4;
        }
      }
      __syncthreads();
      int vb = dup << 4;
      if (kp == 0) {
        for (int vi = 0; vi < 16; ++vi) {
          int v = vb + vi;
          const float4 wv = *(const float4*)&W_u[(v << 5) + (wg << 2)];
          const float t0 = T_u[((zA << 5) + v) << 3];
          acc[0][0] += wv.x * t0; acc[1][0] += wv.y * t0;
          acc[2][0] += wv.z * t0; acc[3][0] += wv.w * t0;
        }
      } else if (kp == 1) {
        for (int vi = 0; vi < 16; ++vi) {
          int v = vb + vi;
          const float4 wv = *(const float4*)&W_u[(v << 5) + (wg << 2)];
          const float4 t = *(const float4*)&T_u[((zA << 5) + v) << 3];
          float wq[4] = {wv.x, wv.y, wv.z, wv.w};
          #pragma unroll
          for (int q = 0; q < 4; ++q) {
            acc[q][1] += wq[q] * t.x; acc[q][2] += wq[q] * t.y; acc[q][3] += wq[q] * t.z;
          }
        }
      } else {
        for (int vi = 0; vi < 16; ++vi) {
          int v = vb + vi;
          const float4 wv = *(const float4*)&W_u[(v << 5) + (wg << 2)];
          const float4 t = *(const float4*)&T_u[((zA << 5) + v) << 3];
          const float tb = T_u[(((zA << 5) + v) << 3) + 4];
          float wq[4] = {wv.x, wv.y, wv.z, wv.w};
          #pragma unroll
          for (int q = 0; q < 4; ++q) {
            acc[q][4] += wq[q] * t.x; acc[q][5] += wq[q] * t.y; acc[q][6] += wq[q] * t.z;
            acc[q][7] += wq[q] * t.w; acc[q][8] += wq[q] * tb;
          }
        }
      }
    }
  }
  // merge dup halves through x_t (16*288 == 16*32*9 floats, exactly fits)
  __syncthreads();
  if (dup) {
    #pragma unroll
    for (int q = 0; q < 4; ++q)
      #pragma unroll
      for (int s = 0; s < 9; ++s)
        x_t[((zA << 5) + (wg << 2) + q) * 9 + s] = acc[q][s];
  }
  __syncthreads();
  if (!dup) {
    #pragma unroll
    for (int q = 0; q < 4; ++q)
      #pragma unroll
      for (int s = 0; s < 9; ++s)
        acc[q][s] += x_t[((zA << 5) + (wg << 2) + q) * 9 + s];
    float* orow = out + (z0 + zA) * 288;
    #pragma unroll
    for (int q = 0; q < 4; ++q) {
      int w = (wg << 2) + q;
      orow[w] = scale * acc[q][0];
      #pragma unroll
      for (int kk = 0; kk < 3; ++kk) orow[32 + w * 3 + kk] = scale * acc[q][1 + kk];
      #pragma unroll
      for (int kk = 0; kk < 5; ++kk) orow[128 + w * 5 + kk] = scale * acc[q][4 + kk];
    }
  }
}

// ---------- uvu part of order2: out += (1/SQM) einsum('zui,zvj,ijk,uv->zuk') ----------
__global__ __launch_bounds__(256) void k_uvu(
    const float* __restrict__ x, const float* __restrict__ W, float* __restrict__ out)
{
  __shared__ __align__(16) float x_t[16 * 288];
  __shared__ float Wt[1024]; // [v][u]
  int tid = threadIdx.x;
  int z0 = blockIdx.x * 16;
  for (int idx = tid; idx < 16 * 72; idx += 256) {
    int r = idx / 72, f = idx - r * 72;
    *(float4*)&x_t[r * 288 + f * 4] = *(const float4*)&x[(z0 + r) * 288 + f * 4];
  }
  int u = tid & 31, zq = tid >> 5;
  float acc0[2] = {0.f, 0.f};
  float acc2[2][5];
  #pragma unroll
  for (int zz = 0; zz < 2; ++zz)
    #pragma unroll
    for (int k = 0; k < 5; ++k) acc2[zz][k] = 0.f;

  for (int p = 0; p < 5; ++p) {
    int pi = PL_UVU[p];
    const float* Wp = W + p * 1024;
    int ip = P_IP[pi], jp = P_JP[pi], kp = P_KP[pi];
    int di = DLT[ip], dj = DLT[jp];
    int xb = OFFT[ip], yb = OFFT[jp];
    __syncthreads();
    for (int idx = tid; idx < 1024; idx += 256)
      Wt[((idx & 31) << 5) + (idx >> 5)] = Wp[idx];
    __syncthreads();
    #pragma unroll
    for (int zz = 0; zz < 2; ++zz) {
      int z = zq + (zz << 3);
      const float* xr = &x_t[z * 288 + xb + u * di];
      const float* yrb = &x_t[z * 288 + yb];
      for (int v = 0; v < 32; ++v) {
        float wv = Wt[(v << 5) + u];
        const float* yr = yrb + v * dj;
        if (kp == 0) {
          float t = 0.f;
          for (int n = PKo[pi][0]; n < PKo[pi][1]; ++n) t += xr[NZ_I[n]] * yr[NZ_J[n]] * NZ_V[n];
          acc0[zz] += wv * t;
        } else {
          float t;
          t = 0.f; for (int n = PKo[pi][0]; n < PKo[pi][1]; ++n) t += xr[NZ_I[n]] * yr[NZ_J[n]] * NZ_V[n];
          acc2[zz][0] += wv * t;
          t = 0.f; for (int n = PKo[pi][1]; n < PKo[pi][2]; ++n) t += xr[NZ_I[n]] * yr[NZ_J[n]] * NZ_V[n];
          acc2[zz][1] += wv * t;
          t = 0.f; for (int n = PKo[pi][2]; n < PKo[pi][3]; ++n) t += xr[NZ_I[n]] * yr[NZ_J[n]] * NZ_V[n];
          acc2[zz][2] += wv * t;
          t = 0.f; for (int n = PKo[pi][3]; n < PKo[pi][4]; ++n) t += xr[NZ_I[n]] * yr[NZ_J[n]] * NZ_V[n];
          acc2[zz][3] += wv * t;
          t = 0.f; for (int n = PKo[pi][4]; n < PKo[pi][5]; ++n) t += xr[NZ_I[n]] * yr[NZ_J[n]] * NZ_V[n];
          acc2[zz][4] += wv * t;
        }
      }
    }
  }
  #pragma unroll
  for (int zz = 0; zz < 2; ++zz) {
    int zg = z0 + zq + (zz << 3);
    float* orow = out + zg * 288;
    orow[u] += INV_SQM * acc0[zz];
    #pragma unroll
    for (int kk = 0; kk < 5; ++kk) orow[128 + u * 5 + kk] += INV_SQM * acc2[zz][kk];
  }
}

// ---------- final lin chains + self connection ----------
__device__ __forceinline__ void lin_row(float* dst, const float* src, const float* Wm, int w)
{
  {
    float s = 0.f;
    for (int u = 0; u < 32; ++u) s += src[u] * Wm[(u << 5) + w];
    dst[w] = s * INV_SQM;
  }
  #pragma unroll
  for (int i = 0; i < 3; ++i) {
    float s = 0.f;
    for (int u = 0; u < 32; ++u) s += src[32 + u * 3 + i] * Wm[1024 + (u << 5) + w];
    dst[32 + w * 3 + i] = s * INV_SQM;
  }
  #pragma unroll
  for (int i = 0; i < 5; ++i) {
    float s = 0.f;
    for (int u = 0; u < 32; ++u) s += src[128 + u * 5 + i] * Wm[2048 + (u << 5) + w];
    dst[128 + w * 5 + i] = s * INV_SQM;
  }
}

__device__ __forceinline__ void lin_acc(float* msg, const float* src, const float* Wm, int w)
{
  {
    float s = 0.f;
    for (int u = 0; u < 32; ++u) s += src[u] * Wm[(u << 5) + w];
    msg[0] += s * INV_SQM;
  }
  #pragma unroll
  for (int i = 0; i < 3; ++i) {
    float s = 0.f;
    for (int u = 0; u < 32; ++u) s += src[32 + u * 3 + i] * Wm[1024 + (u << 5) + w];
    msg[1 + i] += s * INV_SQM;
  }
  #pragma unroll
  for (int i = 0; i < 5; ++i) {
    float s = 0.f;
    for (int u = 0; u < 32; ++u) s += src[128 + u * 5 + i] * Wm[2048 + (u << 5) + w];
    msg[4 + i] += s * INV_SQM;
  }
}

__global__ __launch_bounds__(256) void k_finalize(
    const float* __restrict__ a, const float* __restrict__ b2, const float* __restrict__ b3,
    const float* __restrict__ selfc, const float* __restrict__ lin_o1,
    const float* __restrict__ mix_w, const float* __restrict__ comb_w,
    float* __restrict__ out)
{
  __shared__ float bufA[8 * 288];
  __shared__ float bufB[8 * 288];
  int tid = threadIdx.x;
  int w = tid & 31, zl = tid >> 5;
  int z = blockIdx.x * 8 + zl;
  float msg[9];
  #pragma unroll
  for (int s = 0; s < 9; ++s) msg[s] = 0.f;
  float* rowA = &bufA[zl * 288];
  float* rowB = &bufB[zl * 288];
  // order 0: b1 = lin(a, lin_o1); mix; comb
  lin_row(rowA, a + z * 288, lin_o1, w);
  __syncthreads();
  lin_row(rowB, rowA, mix_w, w);
  __syncthreads();
  lin_acc(msg, rowB, comb_w, w);
  __syncthreads();
  // order 1: mix(b2); comb
  lin_row(rowA, b2 + z * 288, mix_w + 3072, w);
  __syncthreads();
  lin_acc(msg, rowA, comb_w + 3072, w);
  __syncthreads();
  // order 2: mix(b3); comb
  lin_row(rowA, b3 + z * 288, mix_w + 6144, w);
  __syncthreads();
  lin_acc(msg, rowA, comb_w + 6144, w);

  float sc = selfc[(z << 5) + w];
  float* orow = out + z * 288;
  orow[w] = msg[0] + sc;
  #pragma unroll
  for (int i = 0; i < 3; ++i) orow[32 + w * 3 + i] = msg[1 + i];
  #pragma unroll
  for (int i = 0; i < 5; ++i) orow[128 + w * 5 + i] = msg[4 + i];
}

extern "C" void kernel_launch(void* const* d_in, const int* in_sizes, int n_in,
                              void* d_out, int out_size, void* d_ws, size_t ws_size,
                              hipStream_t stream)
{
  (void)in_sizes; (void)n_in; (void)out_size; (void)ws_size;
  const float* nf   = (const float*)d_in[0];
  const int*   ei   = (const int*)d_in[1];
  const float* sh   = (const float*)d_in[2];
  const float* re   = (const float*)d_in[3];
  const float* ea   = (const float*)d_in[4];
  const float* rw1  = (const float*)d_in[5];
  const float* rb1  = (const float*)d_in[6];
  const float* rw2  = (const float*)d_in[7];
  const float* rb2  = (const float*)d_in[8];
  const float* rw3  = (const float*)d_in[9];
  const float* rb3  = (const float*)d_in[10];
  const float* aw   = (const float*)d_in[11];
  const float* ab   = (const float*)d_in[12];
  const float* embw = (const float*)d_in[13];
  const float* lino1= (const float*)d_in[14];
  const float* o2uvw= (const float*)d_in[15];
  const float* o2uvu= (const float*)d_in[16];
  const float* o3a  = (const float*)d_in[17];
  const float* o3b  = (const float*)d_in[18];
  const float* mixw = (const float*)d_in[19];
  const float* combw= (const float*)d_in[20];
  const float* selfw= (const float*)d_in[21];
  float* out = (float*)d_out;
  float* ws  = (float*)d_ws;

  // workspace layout (floats)
  float* h     = ws;                // 320000
  float* selfc = ws + 320000;       // 320000
  float* rfb   = ws + 640000;       // 4096000  (rf; reused as b2 afterwards)
  float* a     = ws + 4736000;      // 2880000
  float* cnt   = ws + 7616000;      // 10000
  float* cint  = ws + 7626000;      // 2880000  (b3 computed in-place)
  float* b2 = rfb;
  float* b3 = cint;

  hipMemsetAsync(a, 0, (2880000 + 10000) * sizeof(float), stream);
  k_embed<<<1250, 256, 0, stream>>>(nf, embw, selfw, h, selfc);
  k_radial<<<16000, 256, 0, stream>>>(re, ea, rw1, rb1, rw2, rb2, rw3, rb3, rfb);
  k_edge<<<1000, 256, 0, stream>>>(rfb, h, ei, sh, aw, ab, a, cnt);
  k_div<<<10000, 256, 0, stream>>>(a, cnt);
  k_pairwise<<<625, 256, 0, stream>>>(a, a, o2uvw, b2, 3, 1, INV_MUL);
  k_uvu<<<625, 256, 0, stream>>>(a, o2uvu, b2);
  k_pairwise<<<625, 256, 0, stream>>>(a, a, o3a, cint, 11, 0, INV_MUL);
  k_pairwise<<<625, 256, 0, stream>>>(cint, a, o3b, b3, 11, 0, INV_MUL);
  k_finalize<<<1250, 256, 0, stream>>>(a, b2, b3, selfc, lino1, mixw, combw, out);
}

// Round 3
// 1586.161 us; speedup vs baseline: 4.1105x; 4.1105x over previous
//
#include <hip/hip_runtime.h>

#define NN 10000
#define NE 64000
#define INV_SQM 0.17677669529663687f   // 1/sqrt(32)
#define INV_MUL 0.03125f               // 1/32

typedef __attribute__((ext_vector_type(8))) short bfrag;   // 8 bf16 (4 VGPRs)
typedef __attribute__((ext_vector_type(4))) float ffrag;   // 4 fp32 acc

__device__ __forceinline__ short f2bf(float f) {
  unsigned u = __float_as_uint(f);
  unsigned r = (u + 0x7FFFu + ((u >> 16) & 1u)) >> 16;  // RNE
  return (short)r;
}

// ---------- Clebsch-Gordan sparse tables (runtime copies for k_uvu) ----------
__constant__ int P_IP[11] = {0,0,0,1,1,1,1,2,2,2,2};
__constant__ int P_JP[11] = {0,1,2,0,1,1,2,0,1,2,2};
__constant__ int P_KP[11] = {0,1,2,1,0,2,1,2,1,0,2};
__constant__ int PKo[11][6] = {
  {0,1,1,1,1,1},{1,2,3,4,4,4},{4,5,6,7,8,9},{9,10,11,12,12,12},
  {12,15,15,15,15,15},{15,17,19,22,24,26},{26,30,34,37,37,37},
  {37,38,39,40,41,42},{42,46,50,53,53,53},{53,58,58,58,58,58},
  {58,62,68,73,79,83}};
__constant__ int DLT[3]  = {1,3,5};
__constant__ int OFFT[3] = {0,32,128};
__constant__ unsigned char NZ_I[83] = {
  0,
  0,0,0,
  0,0,0,0,0,
  0,1,2,
  0,1,2,
  0,1,1,2,0,1,2,0,2,0,1,
  1,0,2,0,0,2,1,1,1,2,0,
  0,1,2,3,4,
  0,2,3,4,0,1,2,4,1,2,3,
  0,1,2,3,4,
  0,2,1,3,0,3,1,2,1,4,0,1,2,3,4,0,1,2,3,3,4,1,2,4,3};
__constant__ unsigned char NZ_J[83] = {
  0,
  0,1,2,
  0,1,2,3,4,
  0,0,0,
  0,1,2,
  1,0,2,1,0,1,2,2,0,0,1,
  0,2,3,4,0,1,2,4,1,2,3,
  0,0,0,0,0,
  1,0,2,0,0,2,1,1,1,2,0,
  0,1,2,3,4,
  2,0,3,1,3,0,2,1,4,1,0,1,2,3,4,1,0,3,2,4,3,1,4,2,3};
__constant__ float NZ_V[83] = {
  1.0f,
  0.57735027f,0.57735027f,0.57735027f,
  0.44721360f,0.44721360f,0.44721360f,0.44721360f,0.44721360f,
  0.57735027f,0.57735027f,0.57735027f,
  0.57735027f,0.57735027f,0.57735027f,
  0.31622777f,0.31622777f,0.31622777f,0.31622777f,-0.18257419f,-0.18257419f,
  0.36514837f,0.31622777f,0.31622777f,0.31622777f,-0.31622777f,
  0.31622777f,-0.18257419f,0.31622777f,0.31622777f,0.31622777f,0.31622777f,
  -0.18257419f,-0.31622777f,0.31622777f,0.36514837f,0.31622777f,
  0.44721360f,0.44721360f,0.44721360f,0.44721360f,0.44721360f,
  0.31622777f,-0.18257419f,0.31622777f,0.31622777f,0.31622777f,0.31622777f,
  -0.18257419f,-0.31622777f,0.31622777f,0.36514837f,0.31622777f,
  0.44721360f,0.44721360f,0.44721360f,0.44721360f,0.44721360f,
  -0.23904572f,-0.23904572f,0.20702483f,0.20702483f,
  0.20702483f,0.20702483f,0.11952286f,0.11952286f,-0.20702483f,-0.20702483f,
  -0.23904572f,0.11952286f,0.23904572f,0.11952286f,-0.23904572f,
  0.20702483f,0.20702483f,0.11952286f,0.11952286f,0.20702483f,0.20702483f,
  -0.20702483f,-0.23904572f,-0.23904572f,0.20702483f};
__constant__ int PL_UVU[5] = {0,4,5,9,10};  // O2_UVU paths within PATHS_FULL

// ---------- compile-time copies for the templated MFMA path ----------
constexpr int cIP[11] = {0,0,0,1,1,1,1,2,2,2,2};
constexpr int cJP[11] = {0,1,2,0,1,1,2,0,1,2,2};
constexpr int cKP[11] = {0,1,2,1,0,2,1,2,1,0,2};
constexpr int cKo[11][6] = {
  {0,1,1,1,1,1},{1,2,3,4,4,4},{4,5,6,7,8,9},{9,10,11,12,12,12},
  {12,15,15,15,15,15},{15,17,19,22,24,26},{26,30,34,37,37,37},
  {37,38,39,40,41,42},{42,46,50,53,53,53},{53,58,58,58,58,58},
  {58,62,68,73,79,83}};
constexpr int cDL[3]  = {1,3,5};
constexpr int cOF[3]  = {0,32,128};
constexpr int cNI[83] = {
  0, 0,0,0, 0,0,0,0,0, 0,1,2, 0,1,2,
  0,1,1,2,0,1,2,0,2,0,1,
  1,0,2,0,0,2,1,1,1,2,0,
  0,1,2,3,4,
  0,2,3,4,0,1,2,4,1,2,3,
  0,1,2,3,4,
  0,2,1,3,0,3,1,2,1,4,0,1,2,3,4,0,1,2,3,3,4,1,2,4,3};
constexpr int cNJ[83] = {
  0, 0,1,2, 0,1,2,3,4, 0,0,0, 0,1,2,
  1,0,2,1,0,1,2,2,0,0,1,
  0,2,3,4,0,1,2,4,1,2,3,
  0,0,0,0,0,
  1,0,2,0,0,2,1,1,1,2,0,
  0,1,2,3,4,
  2,0,3,1,3,0,2,1,4,1,0,1,2,3,4,1,0,3,2,4,3,1,4,2,3};
constexpr float cNV[83] = {
  1.0f,
  0.57735027f,0.57735027f,0.57735027f,
  0.44721360f,0.44721360f,0.44721360f,0.44721360f,0.44721360f,
  0.57735027f,0.57735027f,0.57735027f,
  0.57735027f,0.57735027f,0.57735027f,
  0.31622777f,0.31622777f,0.31622777f,0.31622777f,-0.18257419f,-0.18257419f,
  0.36514837f,0.31622777f,0.31622777f,0.31622777f,-0.31622777f,
  0.31622777f,-0.18257419f,0.31622777f,0.31622777f,0.31622777f,0.31622777f,
  -0.18257419f,-0.31622777f,0.31622777f,0.36514837f,0.31622777f,
  0.44721360f,0.44721360f,0.44721360f,0.44721360f,0.44721360f,
  0.31622777f,-0.18257419f,0.31622777f,0.31622777f,0.31622777f,0.31622777f,
  -0.18257419f,-0.31622777f,0.31622777f,0.36514837f,0.31622777f,
  0.44721360f,0.44721360f,0.44721360f,0.44721360f,0.44721360f,
  -0.23904572f,-0.23904572f,0.20702483f,0.20702483f,
  0.20702483f,0.20702483f,0.11952286f,0.11952286f,-0.20702483f,-0.20702483f,
  -0.23904572f,0.11952286f,0.23904572f,0.11952286f,-0.23904572f,
  0.20702483f,0.20702483f,0.11952286f,0.11952286f,0.20702483f,0.20702483f,
  -0.20702483f,-0.23904572f,-0.23904572f,0.20702483f};

// ---------- h = nf@emb_w/SQM ; selfc = nf@self_w/SQM ----------
__global__ __launch_bounds__(256) void k_embed(const float* __restrict__ nf,
    const float* __restrict__ emb_w, const float* __restrict__ self_w,
    float* __restrict__ h, float* __restrict__ selfc)
{
  __shared__ float We[1024], Wsf[1024];
  int tid = threadIdx.x;
  for (int i = tid; i < 1024; i += 256) { We[i] = emb_w[i]; Wsf[i] = self_w[i]; }
  __syncthreads();
  int z = blockIdx.x * 8 + (tid >> 5);
  int u = tid & 31;
  if (z >= NN) return;
  const float* row = nf + z * 32;
  float ah = 0.f, as = 0.f;
  #pragma unroll 8
  for (int v = 0; v < 32; ++v) {
    float xv = row[v];
    ah += xv * We[(v << 5) + u];
    as += xv * Wsf[(v << 5) + u];
  }
  h[(z << 5) + u]     = ah * INV_SQM;
  selfc[(z << 5) + u] = as * INV_SQM;
}

// ---------- per-edge radial MLP -> rf[64] ----------
__global__ __launch_bounds__(256) void k_radial(
    const float* __restrict__ re, const float* __restrict__ ea,
    const float* __restrict__ w1, const float* __restrict__ b1,
    const float* __restrict__ w2, const float* __restrict__ b2,
    const float* __restrict__ w3, const float* __restrict__ b3,
    float* __restrict__ rf)
{
  __shared__ float W1[24 * 64];
  __shared__ float W2[64 * 64];
  __shared__ float W3[64 * 64];
  __shared__ float rin[4][24];
  __shared__ float t1[4][65], t2[4][65];
  int t = threadIdx.x;
  for (int i = t; i < 24 * 64; i += 256) W1[i] = w1[i];
  for (int i = t; i < 4096; i += 256) { W2[i] = w2[i]; W3[i] = w3[i]; }
  int e0 = blockIdx.x * 4;
  if (t < 96) {
    int el = t / 24, i = t - el * 24;
    int e = e0 + el;
    rin[el][i] = (i < 8) ? re[e * 8 + i] : ea[e * 16 + (i - 8)];
  }
  __syncthreads();
  int el = t >> 6, o = t & 63;
  int e = e0 + el;
  float acc = b1[o];
  #pragma unroll 8
  for (int i = 0; i < 24; ++i) acc += rin[el][i] * W1[i * 64 + o];
  acc = acc / (1.f + __expf(-acc));
  t1[el][o] = acc;
  __syncthreads();
  acc = b2[o];
  #pragma unroll 8
  for (int c = 0; c < 64; ++c) acc += t1[el][c] * W2[(c << 6) + o];
  acc = acc / (1.f + __expf(-acc));
  t2[el][o] = acc;
  __syncthreads();
  acc = b3[o];
  #pragma unroll 8
  for (int c = 0; c < 64; ++c) acc += t2[el][c] * W3[(c << 6) + o];
  rf[e * 64 + o] = acc;
}

// ---------- edge kernel ----------
__global__ __launch_bounds__(256) void k_edge(
    const float* __restrict__ rf, const float* __restrict__ h,
    const int* __restrict__ ei, const float* __restrict__ sh,
    const float* __restrict__ a_w, const float* __restrict__ a_b,
    float* __restrict__ aout, float* __restrict__ cnt)
{
  __shared__ __align__(16) float rf_t[64 * 72];   // [c][e], stride 72
  __shared__ __align__(16) float aw_s[64 * 128];  // [c][w][q]
  __shared__ __align__(16) float hs[64 * 32];     // [e][u]
  __shared__ float sh_s[64 * 9];
  __shared__ float ab_s[128];
  __shared__ int dst_s[64];

  int tid = threadIdx.x;
  int e0 = blockIdx.x * 64;
  for (int idx = tid; idx < 64 * 64; idx += 256) {
    int e = idx >> 6, c = idx & 63;
    rf_t[c * 72 + e] = rf[(e0 + e) * 64 + c];
  }
  for (int idx = tid; idx < 64 * 32; idx += 256) {
    int e = idx >> 5, u = idx & 31;
    hs[(e << 5) + u] = h[ei[e0 + e] * 32 + u];
  }
  if (tid < 64) dst_s[tid] = ei[NE + e0 + tid];
  for (int idx = tid; idx < 64 * 9; idx += 256) {
    int e = idx / 9, i = idx - e * 9;
    sh_s[idx] = sh[(e0 + e) * 9 + i];
  }

  int w = tid & 31, eg = tid >> 5;
  int ebase = eg * 8;
  float macc[8][3];
  #pragma unroll
  for (int e = 0; e < 8; ++e)
    #pragma unroll
    for (int l = 0; l < 3; ++l) macc[e][l] = 0.f;

  #pragma unroll
  for (int l = 0; l < 3; ++l) {
    for (int ch8 = 0; ch8 < 8; ++ch8) {
      int cb = (l * 8 + ch8) * 128;
      __syncthreads();
      for (int idx = tid; idx < 8192; idx += 256) {
        int c = idx >> 7, cl = idx & 127;
        aw_s[(c << 7) + ((cl & 31) << 2) + (cl >> 5)] = a_w[c * 3072 + cb + cl];
      }
      if (tid < 128) ab_s[tid] = a_b[cb + tid];
      __syncthreads();
      float C[8][4];
      #pragma unroll
      for (int e = 0; e < 8; ++e)
        #pragma unroll
        for (int q = 0; q < 4; ++q) C[e][q] = 0.f;
      for (int c = 0; c < 64; ++c) {
        const float4 a4 = *(const float4*)&aw_s[(c << 7) + (w << 2)];
        const float4 r0 = *(const float4*)&rf_t[c * 72 + ebase];
        const float4 r1 = *(const float4*)&rf_t[c * 72 + ebase + 4];
        float ar[8] = {r0.x, r0.y, r0.z, r0.w, r1.x, r1.y, r1.z, r1.w};
        float aq[4] = {a4.x, a4.y, a4.z, a4.w};
        #pragma unroll
        for (int e = 0; e < 8; ++e)
          #pragma unroll
          for (int q = 0; q < 4; ++q) C[e][q] += ar[e] * aq[q];
      }
      #pragma unroll
      for (int q = 0; q < 4; ++q) {
        float bq = ab_s[(q << 5) + w];
        #pragma unroll
        for (int e = 0; e < 8; ++e) {
          float hv = hs[((ebase + e) << 5) + ch8 * 4 + q];
          macc[e][l] += hv * (C[e][q] + bq);
        }
      }
    }
  }

  if (tid < 64) atomicAdd(&cnt[dst_s[tid]], 1.0f);
  #pragma unroll
  for (int e = 0; e < 8; ++e) {
    int eG = ebase + e;
    float* arow = aout + dst_s[eG] * 288;
    float m0 = macc[e][0] * INV_SQM;
    float m1 = macc[e][1] * INV_SQM;
    float m2 = macc[e][2] * INV_SQM;
    atomicAdd(&arow[w], m0 * sh_s[eG * 9 + 0]);
    #pragma unroll
    for (int i = 0; i < 3; ++i)
      atomicAdd(&arow[32 + w * 3 + i], m1 * sh_s[eG * 9 + 1 + i] * 0.57735027f);
    #pragma unroll
    for (int i = 0; i < 5; ++i)
      atomicAdd(&arow[128 + w * 5 + i], m2 * sh_s[eG * 9 + 4 + i] * 0.44721360f);
  }
}

// ---------- a /= max(cnt,1) ----------
__global__ __launch_bounds__(256) void k_div(float* __restrict__ a, const float* __restrict__ cnt)
{
  int z = blockIdx.x;
  float inv = 1.0f / fmaxf(cnt[z], 1.0f);
  for (int c = threadIdx.x; c < 288; c += 256) a[z * 288 + c] *= inv;
}

// ---------- W[p][u][v][w] f32  ->  Wt[p][u][w][v] bf16 (one (p,u) slice/block) ----------
__global__ __launch_bounds__(256) void k_prepw(const float* __restrict__ W,
                                               unsigned short* __restrict__ Wt)
{
  __shared__ float buf[32 * 33];
  int tid = threadIdx.x;
  long base = (long)blockIdx.x * 1024;
  #pragma unroll
  for (int it = 0; it < 4; ++it) {
    int idx = it * 256 + tid;
    int w = idx & 31, v = idx >> 5;
    buf[w * 33 + v] = W[base + v * 32 + w];
  }
  __syncthreads();
  unsigned* out32 = (unsigned*)(Wt + base);
  #pragma unroll
  for (int it = 0; it < 2; ++it) {
    int idx = it * 256 + tid;
    int w = idx >> 4, vp = idx & 15;
    float f0 = buf[w * 33 + vp * 2], f1 = buf[w * 33 + vp * 2 + 1];
    unsigned pk = (unsigned)(unsigned short)f2bf(f0) |
                  ((unsigned)(unsigned short)f2bf(f1) << 16);
    out32[w * 16 + vp] = pk;
  }
}

// ---------- one TP path on MFMA ----------
template<int PI, int WIDX>
__device__ __forceinline__ void process_path(const float* __restrict__ x_s,
    const float* __restrict__ y_s, const unsigned short* __restrict__ wt,
    int lane, int wave, ffrag acc[9][2])
{
  constexpr int ip = cIP[PI], jp = cJP[PI], kp = cKP[PI];
  constexpr int di = cDL[ip], dj = cDL[jp], dk = cDL[kp];
  constexpr int xb = cOF[ip], yb = cOF[jp];
  constexpr int ks0 = (kp == 0) ? 0 : ((kp == 1) ? 1 : 4);
  constexpr int nA = cKo[PI][0];
  constexpr int nB = cKo[PI][dk];
  const int z = lane & 15, quad = lane >> 4;

  float yreg[8][dj];
  #pragma unroll
  for (int vi = 0; vi < 8; ++vi)
    #pragma unroll
    for (int j = 0; j < dj; ++j)
      yreg[vi][j] = y_s[z * 292 + yb + (quad * 8 + vi) * dj + j];

  for (int uu = 0; uu < 8; ++uu) {
    int u = wave * 8 + uu;
    const unsigned short* wb = wt + (((WIDX * 32 + u) * 32) << 5) + quad * 8;
    bfrag b0 = *(const bfrag*)(wb + (z << 5));          // w = lane&15
    bfrag b1 = *(const bfrag*)(wb + ((16 + z) << 5));   // w = 16 + lane&15
    float xv[di];
    #pragma unroll
    for (int i = 0; i < di; ++i) xv[i] = x_s[z * 292 + xb + u * di + i];
    float xc[nB - nA];
    #pragma unroll
    for (int n = nA; n < nB; ++n) xc[n - nA] = xv[cNI[n]] * cNV[n];
    bfrag fa[dk];
    #pragma unroll
    for (int vi = 0; vi < 8; ++vi) {
      float T[dk];
      #pragma unroll
      for (int k = 0; k < dk; ++k) T[k] = 0.f;
      #pragma unroll
      for (int k = 0; k < dk; ++k)
        #pragma unroll
        for (int n = cKo[PI][k]; n < cKo[PI][k + 1]; ++n)
          T[k] += xc[n - nA] * yreg[vi][cNJ[n]];
      #pragma unroll
      for (int k = 0; k < dk; ++k) fa[k][vi] = f2bf(T[k]);
    }
    #pragma unroll
    for (int k = 0; k < dk; ++k) {
      acc[ks0 + k][0] = __builtin_amdgcn_mfma_f32_16x16x32_bf16(fa[k], b0, acc[ks0 + k][0], 0, 0, 0);
      acc[ks0 + k][1] = __builtin_amdgcn_mfma_f32_16x16x32_bf16(fa[k], b1, acc[ks0 + k][1], 0, 0, 0);
    }
  }
}

// MODE 0: all 11 paths (o3a/o3b). MODE 1: o2_uvw paths {1,2,6}.
template<int MODE>
__global__ __launch_bounds__(256, 2) void k_pairwise_mfma(
    const float* __restrict__ x, const float* __restrict__ y,
    const unsigned short* __restrict__ wt, float* __restrict__ out, float scale)
{
  __shared__ float smem[9504];        // x_s[16*292] | y_s[16*292]; 2 red slices of 4752
  float* x_s = smem;
  float* y_s = smem + 4672;
  int tid = threadIdx.x;
  int z0 = blockIdx.x * 16;
  for (int idx = tid; idx < 16 * 72; idx += 256) {
    int r = idx / 72, f = (idx - r * 72) * 4;
    *(float4*)&x_s[r * 292 + f] = *(const float4*)&x[(z0 + r) * 288 + f];
    *(float4*)&y_s[r * 292 + f] = *(const float4*)&y[(z0 + r) * 288 + f];
  }
  __syncthreads();
  int lane = tid & 63, wave = tid >> 6;
  ffrag acc[9][2] = {};

  if constexpr (MODE == 0) {
    process_path<0, 0>(x_s, y_s, wt, lane, wave, acc);
    process_path<1, 1>(x_s, y_s, wt, lane, wave, acc);
    process_path<2, 2>(x_s, y_s, wt, lane, wave, acc);
    process_path<3, 3>(x_s, y_s, wt, lane, wave, acc);
    process_path<4, 4>(x_s, y_s, wt, lane, wave, acc);
    process_path<5, 5>(x_s, y_s, wt, lane, wave, acc);
    process_path<6, 6>(x_s, y_s, wt, lane, wave, acc);
    process_path<7, 7>(x_s, y_s, wt, lane, wave, acc);
    process_path<8, 8>(x_s, y_s, wt, lane, wave, acc);
    process_path<9, 9>(x_s, y_s, wt, lane, wave, acc);
    process_path<10, 10>(x_s, y_s, wt, lane, wave, acc);
  } else {
    process_path<1, 0>(x_s, y_s, wt, lane, wave, acc);
    process_path<2, 1>(x_s, y_s, wt, lane, wave, acc);
    process_path<6, 2>(x_s, y_s, wt, lane, wave, acc);
  }

  // ---- deterministic cross-wave reduction: (w0 + w2) + (w1 + w3) ----
  // Fixed summation order regardless of wave scheduling (bitwise reproducible
  // across graph replays — LDS atomicAdd here tripped the harness tripwire).
  float* slice0 = smem;          // 4752 floats, row stride 33
  float* slice1 = smem + 4752;   // 4752 floats
  int n15 = lane & 15, quad = lane >> 4;
  __syncthreads();
  if (wave >= 2) {
    float* sl = (wave == 2) ? slice0 : slice1;
    #pragma unroll
    for (int s = 0; s < 9; ++s)
      #pragma unroll
      for (int wh = 0; wh < 2; ++wh)
        #pragma unroll
        for (int r = 0; r < 4; ++r)
          sl[(s * 16 + quad * 4 + r) * 33 + wh * 16 + n15] = acc[s][wh][r];
  }
  __syncthreads();
  if (wave < 2) {
    float* sl = (wave == 0) ? slice0 : slice1;
    #pragma unroll
    for (int s = 0; s < 9; ++s)
      #pragma unroll
      for (int wh = 0; wh < 2; ++wh)
        #pragma unroll
        for (int r = 0; r < 4; ++r)
          acc[s][wh][r] += sl[(s * 16 + quad * 4 + r) * 33 + wh * 16 + n15];
  }
  __syncthreads();
  if (wave == 1) {
    #pragma unroll
    for (int s = 0; s < 9; ++s)
      #pragma unroll
      for (int wh = 0; wh < 2; ++wh)
        #pragma unroll
        for (int r = 0; r < 4; ++r)
          slice1[(s * 16 + quad * 4 + r) * 33 + wh * 16 + n15] = acc[s][wh][r];
  }
  __syncthreads();
  if (wave == 0) {
    #pragma unroll
    for (int s = 0; s < 9; ++s)
      #pragma unroll
      for (int wh = 0; wh < 2; ++wh)
        #pragma unroll
        for (int r = 0; r < 4; ++r) {
          int o = (s * 16 + quad * 4 + r) * 33 + wh * 16 + n15;
          slice0[o] = acc[s][wh][r] + slice1[o];
        }
  }
  __syncthreads();
  for (int idx = tid; idx < 4608; idx += 256) {
    int w = idx & 31, rest = idx >> 5;
    int zz = rest & 15, ks = rest >> 4;
    int c = (ks == 0) ? w : (ks < 4 ? 32 + w * 3 + (ks - 1) : 128 + w * 5 + (ks - 4));
    out[(z0 + zz) * 288 + c] = scale * slice0[(ks * 16 + zz) * 33 + w];
  }
}

// ---------- uvu part of order2 ----------
__global__ __launch_bounds__(256) void k_uvu(
    const float* __restrict__ x, const float* __restrict__ W, float* __restrict__ out)
{
  __shared__ __align__(16) float x_t[16 * 288];
  __shared__ float Wt[1024]; // [v][u]
  int tid = threadIdx.x;
  int z0 = blockIdx.x * 16;
  for (int idx = tid; idx < 16 * 72; idx += 256) {
    int r = idx / 72, f = idx - r * 72;
    *(float4*)&x_t[r * 288 + f * 4] = *(const float4*)&x[(z0 + r) * 288 + f * 4];
  }
  int u = tid & 31, zq = tid >> 5;
  float acc0[2] = {0.f, 0.f};
  float acc2[2][5];
  #pragma unroll
  for (int zz = 0; zz < 2; ++zz)
    #pragma unroll
    for (int k = 0; k < 5; ++k) acc2[zz][k] = 0.f;

  for (int p = 0; p < 5; ++p) {
    int pi = PL_UVU[p];
    const float* Wp = W + p * 1024;
    int ip = P_IP[pi], jp = P_JP[pi], kp = P_KP[pi];
    int di = DLT[ip], dj = DLT[jp];
    int xb = OFFT[ip], yb = OFFT[jp];
    __syncthreads();
    for (int idx = tid; idx < 1024; idx += 256)
      Wt[((idx & 31) << 5) + (idx >> 5)] = Wp[idx];
    __syncthreads();
    #pragma unroll
    for (int zz = 0; zz < 2; ++zz) {
      int z = zq + (zz << 3);
      const float* xr = &x_t[z * 288 + xb + u * di];
      const float* yrb = &x_t[z * 288 + yb];
      for (int v = 0; v < 32; ++v) {
        float wv = Wt[(v << 5) + u];
        const float* yr = yrb + v * dj;
        if (kp == 0) {
          float t = 0.f;
          for (int n = PKo[pi][0]; n < PKo[pi][1]; ++n) t += xr[NZ_I[n]] * yr[NZ_J[n]] * NZ_V[n];
          acc0[zz] += wv * t;
        } else {
          float t;
          t = 0.f; for (int n = PKo[pi][0]; n < PKo[pi][1]; ++n) t += xr[NZ_I[n]] * yr[NZ_J[n]] * NZ_V[n];
          acc2[zz][0] += wv * t;
          t = 0.f; for (int n = PKo[pi][1]; n < PKo[pi][2]; ++n) t += xr[NZ_I[n]] * yr[NZ_J[n]] * NZ_V[n];
          acc2[zz][1] += wv * t;
          t = 0.f; for (int n = PKo[pi][2]; n < PKo[pi][3]; ++n) t += xr[NZ_I[n]] * yr[NZ_J[n]] * NZ_V[n];
          acc2[zz][2] += wv * t;
          t = 0.f; for (int n = PKo[pi][3]; n < PKo[pi][4]; ++n) t += xr[NZ_I[n]] * yr[NZ_J[n]] * NZ_V[n];
          acc2[zz][3] += wv * t;
          t = 0.f; for (int n = PKo[pi][4]; n < PKo[pi][5]; ++n) t += xr[NZ_I[n]] * yr[NZ_J[n]] * NZ_V[n];
          acc2[zz][4] += wv * t;
        }
      }
    }
  }
  #pragma unroll
  for (int zz = 0; zz < 2; ++zz) {
    int zg = z0 + zq + (zz << 3);
    float* orow = out + zg * 288;
    orow[u] += INV_SQM * acc0[zz];
    #pragma unroll
    for (int kk = 0; kk < 5; ++kk) orow[128 + u * 5 + kk] += INV_SQM * acc2[zz][kk];
  }
}

// ---------- final lin chains + self connection ----------
__device__ __forceinline__ void lin_row(float* dst, const float* src, const float* Wm, int w)
{
  {
    float s = 0.f;
    for (int u = 0; u < 32; ++u) s += src[u] * Wm[(u << 5) + w];
    dst[w] = s * INV_SQM;
  }
  #pragma unroll
  for (int i = 0; i < 3; ++i) {
    float s = 0.f;
    for (int u = 0; u < 32; ++u) s += src[32 + u * 3 + i] * Wm[1024 + (u << 5) + w];
    dst[32 + w * 3 + i] = s * INV_SQM;
  }
  #pragma unroll
  for (int i = 0; i < 5; ++i) {
    float s = 0.f;
    for (int u = 0; u < 32; ++u) s += src[128 + u * 5 + i] * Wm[2048 + (u << 5) + w];
    dst[128 + w * 5 + i] = s * INV_SQM;
  }
}

__device__ __forceinline__ void lin_acc(float* msg, const float* src, const float* Wm, int w)
{
  {
    float s = 0.f;
    for (int u = 0; u < 32; ++u) s += src[u] * Wm[(u << 5) + w];
    msg[0] += s * INV_SQM;
  }
  #pragma unroll
  for (int i = 0; i < 3; ++i) {
    float s = 0.f;
    for (int u = 0; u < 32; ++u) s += src[32 + u * 3 + i] * Wm[1024 + (u << 5) + w];
    msg[1 + i] += s * INV_SQM;
  }
  #pragma unroll
  for (int i = 0; i < 5; ++i) {
    float s = 0.f;
    for (int u = 0; u < 32; ++u) s += src[128 + u * 5 + i] * Wm[2048 + (u << 5) + w];
    msg[4 + i] += s * INV_SQM;
  }
}

__global__ __launch_bounds__(256) void k_finalize(
    const float* __restrict__ a, const float* __restrict__ b2, const float* __restrict__ b3,
    const float* __restrict__ selfc, const float* __restrict__ lin_o1,
    const float* __restrict__ mix_w, const float* __restrict__ comb_w,
    float* __restrict__ out)
{
  __shared__ float bufA[8 * 288];
  __shared__ float bufB[8 * 288];
  int tid = threadIdx.x;
  int w = tid & 31, zl = tid >> 5;
  int z = blockIdx.x * 8 + zl;
  float msg[9];
  #pragma unroll
  for (int s = 0; s < 9; ++s) msg[s] = 0.f;
  float* rowA = &bufA[zl * 288];
  float* rowB = &bufB[zl * 288];
  lin_row(rowA, a + z * 288, lin_o1, w);
  __syncthreads();
  lin_row(rowB, rowA, mix_w, w);
  __syncthreads();
  lin_acc(msg, rowB, comb_w, w);
  __syncthreads();
  lin_row(rowA, b2 + z * 288, mix_w + 3072, w);
  __syncthreads();
  lin_acc(msg, rowA, comb_w + 3072, w);
  __syncthreads();
  lin_row(rowA, b3 + z * 288, mix_w + 6144, w);
  __syncthreads();
  lin_acc(msg, rowA, comb_w + 6144, w);

  float sc = selfc[(z << 5) + w];
  float* orow = out + z * 288;
  orow[w] = msg[0] + sc;
  #pragma unroll
  for (int i = 0; i < 3; ++i) orow[32 + w * 3 + i] = msg[1 + i];
  #pragma unroll
  for (int i = 0; i < 5; ++i) orow[128 + w * 5 + i] = msg[4 + i];
}

extern "C" void kernel_launch(void* const* d_in, const int* in_sizes, int n_in,
                              void* d_out, int out_size, void* d_ws, size_t ws_size,
                              hipStream_t stream)
{
  (void)in_sizes; (void)n_in; (void)out_size; (void)ws_size;
  const float* nf   = (const float*)d_in[0];
  const int*   ei   = (const int*)d_in[1];
  const float* sh   = (const float*)d_in[2];
  const float* re   = (const float*)d_in[3];
  const float* ea   = (const float*)d_in[4];
  const float* rw1  = (const float*)d_in[5];
  const float* rb1  = (const float*)d_in[6];
  const float* rw2  = (const float*)d_in[7];
  const float* rb2  = (const float*)d_in[8];
  const float* rw3  = (const float*)d_in[9];
  const float* rb3  = (const float*)d_in[10];
  const float* aw   = (const float*)d_in[11];
  const float* ab   = (const float*)d_in[12];
  const float* embw = (const float*)d_in[13];
  const float* lino1= (const float*)d_in[14];
  const float* o2uvw= (const float*)d_in[15];
  const float* o2uvu= (const float*)d_in[16];
  const float* o3a  = (const float*)d_in[17];
  const float* o3b  = (const float*)d_in[18];
  const float* mixw = (const float*)d_in[19];
  const float* combw= (const float*)d_in[20];
  const float* selfw= (const float*)d_in[21];
  float* out = (float*)d_out;
  float* ws  = (float*)d_ws;

  // workspace layout (floats)
  float* h     = ws;                // 320000
  float* selfc = ws + 320000;       // 320000
  float* rfb   = ws + 640000;       // 4096000  (rf; reused as b2 afterwards)
  float* a     = ws + 4736000;      // 2880000
  float* cnt   = ws + 7616000;      // 10000
  float* cint  = ws + 7626000;      // 2880000  (b3 computed in-place)
  float* b2 = rfb;
  float* b3 = cint;
  unsigned short* wt_o2  = (unsigned short*)(ws + 10506000); //  98304 ush
  unsigned short* wt_o3a = wt_o2 + 98304;                    // 360448 ush
  unsigned short* wt_o3b = wt_o3a + 360448;                  // 360448 ush

  hipMemsetAsync(a, 0, (2880000 + 10000) * sizeof(float), stream);
  k_prepw<<<96, 256, 0, stream>>>(o2uvw, wt_o2);
  k_prepw<<<352, 256, 0, stream>>>(o3a, wt_o3a);
  k_prepw<<<352, 256, 0, stream>>>(o3b, wt_o3b);
  k_embed<<<1250, 256, 0, stream>>>(nf, embw, selfw, h, selfc);
  k_radial<<<16000, 256, 0, stream>>>(re, ea, rw1, rb1, rw2, rb2, rw3, rb3, rfb);
  k_edge<<<1000, 256, 0, stream>>>(rfb, h, ei, sh, aw, ab, a, cnt);
  k_div<<<10000, 256, 0, stream>>>(a, cnt);
  k_pairwise_mfma<1><<<625, 256, 0, stream>>>(a, a, wt_o2, b2, INV_MUL);
  k_uvu<<<625, 256, 0, stream>>>(a, o2uvu, b2);
  k_pairwise_mfma<0><<<625, 256, 0, stream>>>(a, a, wt_o3a, cint, INV_MUL);
  k_pairwise_mfma<0><<<625, 256, 0, stream>>>(cint, a, wt_o3b, b3, INV_MUL);
  k_finalize<<<1250, 256, 0, stream>>>(a, b2, b3, selfc, lino1, mixw, combw, out);
}

// Round 6
// 1445.155 us; speedup vs baseline: 4.5116x; 1.0976x over previous
//
#include <hip/hip_runtime.h>

#define NN 10000
#define NE 64000
#define INV_SQM 0.17677669529663687f   // 1/sqrt(32)
#define INV_MUL 0.03125f               // 1/32

typedef __attribute__((ext_vector_type(8))) short bfrag;   // 8 bf16 (4 VGPRs)
typedef __attribute__((ext_vector_type(4))) float ffrag;   // 4 fp32 acc

__device__ __forceinline__ short f2bf(float f) {
  unsigned u = __float_as_uint(f);
  unsigned r = (u + 0x7FFFu + ((u >> 16) & 1u)) >> 16;  // RNE
  return (short)r;
}

// ---------- Clebsch-Gordan sparse tables (runtime copies for k_uvu) ----------
__constant__ int P_IP[11] = {0,0,0,1,1,1,1,2,2,2,2};
__constant__ int P_JP[11] = {0,1,2,0,1,1,2,0,1,2,2};
__constant__ int P_KP[11] = {0,1,2,1,0,2,1,2,1,0,2};
__constant__ int PKo[11][6] = {
  {0,1,1,1,1,1},{1,2,3,4,4,4},{4,5,6,7,8,9},{9,10,11,12,12,12},
  {12,15,15,15,15,15},{15,17,19,22,24,26},{26,30,34,37,37,37},
  {37,38,39,40,41,42},{42,46,50,53,53,53},{53,58,58,58,58,58},
  {58,62,68,73,79,83}};
__constant__ int DLT[3]  = {1,3,5};
__constant__ int OFFT[3] = {0,32,128};
__constant__ unsigned char NZ_I[83] = {
  0,
  0,0,0,
  0,0,0,0,0,
  0,1,2,
  0,1,2,
  0,1,1,2,0,1,2,0,2,0,1,
  1,0,2,0,0,2,1,1,1,2,0,
  0,1,2,3,4,
  0,2,3,4,0,1,2,4,1,2,3,
  0,1,2,3,4,
  0,2,1,3,0,3,1,2,1,4,0,1,2,3,4,0,1,2,3,3,4,1,2,4,3};
__constant__ unsigned char NZ_J[83] = {
  0,
  0,1,2,
  0,1,2,3,4,
  0,0,0,
  0,1,2,
  1,0,2,1,0,1,2,2,0,0,1,
  0,2,3,4,0,1,2,4,1,2,3,
  0,0,0,0,0,
  1,0,2,0,0,2,1,1,1,2,0,
  0,1,2,3,4,
  2,0,3,1,3,0,2,1,4,1,0,1,2,3,4,1,0,3,2,4,3,1,4,2,3};
__constant__ float NZ_V[83] = {
  1.0f,
  0.57735027f,0.57735027f,0.57735027f,
  0.44721360f,0.44721360f,0.44721360f,0.44721360f,0.44721360f,
  0.57735027f,0.57735027f,0.57735027f,
  0.57735027f,0.57735027f,0.57735027f,
  0.31622777f,0.31622777f,0.31622777f,0.31622777f,-0.18257419f,-0.18257419f,
  0.36514837f,0.31622777f,0.31622777f,0.31622777f,-0.31622777f,
  0.31622777f,-0.18257419f,0.31622777f,0.31622777f,0.31622777f,0.31622777f,
  -0.18257419f,-0.31622777f,0.31622777f,0.36514837f,0.31622777f,
  0.44721360f,0.44721360f,0.44721360f,0.44721360f,0.44721360f,
  0.31622777f,-0.18257419f,0.31622777f,0.31622777f,0.31622777f,0.31622777f,
  -0.18257419f,-0.31622777f,0.31622777f,0.36514837f,0.31622777f,
  0.44721360f,0.44721360f,0.44721360f,0.44721360f,0.44721360f,
  -0.23904572f,-0.23904572f,0.20702483f,0.20702483f,
  0.20702483f,0.20702483f,0.11952286f,0.11952286f,-0.20702483f,-0.20702483f,
  -0.23904572f,0.11952286f,0.23904572f,0.11952286f,-0.23904572f,
  0.20702483f,0.20702483f,0.11952286f,0.11952286f,0.20702483f,0.20702483f,
  -0.20702483f,-0.23904572f,-0.23904572f,0.20702483f};
__constant__ int PL_UVU[5] = {0,4,5,9,10};  // O2_UVU paths within PATHS_FULL

// ---------- compile-time copies for the templated MFMA path ----------
constexpr int cIP[11] = {0,0,0,1,1,1,1,2,2,2,2};
constexpr int cJP[11] = {0,1,2,0,1,1,2,0,1,2,2};
constexpr int cKP[11] = {0,1,2,1,0,2,1,2,1,0,2};
constexpr int cKo[11][6] = {
  {0,1,1,1,1,1},{1,2,3,4,4,4},{4,5,6,7,8,9},{9,10,11,12,12,12},
  {12,15,15,15,15,15},{15,17,19,22,24,26},{26,30,34,37,37,37},
  {37,38,39,40,41,42},{42,46,50,53,53,53},{53,58,58,58,58,58},
  {58,62,68,73,79,83}};
constexpr int cDL[3]  = {1,3,5};
constexpr int cOF[3]  = {0,32,128};
constexpr int cNI[83] = {
  0, 0,0,0, 0,0,0,0,0, 0,1,2, 0,1,2,
  0,1,1,2,0,1,2,0,2,0,1,
  1,0,2,0,0,2,1,1,1,2,0,
  0,1,2,3,4,
  0,2,3,4,0,1,2,4,1,2,3,
  0,1,2,3,4,
  0,2,1,3,0,3,1,2,1,4,0,1,2,3,4,0,1,2,3,3,4,1,2,4,3};
constexpr int cNJ[83] = {
  0, 0,1,2, 0,1,2,3,4, 0,0,0, 0,1,2,
  1,0,2,1,0,1,2,2,0,0,1,
  0,2,3,4,0,1,2,4,1,2,3,
  0,0,0,0,0,
  1,0,2,0,0,2,1,1,1,2,0,
  0,1,2,3,4,
  2,0,3,1,3,0,2,1,4,1,0,1,2,3,4,1,0,3,2,4,3,1,4,2,3};
constexpr float cNV[83] = {
  1.0f,
  0.57735027f,0.57735027f,0.57735027f,
  0.44721360f,0.44721360f,0.44721360f,0.44721360f,0.44721360f,
  0.57735027f,0.57735027f,0.57735027f,
  0.57735027f,0.57735027f,0.57735027f,
  0.31622777f,0.31622777f,0.31622777f,0.31622777f,-0.18257419f,-0.18257419f,
  0.36514837f,0.31622777f,0.31622777f,0.31622777f,-0.31622777f,
  0.31622777f,-0.18257419f,0.31622777f,0.31622777f,0.31622777f,0.31622777f,
  -0.18257419f,-0.31622777f,0.31622777f,0.36514837f,0.31622777f,
  0.44721360f,0.44721360f,0.44721360f,0.44721360f,0.44721360f,
  0.31622777f,-0.18257419f,0.31622777f,0.31622777f,0.31622777f,0.31622777f,
  -0.18257419f,-0.31622777f,0.31622777f,0.36514837f,0.31622777f,
  0.44721360f,0.44721360f,0.44721360f,0.44721360f,0.44721360f,
  -0.23904572f,-0.23904572f,0.20702483f,0.20702483f,
  0.20702483f,0.20702483f,0.11952286f,0.11952286f,-0.20702483f,-0.20702483f,
  -0.23904572f,0.11952286f,0.23904572f,0.11952286f,-0.23904572f,
  0.20702483f,0.20702483f,0.11952286f,0.11952286f,0.20702483f,0.20702483f,
  -0.20702483f,-0.23904572f,-0.23904572f,0.20702483f};

// ---------- h = nf@emb_w/SQM ; selfc = nf@self_w/SQM ----------
__global__ __launch_bounds__(256) void k_embed(const float* __restrict__ nf,
    const float* __restrict__ emb_w, const float* __restrict__ self_w,
    float* __restrict__ h, float* __restrict__ selfc)
{
  __shared__ float We[1024], Wsf[1024];
  int tid = threadIdx.x;
  for (int i = tid; i < 1024; i += 256) { We[i] = emb_w[i]; Wsf[i] = self_w[i]; }
  __syncthreads();
  int z = blockIdx.x * 8 + (tid >> 5);
  int u = tid & 31;
  if (z >= NN) return;
  const float* row = nf + z * 32;
  float ah = 0.f, as = 0.f;
  #pragma unroll 8
  for (int v = 0; v < 32; ++v) {
    float xv = row[v];
    ah += xv * We[(v << 5) + u];
    as += xv * Wsf[(v << 5) + u];
  }
  h[(z << 5) + u]     = ah * INV_SQM;
  selfc[(z << 5) + u] = as * INV_SQM;
}

// ---------- per-edge radial MLP -> rf[64], 32 edges/block ----------
__global__ __launch_bounds__(256) void k_radial(
    const float* __restrict__ re, const float* __restrict__ ea,
    const float* __restrict__ w1, const float* __restrict__ b1,
    const float* __restrict__ w2, const float* __restrict__ b2,
    const float* __restrict__ w3, const float* __restrict__ b3,
    float* __restrict__ rf)
{
  __shared__ float W1[24 * 64];
  __shared__ float W2[64 * 64];
  __shared__ float W3[64 * 64];
  __shared__ float rin[32][25];
  __shared__ float t1[32][65], t2[32][65];
  int t = threadIdx.x;
  for (int i = t; i < 24 * 64; i += 256) W1[i] = w1[i];
  for (int i = t; i < 4096; i += 256) { W2[i] = w2[i]; W3[i] = w3[i]; }
  int e0 = blockIdx.x * 32;
  for (int idx = t; idx < 768; idx += 256) {
    int el = idx / 24, i = idx - el * 24;
    int e = e0 + el;
    rin[el][i] = (i < 8) ? re[e * 8 + i] : ea[e * 16 + (i - 8)];
  }
  __syncthreads();
  #pragma unroll
  for (int g = 0; g < 8; ++g) {
    int idx = g * 256 + t, el = idx >> 6, o = idx & 63;
    float acc = b1[o];
    #pragma unroll 8
    for (int i = 0; i < 24; ++i) acc += rin[el][i] * W1[i * 64 + o];
    t1[el][o] = acc / (1.f + __expf(-acc));
  }
  __syncthreads();
  #pragma unroll
  for (int g = 0; g < 8; ++g) {
    int idx = g * 256 + t, el = idx >> 6, o = idx & 63;
    float acc = b2[o];
    #pragma unroll 8
    for (int c = 0; c < 64; ++c) acc += t1[el][c] * W2[(c << 6) + o];
    t2[el][o] = acc / (1.f + __expf(-acc));
  }
  __syncthreads();
  #pragma unroll
  for (int g = 0; g < 8; ++g) {
    int idx = g * 256 + t, el = idx >> 6, o = idx & 63;
    float acc = b3[o];
    #pragma unroll 8
    for (int c = 0; c < 64; ++c) acc += t2[el][c] * W3[(c << 6) + o];
    rf[(e0 + el) * 64 + o] = acc;
  }
}

// ---------- Bt hi/lo split (3xBF16 scheme) ----------
// Bt[n=l*32+w][k]: k<2048 -> a_w[c=k>>5][l][u=k&31][w]; k in [2048,2080) -> a_b.
// hi = exact float truncation to top-16 bits; lo = v - hi (exact), trunc16.
__global__ __launch_bounds__(256) void k_prepb(const float* __restrict__ aw,
    const float* __restrict__ ab, unsigned short* __restrict__ Bthi,
    unsigned short* __restrict__ Btlo)
{
  int n = blockIdx.x;          // 0..95
  int l = n >> 5, w = n & 31;
  for (int k = threadIdx.x; k < 2080; k += 256) {
    float v = (k < 2048) ? aw[(k >> 5) * 3072 + l * 1024 + (k & 31) * 32 + w]
                         : ab[l * 1024 + (k - 2048) * 32 + w];
    unsigned u = __float_as_uint(v);
    float hif = __uint_as_float(u & 0xffff0000u);
    float lo = v - hif;
    Bthi[n * 2080 + k] = (unsigned short)(u >> 16);
    Btlo[n * 2080 + k] = (unsigned short)(__float_as_uint(lo) >> 16);
  }
}

// ---------- edge GEMM on MFMA (split-precision) + fused scatter ----------
// mixed[e][n=l*32+w] = sum_k g[e,k]*Bt[n][k], g[e, c*32+u] = rf[e,c]*h[src,u],
// k-step 64 (ko=2048) is the bias block with r=1. 3xBF16: Ahi*Bhi + Alo*Bhi
// + Ahi*Blo -> fp32-grade (residual ~2^-16), keeps bf16-MFMA throughput.
__global__ __launch_bounds__(256, 2) void k_edge_mfma(
    const float* __restrict__ rf, const float* __restrict__ h,
    const int* __restrict__ ei, const float* __restrict__ sh,
    const unsigned short* __restrict__ Bthi, const unsigned short* __restrict__ Btlo,
    float* __restrict__ aout, float* __restrict__ cnt)
{
  __shared__ float rf_s[128 * 65];   // 33.3 KB, pad 65 -> conflict-free column reads
  __shared__ float sh_s[128 * 9];
  __shared__ int dst_s[128];
  __shared__ int src_s[128];
  int tid = threadIdx.x;
  int e0 = blockIdx.x * 128;
  for (int idx = tid; idx < 128 * 64; idx += 256) {
    int e = idx >> 6, c = idx & 63;
    rf_s[e * 65 + c] = rf[(e0 + e) * 64 + c];
  }
  for (int idx = tid; idx < 128 * 9; idx += 256) {
    int e = idx / 9, i = idx - e * 9;
    sh_s[idx] = sh[(e0 + e) * 9 + i];
  }
  if (tid < 128) { src_s[tid] = ei[e0 + tid]; dst_s[tid] = ei[NE + e0 + tid]; }
  __syncthreads();

  int lane = tid & 63, wave = tid >> 6;
  int col = lane & 15, quad = lane >> 4;
  int eA = wave * 32 + col;          // m-tile 0 local edge (row = col in A)
  int eB = eA + 16;                  // m-tile 1
  const float* hpA = h + src_s[eA] * 32 + quad * 8;
  const float* hpB = h + src_s[eB] * 32 + quad * 8;
  float4 a0 = *(const float4*)hpA, a1 = *(const float4*)(hpA + 4);
  float4 b0 = *(const float4*)hpB, b1 = *(const float4*)(hpB + 4);
  float ha[8] = {a0.x, a0.y, a0.z, a0.w, a1.x, a1.y, a1.z, a1.w};
  float hb[8] = {b0.x, b0.y, b0.z, b0.w, b1.x, b1.y, b1.z, b1.w};

  ffrag acc[2][6] = {};
  const unsigned short* bhib = Bthi + col * 2080 + quad * 8;
  const unsigned short* blob = Btlo + col * 2080 + quad * 8;

  for (int s = 0; s < 65; ++s) {        // s==64: bias block (ko=2048), r=1
    float rA = (s < 64) ? rf_s[eA * 65 + s] : 1.0f;
    float rB = (s < 64) ? rf_s[eB * 65 + s] : 1.0f;
    bfrag hA, lA, hB, lB;
    #pragma unroll
    for (int j = 0; j < 8; ++j) {
      float gA = rA * ha[j];
      unsigned uA = __float_as_uint(gA);
      hA[j] = (short)(uA >> 16);
      float loA = gA - __uint_as_float(uA & 0xffff0000u);
      lA[j] = (short)(__float_as_uint(loA) >> 16);
      float gB = rB * hb[j];
      unsigned uB = __float_as_uint(gB);
      hB[j] = (short)(uB >> 16);
      float loB = gB - __uint_as_float(uB & 0xffff0000u);
      lB[j] = (short)(__float_as_uint(loB) >> 16);
    }
    int ko = s << 5;
    #pragma unroll
    for (int t = 0; t < 6; ++t) {
      bfrag bh = *(const bfrag*)(bhib + t * 16 * 2080 + ko);
      bfrag bl = *(const bfrag*)(blob + t * 16 * 2080 + ko);
      acc[0][t] = __builtin_amdgcn_mfma_f32_16x16x32_bf16(hA, bh, acc[0][t], 0, 0, 0);
      acc[1][t] = __builtin_amdgcn_mfma_f32_16x16x32_bf16(hB, bh, acc[1][t], 0, 0, 0);
      acc[0][t] = __builtin_amdgcn_mfma_f32_16x16x32_bf16(lA, bh, acc[0][t], 0, 0, 0);
      acc[1][t] = __builtin_amdgcn_mfma_f32_16x16x32_bf16(lB, bh, acc[1][t], 0, 0, 0);
      acc[0][t] = __builtin_amdgcn_mfma_f32_16x16x32_bf16(hA, bl, acc[0][t], 0, 0, 0);
      acc[1][t] = __builtin_amdgcn_mfma_f32_16x16x32_bf16(hB, bl, acc[1][t], 0, 0, 0);
    }
  }

  if (tid < 128) atomicAdd(&cnt[dst_s[tid]], 1.0f);
  // C tile (mt, t): edge = wave*32 + mt*16 + quad*4 + r; n = t*16 + col;
  // l = t>>1, w = (t&1)*16 + col  (uniform per t -> no divergence)
  #pragma unroll
  for (int mt = 0; mt < 2; ++mt) {
    #pragma unroll
    for (int r = 0; r < 4; ++r) {
      int el = wave * 32 + mt * 16 + quad * 4 + r;
      float* arow = aout + dst_s[el] * 288;
      const float* shp = &sh_s[el * 9];
      #pragma unroll
      for (int t = 0; t < 6; ++t) {
        int l = t >> 1;
        int w = ((t & 1) << 4) + col;
        float v = acc[mt][t][r] * INV_SQM;
        if (l == 0) {
          atomicAdd(&arow[w], v * shp[0]);
        } else if (l == 1) {
          #pragma unroll
          for (int i = 0; i < 3; ++i)
            atomicAdd(&arow[32 + w * 3 + i], v * shp[1 + i] * 0.57735027f);
        } else {
          #pragma unroll
          for (int i = 0; i < 5; ++i)
            atomicAdd(&arow[128 + w * 5 + i], v * shp[4 + i] * 0.44721360f);
        }
      }
    }
  }
}

// ---------- a /= max(cnt,1) ----------
__global__ __launch_bounds__(256) void k_div(float* __restrict__ a, const float* __restrict__ cnt)
{
  int z = blockIdx.x;
  float inv = 1.0f / fmaxf(cnt[z], 1.0f);
  for (int c = threadIdx.x; c < 288; c += 256) a[z * 288 + c] *= inv;
}

// ---------- W[p][u][v][w] f32  ->  Wt[p][u][w][v] bf16 (one (p,u) slice/block) ----------
__global__ __launch_bounds__(256) void k_prepw(const float* __restrict__ W,
                                               unsigned short* __restrict__ Wt)
{
  __shared__ float buf[32 * 33];
  int tid = threadIdx.x;
  long base = (long)blockIdx.x * 1024;
  #pragma unroll
  for (int it = 0; it < 4; ++it) {
    int idx = it * 256 + tid;
    int w = idx & 31, v = idx >> 5;
    buf[w * 33 + v] = W[base + v * 32 + w];
  }
  __syncthreads();
  unsigned* out32 = (unsigned*)(Wt + base);
  #pragma unroll
  for (int it = 0; it < 2; ++it) {
    int idx = it * 256 + tid;
    int w = idx >> 4, vp = idx & 15;
    float f0 = buf[w * 33 + vp * 2], f1 = buf[w * 33 + vp * 2 + 1];
    unsigned pk = (unsigned)(unsigned short)f2bf(f0) |
                  ((unsigned)(unsigned short)f2bf(f1) << 16);
    out32[w * 16 + vp] = pk;
  }
}

// ---------- one TP path on MFMA ----------
template<int PI, int WIDX>
__device__ __forceinline__ void process_path(const float* __restrict__ x_s,
    const float* __restrict__ y_s, const unsigned short* __restrict__ wt,
    int lane, int wave, ffrag acc[9][2])
{
  constexpr int ip = cIP[PI], jp = cJP[PI], kp = cKP[PI];
  constexpr int di = cDL[ip], dj = cDL[jp], dk = cDL[kp];
  constexpr int xb = cOF[ip], yb = cOF[jp];
  constexpr int ks0 = (kp == 0) ? 0 : ((kp == 1) ? 1 : 4);
  constexpr int nA = cKo[PI][0];
  constexpr int nB = cKo[PI][dk];
  const int z = lane & 15, quad = lane >> 4;

  float yreg[8][dj];
  #pragma unroll
  for (int vi = 0; vi < 8; ++vi)
    #pragma unroll
    for (int j = 0; j < dj; ++j)
      yreg[vi][j] = y_s[z * 292 + yb + (quad * 8 + vi) * dj + j];

  for (int uu = 0; uu < 8; ++uu) {
    int u = wave * 8 + uu;
    const unsigned short* wb = wt + (((WIDX * 32 + u) * 32) << 5) + quad * 8;
    bfrag b0 = *(const bfrag*)(wb + (z << 5));          // w = lane&15
    bfrag b1 = *(const bfrag*)(wb + ((16 + z) << 5));   // w = 16 + lane&15
    float xv[di];
    #pragma unroll
    for (int i = 0; i < di; ++i) xv[i] = x_s[z * 292 + xb + u * di + i];
    float xc[nB - nA];
    #pragma unroll
    for (int n = nA; n < nB; ++n) xc[n - nA] = xv[cNI[n]] * cNV[n];
    bfrag fa[dk];
    #pragma unroll
    for (int vi = 0; vi < 8; ++vi) {
      float T[dk];
      #pragma unroll
      for (int k = 0; k < dk; ++k) T[k] = 0.f;
      #pragma unroll
      for (int k = 0; k < dk; ++k)
        #pragma unroll
        for (int n = cKo[PI][k]; n < cKo[PI][k + 1]; ++n)
          T[k] += xc[n - nA] * yreg[vi][cNJ[n]];
      #pragma unroll
      for (int k = 0; k < dk; ++k) fa[k][vi] = f2bf(T[k]);
    }
    #pragma unroll
    for (int k = 0; k < dk; ++k) {
      acc[ks0 + k][0] = __builtin_amdgcn_mfma_f32_16x16x32_bf16(fa[k], b0, acc[ks0 + k][0], 0, 0, 0);
      acc[ks0 + k][1] = __builtin_amdgcn_mfma_f32_16x16x32_bf16(fa[k], b1, acc[ks0 + k][1], 0, 0, 0);
    }
  }
}

// MODE 0: all 11 paths (o3a/o3b). MODE 1: o2_uvw paths {1,2,6}.
template<int MODE>
__global__ __launch_bounds__(256, 2) void k_pairwise_mfma(
    const float* __restrict__ x, const float* __restrict__ y,
    const unsigned short* __restrict__ wt, float* __restrict__ out, float scale)
{
  __shared__ float smem[9504];        // x_s[16*292] | y_s[16*292]; 2 red slices of 4752
  float* x_s = smem;
  float* y_s = smem + 4672;
  int tid = threadIdx.x;
  int z0 = blockIdx.x * 16;
  for (int idx = tid; idx < 16 * 72; idx += 256) {
    int r = idx / 72, f = (idx - r * 72) * 4;
    *(float4*)&x_s[r * 292 + f] = *(const float4*)&x[(z0 + r) * 288 + f];
    *(float4*)&y_s[r * 292 + f] = *(const float4*)&y[(z0 + r) * 288 + f];
  }
  __syncthreads();
  int lane = tid & 63, wave = tid >> 6;
  ffrag acc[9][2] = {};

  if constexpr (MODE == 0) {
    process_path<0, 0>(x_s, y_s, wt, lane, wave, acc);
    process_path<1, 1>(x_s, y_s, wt, lane, wave, acc);
    process_path<2, 2>(x_s, y_s, wt, lane, wave, acc);
    process_path<3, 3>(x_s, y_s, wt, lane, wave, acc);
    process_path<4, 4>(x_s, y_s, wt, lane, wave, acc);
    process_path<5, 5>(x_s, y_s, wt, lane, wave, acc);
    process_path<6, 6>(x_s, y_s, wt, lane, wave, acc);
    process_path<7, 7>(x_s, y_s, wt, lane, wave, acc);
    process_path<8, 8>(x_s, y_s, wt, lane, wave, acc);
    process_path<9, 9>(x_s, y_s, wt, lane, wave, acc);
    process_path<10, 10>(x_s, y_s, wt, lane, wave, acc);
  } else {
    process_path<1, 0>(x_s, y_s, wt, lane, wave, acc);
    process_path<2, 1>(x_s, y_s, wt, lane, wave, acc);
    process_path<6, 2>(x_s, y_s, wt, lane, wave, acc);
  }

  // ---- deterministic cross-wave reduction: (w0 + w2) + (w1 + w3) ----
  float* slice0 = smem;          // 4752 floats, row stride 33
  float* slice1 = smem + 4752;   // 4752 floats
  int n15 = lane & 15, quad = lane >> 4;
  __syncthreads();
  if (wave >= 2) {
    float* sl = (wave == 2) ? slice0 : slice1;
    #pragma unroll
    for (int s = 0; s < 9; ++s)
      #pragma unroll
      for (int wh = 0; wh < 2; ++wh)
        #pragma unroll
        for (int r = 0; r < 4; ++r)
          sl[(s * 16 + quad * 4 + r) * 33 + wh * 16 + n15] = acc[s][wh][r];
  }
  __syncthreads();
  if (wave < 2) {
    float* sl = (wave == 0) ? slice0 : slice1;
    #pragma unroll
    for (int s = 0; s < 9; ++s)
      #pragma unroll
      for (int wh = 0; wh < 2; ++wh)
        #pragma unroll
        for (int r = 0; r < 4; ++r)
          acc[s][wh][r] += sl[(s * 16 + quad * 4 + r) * 33 + wh * 16 + n15];
  }
  __syncthreads();
  if (wave == 1) {
    #pragma unroll
    for (int s = 0; s < 9; ++s)
      #pragma unroll
      for (int wh = 0; wh < 2; ++wh)
        #pragma unroll
        for (int r = 0; r < 4; ++r)
          slice1[(s * 16 + quad * 4 + r) * 33 + wh * 16 + n15] = acc[s][wh][r];
  }
  __syncthreads();
  if (wave == 0) {
    #pragma unroll
    for (int s = 0; s < 9; ++s)
      #pragma unroll
      for (int wh = 0; wh < 2; ++wh)
        #pragma unroll
        for (int r = 0; r < 4; ++r) {
          int o = (s * 16 + quad * 4 + r) * 33 + wh * 16 + n15;
          slice0[o] = acc[s][wh][r] + slice1[o];
        }
  }
  __syncthreads();
  for (int idx = tid; idx < 4608; idx += 256) {
    int w = idx & 31, rest = idx >> 5;
    int zz = rest & 15, ks = rest >> 4;
    int c = (ks == 0) ? w : (ks < 4 ? 32 + w * 3 + (ks - 1) : 128 + w * 5 + (ks - 4));
    out[(z0 + zz) * 288 + c] = scale * slice0[(ks * 16 + zz) * 33 + w];
  }
}

// ---------- uvu part of order2 ----------
__global__ __launch_bounds__(256) void k_uvu(
    const float* __restrict__ x, const float* __restrict__ W, float* __restrict__ out)
{
  __shared__ __align__(16) float x_t[16 * 288];
  __shared__ float Wt[1024]; // [v][u]
  int tid = threadIdx.x;
  int z0 = blockIdx.x * 16;
  for (int idx = tid; idx < 16 * 72; idx += 256) {
    int r = idx / 72, f = idx - r * 72;
    *(float4*)&x_t[r * 288 + f * 4] = *(const float4*)&x[(z0 + r) * 288 + f * 4];
  }
  int u = tid & 31, zq = tid >> 5;
  float acc0[2] = {0.f, 0.f};
  float acc2[2][5];
  #pragma unroll
  for (int zz = 0; zz < 2; ++zz)
    #pragma unroll
    for (int k = 0; k < 5; ++k) acc2[zz][k] = 0.f;

  for (int p = 0; p < 5; ++p) {
    int pi = PL_UVU[p];
    const float* Wp = W + p * 1024;
    int ip = P_IP[pi], jp = P_JP[pi], kp = P_KP[pi];
    int di = DLT[ip], dj = DLT[jp];
    int xb = OFFT[ip], yb = OFFT[jp];
    __syncthreads();
    for (int idx = tid; idx < 1024; idx += 256)
      Wt[((idx & 31) << 5) + (idx >> 5)] = Wp[idx];
    __syncthreads();
    #pragma unroll
    for (int zz = 0; zz < 2; ++zz) {
      int z = zq + (zz << 3);
      const float* xr = &x_t[z * 288 + xb + u * di];
      const float* yrb = &x_t[z * 288 + yb];
      for (int v = 0; v < 32; ++v) {
        float wv = Wt[(v << 5) + u];
        const float* yr = yrb + v * dj;
        if (kp == 0) {
          float t = 0.f;
          for (int n = PKo[pi][0]; n < PKo[pi][1]; ++n) t += xr[NZ_I[n]] * yr[NZ_J[n]] * NZ_V[n];
          acc0[zz] += wv * t;
        } else {
          float t;
          t = 0.f; for (int n = PKo[pi][0]; n < PKo[pi][1]; ++n) t += xr[NZ_I[n]] * yr[NZ_J[n]] * NZ_V[n];
          acc2[zz][0] += wv * t;
          t = 0.f; for (int n = PKo[pi][1]; n < PKo[pi][2]; ++n) t += xr[NZ_I[n]] * yr[NZ_J[n]] * NZ_V[n];
          acc2[zz][1] += wv * t;
          t = 0.f; for (int n = PKo[pi][2]; n < PKo[pi][3]; ++n) t += xr[NZ_I[n]] * yr[NZ_J[n]] * NZ_V[n];
          acc2[zz][2] += wv * t;
          t = 0.f; for (int n = PKo[pi][3]; n < PKo[pi][4]; ++n) t += xr[NZ_I[n]] * yr[NZ_J[n]] * NZ_V[n];
          acc2[zz][3] += wv * t;
          t = 0.f; for (int n = PKo[pi][4]; n < PKo[pi][5]; ++n) t += xr[NZ_I[n]] * yr[NZ_J[n]] * NZ_V[n];
          acc2[zz][4] += wv * t;
        }
      }
    }
  }
  #pragma unroll
  for (int zz = 0; zz < 2; ++zz) {
    int zg = z0 + zq + (zz << 3);
    float* orow = out + zg * 288;
    orow[u] += INV_SQM * acc0[zz];
    #pragma unroll
    for (int kk = 0; kk < 5; ++kk) orow[128 + u * 5 + kk] += INV_SQM * acc2[zz][kk];
  }
}

// ---------- final lin chains + self connection ----------
__device__ __forceinline__ void lin_row(float* dst, const float* src, const float* Wm, int w)
{
  {
    float s = 0.f;
    for (int u = 0; u < 32; ++u) s += src[u] * Wm[(u << 5) + w];
    dst[w] = s * INV_SQM;
  }
  #pragma unroll
  for (int i = 0; i < 3; ++i) {
    float s = 0.f;
    for (int u = 0; u < 32; ++u) s += src[32 + u * 3 + i] * Wm[1024 + (u << 5) + w];
    dst[32 + w * 3 + i] = s * INV_SQM;
  }
  #pragma unroll
  for (int i = 0; i < 5; ++i) {
    float s = 0.f;
    for (int u = 0; u < 32; ++u) s += src[128 + u * 5 + i] * Wm[2048 + (u << 5) + w];
    dst[128 + w * 5 + i] = s * INV_SQM;
  }
}

__device__ __forceinline__ void lin_acc(float* msg, const float* src, const float* Wm, int w)
{
  {
    float s = 0.f;
    for (int u = 0; u < 32; ++u) s += src[u] * Wm[(u << 5) + w];
    msg[0] += s * INV_SQM;
  }
  #pragma unroll
  for (int i = 0; i < 3; ++i) {
    float s = 0.f;
    for (int u = 0; u < 32; ++u) s += src[32 + u * 3 + i] * Wm[1024 + (u << 5) + w];
    msg[1 + i] += s * INV_SQM;
  }
  #pragma unroll
  for (int i = 0; i < 5; ++i) {
    float s = 0.f;
    for (int u = 0; u < 32; ++u) s += src[128 + u * 5 + i] * Wm[2048 + (u << 5) + w];
    msg[4 + i] += s * INV_SQM;
  }
}

__global__ __launch_bounds__(256) void k_finalize(
    const float* __restrict__ a, const float* __restrict__ b2, const float* __restrict__ b3,
    const float* __restrict__ selfc, const float* __restrict__ lin_o1,
    const float* __restrict__ mix_w, const float* __restrict__ comb_w,
    float* __restrict__ out)
{
  __shared__ float bufA[8 * 288];
  __shared__ float bufB[8 * 288];
  int tid = threadIdx.x;
  int w = tid & 31, zl = tid >> 5;
  int z = blockIdx.x * 8 + zl;
  float msg[9];
  #pragma unroll
  for (int s = 0; s < 9; ++s) msg[s] = 0.f;
  float* rowA = &bufA[zl * 288];
  float* rowB = &bufB[zl * 288];
  lin_row(rowA, a + z * 288, lin_o1, w);
  __syncthreads();
  lin_row(rowB, rowA, mix_w, w);
  __syncthreads();
  lin_acc(msg, rowB, comb_w, w);
  __syncthreads();
  lin_row(rowA, b2 + z * 288, mix_w + 3072, w);
  __syncthreads();
  lin_acc(msg, rowA, comb_w + 3072, w);
  __syncthreads();
  lin_row(rowA, b3 + z * 288, mix_w + 6144, w);
  __syncthreads();
  lin_acc(msg, rowA, comb_w + 6144, w);

  float sc = selfc[(z << 5) + w];
  float* orow = out + z * 288;
  orow[w] = msg[0] + sc;
  #pragma unroll
  for (int i = 0; i < 3; ++i) orow[32 + w * 3 + i] = msg[1 + i];
  #pragma unroll
  for (int i = 0; i < 5; ++i) orow[128 + w * 5 + i] = msg[4 + i];
}

extern "C" void kernel_launch(void* const* d_in, const int* in_sizes, int n_in,
                              void* d_out, int out_size, void* d_ws, size_t ws_size,
                              hipStream_t stream)
{
  (void)in_sizes; (void)n_in; (void)out_size; (void)ws_size;
  const float* nf   = (const float*)d_in[0];
  const int*   ei   = (const int*)d_in[1];
  const float* sh   = (const float*)d_in[2];
  const float* re   = (const float*)d_in[3];
  const float* ea   = (const float*)d_in[4];
  const float* rw1  = (const float*)d_in[5];
  const float* rb1  = (const float*)d_in[6];
  const float* rw2  = (const float*)d_in[7];
  const float* rb2  = (const float*)d_in[8];
  const float* rw3  = (const float*)d_in[9];
  const float* rb3  = (const float*)d_in[10];
  const float* aw   = (const float*)d_in[11];
  const float* ab   = (const float*)d_in[12];
  const float* embw = (const float*)d_in[13];
  const float* lino1= (const float*)d_in[14];
  const float* o2uvw= (const float*)d_in[15];
  const float* o2uvu= (const float*)d_in[16];
  const float* o3a  = (const float*)d_in[17];
  const float* o3b  = (const float*)d_in[18];
  const float* mixw = (const float*)d_in[19];
  const float* combw= (const float*)d_in[20];
  const float* selfw= (const float*)d_in[21];
  float* out = (float*)d_out;
  float* ws  = (float*)d_ws;

  // workspace layout (floats). High-water mark = 10,915,600 floats
  // (43,662,400 B) == R3's proven-safe footprint. R4/R5 appended bthi/btlo
  // past wt_o3b (44.1/44.5 MB) and failed with a precision-INDEPENDENT,
  // bit-identical absmax — diagnosed as ws overflow clipping Bt. Fix:
  // bthi/btlo alias the cint region (dead until k_pairwise o3a, which runs
  // after k_edge_mfma has consumed them).
  float* h     = ws;                // 320000
  float* selfc = ws + 320000;       // 320000
  float* rfb   = ws + 640000;       // 4096000  (rf; reused as b2 afterwards)
  float* a     = ws + 4736000;      // 2880000
  float* cnt   = ws + 7616000;      // 10000
  float* cint  = ws + 7626000;      // 2880000  (b3 computed in-place)
  float* b2 = rfb;
  float* b3 = cint;
  unsigned short* wt_o2  = (unsigned short*)(ws + 10506000); //  98304 ush
  unsigned short* wt_o3a = wt_o2 + 98304;                    // 360448 ush
  unsigned short* wt_o3b = wt_o3a + 360448;                  // 360448 ush -> ends at float 10915600
  unsigned short* bthi   = (unsigned short*)cint;            // 199680 ush (96 x 2080), aliases cint
  unsigned short* btlo   = bthi + 199680;                    // 199680 ush, still inside cint (399360 ush = 199680 floats << 2880000)

  hipMemsetAsync(a, 0, (2880000 + 10000) * sizeof(float), stream);
  k_prepb<<<96, 256, 0, stream>>>(aw, ab, bthi, btlo);
  k_prepw<<<96, 256, 0, stream>>>(o2uvw, wt_o2);
  k_prepw<<<352, 256, 0, stream>>>(o3a, wt_o3a);
  k_prepw<<<352, 256, 0, stream>>>(o3b, wt_o3b);
  k_embed<<<1250, 256, 0, stream>>>(nf, embw, selfw, h, selfc);
  k_radial<<<2000, 256, 0, stream>>>(re, ea, rw1, rb1, rw2, rb2, rw3, rb3, rfb);
  k_edge_mfma<<<500, 256, 0, stream>>>(rfb, h, ei, sh, bthi, btlo, a, cnt);
  k_div<<<10000, 256, 0, stream>>>(a, cnt);
  k_pairwise_mfma<1><<<625, 256, 0, stream>>>(a, a, wt_o2, b2, INV_MUL);
  k_uvu<<<625, 256, 0, stream>>>(a, o2uvu, b2);
  k_pairwise_mfma<0><<<625, 256, 0, stream>>>(a, a, wt_o3a, cint, INV_MUL);
  k_pairwise_mfma<0><<<625, 256, 0, stream>>>(cint, a, wt_o3b, b3, INV_MUL);
  k_finalize<<<1250, 256, 0, stream>>>(a, b2, b3, selfc, lino1, mixw, combw, out);
}

// Round 7
// 1088.102 us; speedup vs baseline: 5.9920x; 1.3281x over previous
//
#include <hip/hip_runtime.h>

#define NN 10000
#define NE 64000
#define INV_SQM 0.17677669529663687f   // 1/sqrt(32)
#define INV_MUL 0.03125f               // 1/32

typedef __attribute__((ext_vector_type(8))) short bfrag;   // 8 bf16 (4 VGPRs)
typedef __attribute__((ext_vector_type(4))) float ffrag;   // 4 fp32 acc

__device__ __forceinline__ short f2bf(float f) {
  unsigned u = __float_as_uint(f);
  unsigned r = (u + 0x7FFFu + ((u >> 16) & 1u)) >> 16;  // RNE
  return (short)r;
}

// ---------- compile-time Clebsch-Gordan sparse tables ----------
constexpr int cIP[11] = {0,0,0,1,1,1,1,2,2,2,2};
constexpr int cJP[11] = {0,1,2,0,1,1,2,0,1,2,2};
constexpr int cKP[11] = {0,1,2,1,0,2,1,2,1,0,2};
constexpr int cKo[11][6] = {
  {0,1,1,1,1,1},{1,2,3,4,4,4},{4,5,6,7,8,9},{9,10,11,12,12,12},
  {12,15,15,15,15,15},{15,17,19,22,24,26},{26,30,34,37,37,37},
  {37,38,39,40,41,42},{42,46,50,53,53,53},{53,58,58,58,58,58},
  {58,62,68,73,79,83}};
constexpr int cDL[3]  = {1,3,5};
constexpr int cOF[3]  = {0,32,128};
constexpr int cNI[83] = {
  0, 0,0,0, 0,0,0,0,0, 0,1,2, 0,1,2,
  0,1,1,2,0,1,2,0,2,0,1,
  1,0,2,0,0,2,1,1,1,2,0,
  0,1,2,3,4,
  0,2,3,4,0,1,2,4,1,2,3,
  0,1,2,3,4,
  0,2,1,3,0,3,1,2,1,4,0,1,2,3,4,0,1,2,3,3,4,1,2,4,3};
constexpr int cNJ[83] = {
  0, 0,1,2, 0,1,2,3,4, 0,0,0, 0,1,2,
  1,0,2,1,0,1,2,2,0,0,1,
  0,2,3,4,0,1,2,4,1,2,3,
  0,0,0,0,0,
  1,0,2,0,0,2,1,1,1,2,0,
  0,1,2,3,4,
  2,0,3,1,3,0,2,1,4,1,0,1,2,3,4,1,0,3,2,4,3,1,4,2,3};
constexpr float cNV[83] = {
  1.0f,
  0.57735027f,0.57735027f,0.57735027f,
  0.44721360f,0.44721360f,0.44721360f,0.44721360f,0.44721360f,
  0.57735027f,0.57735027f,0.57735027f,
  0.57735027f,0.57735027f,0.57735027f,
  0.31622777f,0.31622777f,0.31622777f,0.31622777f,-0.18257419f,-0.18257419f,
  0.36514837f,0.31622777f,0.31622777f,0.31622777f,-0.31622777f,
  0.31622777f,-0.18257419f,0.31622777f,0.31622777f,0.31622777f,0.31622777f,
  -0.18257419f,-0.31622777f,0.31622777f,0.36514837f,0.31622777f,
  0.44721360f,0.44721360f,0.44721360f,0.44721360f,0.44721360f,
  0.31622777f,-0.18257419f,0.31622777f,0.31622777f,0.31622777f,0.31622777f,
  -0.18257419f,-0.31622777f,0.31622777f,0.36514837f,0.31622777f,
  0.44721360f,0.44721360f,0.44721360f,0.44721360f,0.44721360f,
  -0.23904572f,-0.23904572f,0.20702483f,0.20702483f,
  0.20702483f,0.20702483f,0.11952286f,0.11952286f,-0.20702483f,-0.20702483f,
  -0.23904572f,0.11952286f,0.23904572f,0.11952286f,-0.23904572f,
  0.20702483f,0.20702483f,0.11952286f,0.11952286f,0.20702483f,0.20702483f,
  -0.20702483f,-0.23904572f,-0.23904572f,0.20702483f};

// ---------- h = nf@emb_w/SQM ; selfc = nf@self_w/SQM ----------
__global__ __launch_bounds__(256) void k_embed(const float* __restrict__ nf,
    const float* __restrict__ emb_w, const float* __restrict__ self_w,
    float* __restrict__ h, float* __restrict__ selfc)
{
  __shared__ float We[1024], Wsf[1024];
  int tid = threadIdx.x;
  for (int i = tid; i < 1024; i += 256) { We[i] = emb_w[i]; Wsf[i] = self_w[i]; }
  __syncthreads();
  int z = blockIdx.x * 8 + (tid >> 5);
  int u = tid & 31;
  if (z >= NN) return;
  const float* row = nf + z * 32;
  float ah = 0.f, as = 0.f;
  #pragma unroll 8
  for (int v = 0; v < 32; ++v) {
    float xv = row[v];
    ah += xv * We[(v << 5) + u];
    as += xv * Wsf[(v << 5) + u];
  }
  h[(z << 5) + u]     = ah * INV_SQM;
  selfc[(z << 5) + u] = as * INV_SQM;
}

// ---------- per-edge radial MLP -> rf[64], 32 edges/block ----------
__global__ __launch_bounds__(256) void k_radial(
    const float* __restrict__ re, const float* __restrict__ ea,
    const float* __restrict__ w1, const float* __restrict__ b1,
    const float* __restrict__ w2, const float* __restrict__ b2,
    const float* __restrict__ w3, const float* __restrict__ b3,
    float* __restrict__ rf)
{
  __shared__ float W1[24 * 64];
  __shared__ float W2[64 * 64];
  __shared__ float W3[64 * 64];
  __shared__ float rin[32][25];
  __shared__ float t1[32][65], t2[32][65];
  int t = threadIdx.x;
  for (int i = t; i < 24 * 64; i += 256) W1[i] = w1[i];
  for (int i = t; i < 4096; i += 256) { W2[i] = w2[i]; W3[i] = w3[i]; }
  int e0 = blockIdx.x * 32;
  for (int idx = t; idx < 768; idx += 256) {
    int el = idx / 24, i = idx - el * 24;
    int e = e0 + el;
    rin[el][i] = (i < 8) ? re[e * 8 + i] : ea[e * 16 + (i - 8)];
  }
  __syncthreads();
  #pragma unroll
  for (int g = 0; g < 8; ++g) {
    int idx = g * 256 + t, el = idx >> 6, o = idx & 63;
    float acc = b1[o];
    #pragma unroll 8
    for (int i = 0; i < 24; ++i) acc += rin[el][i] * W1[i * 64 + o];
    t1[el][o] = acc / (1.f + __expf(-acc));
  }
  __syncthreads();
  #pragma unroll
  for (int g = 0; g < 8; ++g) {
    int idx = g * 256 + t, el = idx >> 6, o = idx & 63;
    float acc = b2[o];
    #pragma unroll 8
    for (int c = 0; c < 64; ++c) acc += t1[el][c] * W2[(c << 6) + o];
    t2[el][o] = acc / (1.f + __expf(-acc));
  }
  __syncthreads();
  #pragma unroll
  for (int g = 0; g < 8; ++g) {
    int idx = g * 256 + t, el = idx >> 6, o = idx & 63;
    float acc = b3[o];
    #pragma unroll 8
    for (int c = 0; c < 64; ++c) acc += t2[el][c] * W3[(c << 6) + o];
    rf[(e0 + el) * 64 + o] = acc;
  }
}

// ---------- Bt hi/lo split (3xBF16 scheme) ----------
__global__ __launch_bounds__(256) void k_prepb(const float* __restrict__ aw,
    const float* __restrict__ ab, unsigned short* __restrict__ Bthi,
    unsigned short* __restrict__ Btlo)
{
  int n = blockIdx.x;          // 0..95
  int l = n >> 5, w = n & 31;
  for (int k = threadIdx.x; k < 2080; k += 256) {
    float v = (k < 2048) ? aw[(k >> 5) * 3072 + l * 1024 + (k & 31) * 32 + w]
                         : ab[l * 1024 + (k - 2048) * 32 + w];
    unsigned u = __float_as_uint(v);
    float hif = __uint_as_float(u & 0xffff0000u);
    float lo = v - hif;
    Bthi[n * 2080 + k] = (unsigned short)(u >> 16);
    Btlo[n * 2080 + k] = (unsigned short)(__float_as_uint(lo) >> 16);
  }
}

// ---------- edge GEMM on MFMA (split-precision) + fused scatter ----------
__global__ __launch_bounds__(256, 2) void k_edge_mfma(
    const float* __restrict__ rf, const float* __restrict__ h,
    const int* __restrict__ ei, const float* __restrict__ sh,
    const unsigned short* __restrict__ Bthi, const unsigned short* __restrict__ Btlo,
    float* __restrict__ aout, float* __restrict__ cnt)
{
  __shared__ float rf_s[128 * 65];   // pad 65 -> conflict-free column reads
  __shared__ float sh_s[128 * 9];
  __shared__ int dst_s[128];
  __shared__ int src_s[128];
  int tid = threadIdx.x;
  int e0 = blockIdx.x * 128;
  for (int idx = tid; idx < 128 * 64; idx += 256) {
    int e = idx >> 6, c = idx & 63;
    rf_s[e * 65 + c] = rf[(e0 + e) * 64 + c];
  }
  for (int idx = tid; idx < 128 * 9; idx += 256) {
    int e = idx / 9, i = idx - e * 9;
    sh_s[idx] = sh[(e0 + e) * 9 + i];
  }
  if (tid < 128) { src_s[tid] = ei[e0 + tid]; dst_s[tid] = ei[NE + e0 + tid]; }
  __syncthreads();

  int lane = tid & 63, wave = tid >> 6;
  int col = lane & 15, quad = lane >> 4;
  int eA = wave * 32 + col;          // m-tile 0 local edge (row = col in A)
  int eB = eA + 16;                  // m-tile 1
  const float* hpA = h + src_s[eA] * 32 + quad * 8;
  const float* hpB = h + src_s[eB] * 32 + quad * 8;
  float4 a0 = *(const float4*)hpA, a1 = *(const float4*)(hpA + 4);
  float4 b0 = *(const float4*)hpB, b1 = *(const float4*)(hpB + 4);
  float ha[8] = {a0.x, a0.y, a0.z, a0.w, a1.x, a1.y, a1.z, a1.w};
  float hb[8] = {b0.x, b0.y, b0.z, b0.w, b1.x, b1.y, b1.z, b1.w};

  ffrag acc[2][6] = {};
  const unsigned short* bhib = Bthi + col * 2080 + quad * 8;
  const unsigned short* blob = Btlo + col * 2080 + quad * 8;

  for (int s = 0; s < 65; ++s) {        // s==64: bias block (ko=2048), r=1
    float rA = (s < 64) ? rf_s[eA * 65 + s] : 1.0f;
    float rB = (s < 64) ? rf_s[eB * 65 + s] : 1.0f;
    bfrag hA, lA, hB, lB;
    #pragma unroll
    for (int j = 0; j < 8; ++j) {
      float gA = rA * ha[j];
      unsigned uA = __float_as_uint(gA);
      hA[j] = (short)(uA >> 16);
      float loA = gA - __uint_as_float(uA & 0xffff0000u);
      lA[j] = (short)(__float_as_uint(loA) >> 16);
      float gB = rB * hb[j];
      unsigned uB = __float_as_uint(gB);
      hB[j] = (short)(uB >> 16);
      float loB = gB - __uint_as_float(uB & 0xffff0000u);
      lB[j] = (short)(__float_as_uint(loB) >> 16);
    }
    int ko = s << 5;
    #pragma unroll
    for (int t = 0; t < 6; ++t) {
      bfrag bh = *(const bfrag*)(bhib + t * 16 * 2080 + ko);
      bfrag bl = *(const bfrag*)(blob + t * 16 * 2080 + ko);
      acc[0][t] = __builtin_amdgcn_mfma_f32_16x16x32_bf16(hA, bh, acc[0][t], 0, 0, 0);
      acc[1][t] = __builtin_amdgcn_mfma_f32_16x16x32_bf16(hB, bh, acc[1][t], 0, 0, 0);
      acc[0][t] = __builtin_amdgcn_mfma_f32_16x16x32_bf16(lA, bh, acc[0][t], 0, 0, 0);
      acc[1][t] = __builtin_amdgcn_mfma_f32_16x16x32_bf16(lB, bh, acc[1][t], 0, 0, 0);
      acc[0][t] = __builtin_amdgcn_mfma_f32_16x16x32_bf16(hA, bl, acc[0][t], 0, 0, 0);
      acc[1][t] = __builtin_amdgcn_mfma_f32_16x16x32_bf16(hB, bl, acc[1][t], 0, 0, 0);
    }
  }

  if (tid < 128) atomicAdd(&cnt[dst_s[tid]], 1.0f);
  #pragma unroll
  for (int mt = 0; mt < 2; ++mt) {
    #pragma unroll
    for (int r = 0; r < 4; ++r) {
      int el = wave * 32 + mt * 16 + quad * 4 + r;
      float* arow = aout + dst_s[el] * 288;
      const float* shp = &sh_s[el * 9];
      #pragma unroll
      for (int t = 0; t < 6; ++t) {
        int l = t >> 1;
        int w = ((t & 1) << 4) + col;
        float v = acc[mt][t][r] * INV_SQM;
        if (l == 0) {
          atomicAdd(&arow[w], v * shp[0]);
        } else if (l == 1) {
          #pragma unroll
          for (int i = 0; i < 3; ++i)
            atomicAdd(&arow[32 + w * 3 + i], v * shp[1 + i] * 0.57735027f);
        } else {
          #pragma unroll
          for (int i = 0; i < 5; ++i)
            atomicAdd(&arow[128 + w * 5 + i], v * shp[4 + i] * 0.44721360f);
        }
      }
    }
  }
}

// ---------- a /= max(cnt,1) ----------
__global__ __launch_bounds__(256) void k_div(float* __restrict__ a, const float* __restrict__ cnt)
{
  int z = blockIdx.x;
  float inv = 1.0f / fmaxf(cnt[z], 1.0f);
  for (int c = threadIdx.x; c < 288; c += 256) a[z * 288 + c] *= inv;
}

// ---------- W[p][u][v][w] f32  ->  Wt[p][u][w][v] bf16 (one (p,u) slice/block) ----------
__global__ __launch_bounds__(256) void k_prepw(const float* __restrict__ W,
                                               unsigned short* __restrict__ Wt)
{
  __shared__ float buf[32 * 33];
  int tid = threadIdx.x;
  long base = (long)blockIdx.x * 1024;
  #pragma unroll
  for (int it = 0; it < 4; ++it) {
    int idx = it * 256 + tid;
    int w = idx & 31, v = idx >> 5;
    buf[w * 33 + v] = W[base + v * 32 + w];
  }
  __syncthreads();
  unsigned* out32 = (unsigned*)(Wt + base);
  #pragma unroll
  for (int it = 0; it < 2; ++it) {
    int idx = it * 256 + tid;
    int w = idx >> 4, vp = idx & 15;
    float f0 = buf[w * 33 + vp * 2], f1 = buf[w * 33 + vp * 2 + 1];
    unsigned pk = (unsigned)(unsigned short)f2bf(f0) |
                  ((unsigned)(unsigned short)f2bf(f1) << 16);
    out32[w * 16 + vp] = pk;
  }
}

// ---------- one TP path on MFMA ----------
template<int PI, int WIDX>
__device__ __forceinline__ void process_path(const float* __restrict__ x_s,
    const float* __restrict__ y_s, const unsigned short* __restrict__ wt,
    int lane, int wave, ffrag acc[9][2])
{
  constexpr int ip = cIP[PI], jp = cJP[PI], kp = cKP[PI];
  constexpr int di = cDL[ip], dj = cDL[jp], dk = cDL[kp];
  constexpr int xb = cOF[ip], yb = cOF[jp];
  constexpr int ks0 = (kp == 0) ? 0 : ((kp == 1) ? 1 : 4);
  constexpr int nA = cKo[PI][0];
  constexpr int nB = cKo[PI][dk];
  const int z = lane & 15, quad = lane >> 4;

  float yreg[8][dj];
  #pragma unroll
  for (int vi = 0; vi < 8; ++vi)
    #pragma unroll
    for (int j = 0; j < dj; ++j)
      yreg[vi][j] = y_s[z * 292 + yb + (quad * 8 + vi) * dj + j];

  for (int uu = 0; uu < 8; ++uu) {
    int u = wave * 8 + uu;
    const unsigned short* wb = wt + (((WIDX * 32 + u) * 32) << 5) + quad * 8;
    bfrag b0 = *(const bfrag*)(wb + (z << 5));          // w = lane&15
    bfrag b1 = *(const bfrag*)(wb + ((16 + z) << 5));   // w = 16 + lane&15
    float xv[di];
    #pragma unroll
    for (int i = 0; i < di; ++i) xv[i] = x_s[z * 292 + xb + u * di + i];
    float xc[nB - nA];
    #pragma unroll
    for (int n = nA; n < nB; ++n) xc[n - nA] = xv[cNI[n]] * cNV[n];
    bfrag fa[dk];
    #pragma unroll
    for (int vi = 0; vi < 8; ++vi) {
      float T[dk];
      #pragma unroll
      for (int k = 0; k < dk; ++k) T[k] = 0.f;
      #pragma unroll
      for (int k = 0; k < dk; ++k)
        #pragma unroll
        for (int n = cKo[PI][k]; n < cKo[PI][k + 1]; ++n)
          T[k] += xc[n - nA] * yreg[vi][cNJ[n]];
      #pragma unroll
      for (int k = 0; k < dk; ++k) fa[k][vi] = f2bf(T[k]);
    }
    #pragma unroll
    for (int k = 0; k < dk; ++k) {
      acc[ks0 + k][0] = __builtin_amdgcn_mfma_f32_16x16x32_bf16(fa[k], b0, acc[ks0 + k][0], 0, 0, 0);
      acc[ks0 + k][1] = __builtin_amdgcn_mfma_f32_16x16x32_bf16(fa[k], b1, acc[ks0 + k][1], 0, 0, 0);
    }
  }
}

// MODE 0: all 11 paths (o3a/o3b). MODE 1: o2_uvw paths {1,2,6}.
template<int MODE>
__global__ __launch_bounds__(256, 2) void k_pairwise_mfma(
    const float* __restrict__ x, const float* __restrict__ y,
    const unsigned short* __restrict__ wt, float* __restrict__ out, float scale)
{
  __shared__ float smem[9504];        // x_s[16*292] | y_s[16*292]; 2 red slices of 4752
  float* x_s = smem;
  float* y_s = smem + 4672;
  int tid = threadIdx.x;
  int z0 = blockIdx.x * 16;
  for (int idx = tid; idx < 16 * 72; idx += 256) {
    int r = idx / 72, f = (idx - r * 72) * 4;
    *(float4*)&x_s[r * 292 + f] = *(const float4*)&x[(z0 + r) * 288 + f];
    *(float4*)&y_s[r * 292 + f] = *(const float4*)&y[(z0 + r) * 288 + f];
  }
  __syncthreads();
  int lane = tid & 63, wave = tid >> 6;
  ffrag acc[9][2] = {};

  if constexpr (MODE == 0) {
    process_path<0, 0>(x_s, y_s, wt, lane, wave, acc);
    process_path<1, 1>(x_s, y_s, wt, lane, wave, acc);
    process_path<2, 2>(x_s, y_s, wt, lane, wave, acc);
    process_path<3, 3>(x_s, y_s, wt, lane, wave, acc);
    process_path<4, 4>(x_s, y_s, wt, lane, wave, acc);
    process_path<5, 5>(x_s, y_s, wt, lane, wave, acc);
    process_path<6, 6>(x_s, y_s, wt, lane, wave, acc);
    process_path<7, 7>(x_s, y_s, wt, lane, wave, acc);
    process_path<8, 8>(x_s, y_s, wt, lane, wave, acc);
    process_path<9, 9>(x_s, y_s, wt, lane, wave, acc);
    process_path<10, 10>(x_s, y_s, wt, lane, wave, acc);
  } else {
    process_path<1, 0>(x_s, y_s, wt, lane, wave, acc);
    process_path<2, 1>(x_s, y_s, wt, lane, wave, acc);
    process_path<6, 2>(x_s, y_s, wt, lane, wave, acc);
  }

  // ---- deterministic cross-wave reduction: (w0 + w2) + (w1 + w3) ----
  float* slice0 = smem;          // 4752 floats, row stride 33
  float* slice1 = smem + 4752;   // 4752 floats
  int n15 = lane & 15, quad = lane >> 4;
  __syncthreads();
  if (wave >= 2) {
    float* sl = (wave == 2) ? slice0 : slice1;
    #pragma unroll
    for (int s = 0; s < 9; ++s)
      #pragma unroll
      for (int wh = 0; wh < 2; ++wh)
        #pragma unroll
        for (int r = 0; r < 4; ++r)
          sl[(s * 16 + quad * 4 + r) * 33 + wh * 16 + n15] = acc[s][wh][r];
  }
  __syncthreads();
  if (wave < 2) {
    float* sl = (wave == 0) ? slice0 : slice1;
    #pragma unroll
    for (int s = 0; s < 9; ++s)
      #pragma unroll
      for (int wh = 0; wh < 2; ++wh)
        #pragma unroll
        for (int r = 0; r < 4; ++r)
          acc[s][wh][r] += sl[(s * 16 + quad * 4 + r) * 33 + wh * 16 + n15];
  }
  __syncthreads();
  if (wave == 1) {
    #pragma unroll
    for (int s = 0; s < 9; ++s)
      #pragma unroll
      for (int wh = 0; wh < 2; ++wh)
        #pragma unroll
        for (int r = 0; r < 4; ++r)
          slice1[(s * 16 + quad * 4 + r) * 33 + wh * 16 + n15] = acc[s][wh][r];
  }
  __syncthreads();
  if (wave == 0) {
    #pragma unroll
    for (int s = 0; s < 9; ++s)
      #pragma unroll
      for (int wh = 0; wh < 2; ++wh)
        #pragma unroll
        for (int r = 0; r < 4; ++r) {
          int o = (s * 16 + quad * 4 + r) * 33 + wh * 16 + n15;
          slice0[o] = acc[s][wh][r] + slice1[o];
        }
  }
  __syncthreads();
  for (int idx = tid; idx < 4608; idx += 256) {
    int w = idx & 31, rest = idx >> 5;
    int zz = rest & 15, ks = rest >> 4;
    int c = (ks == 0) ? w : (ks < 4 ? 32 + w * 3 + (ks - 1) : 128 + w * 5 + (ks - 4));
    out[(z0 + zz) * 288 + c] = scale * slice0[(ks * 16 + zz) * 33 + w];
  }
}

// ---------- uvu part of order2: compile-time templated paths ----------
// R6 post-mortem: runtime PKo/NZ_* indexing serialized on lgkmcnt (443 us,
// VALUBusy 14%). Templating makes indices/coeffs immediates and unrolls the
// nnz loops into straight-line FMAs over unrolled ds_reads.
template<int PI>
__device__ __forceinline__ void uvu_path(const float* __restrict__ x_t,
    const float* __restrict__ Wg, int u, int zq, float acc0[2], float acc2[2][5])
{
  constexpr int ip = cIP[PI], jp = cJP[PI], kp = cKP[PI];
  constexpr int di = cDL[ip], dj = cDL[jp], dk = cDL[kp];
  constexpr int xb = cOF[ip], yb = cOF[jp];
  constexpr int nA = cKo[PI][0];
  constexpr int nB = cKo[PI][dk];
  float wrow[32];
  #pragma unroll
  for (int vq = 0; vq < 8; ++vq)
    *(float4*)&wrow[vq * 4] = *(const float4*)&Wg[u * 32 + vq * 4];
  #pragma unroll
  for (int zz = 0; zz < 2; ++zz) {
    int z = zq + (zz << 3);
    float xv[di];
    #pragma unroll
    for (int i = 0; i < di; ++i) xv[i] = x_t[z * 288 + xb + u * di + i];
    float xc[nB - nA];
    #pragma unroll
    for (int n = nA; n < nB; ++n) xc[n - nA] = xv[cNI[n]] * cNV[n];
    const float* yrb = &x_t[z * 288 + yb];
    #pragma unroll 8
    for (int v = 0; v < 32; ++v) {
      float yv[dj];
      #pragma unroll
      for (int j = 0; j < dj; ++j) yv[j] = yrb[v * dj + j];
      float wv = wrow[v];
      if constexpr (kp == 0) {
        float t = 0.f;
        #pragma unroll
        for (int n = nA; n < nB; ++n) t += xc[n - nA] * yv[cNJ[n]];
        acc0[zz] += wv * t;
      } else {
        #pragma unroll
        for (int k = 0; k < 5; ++k) {
          float t = 0.f;
          #pragma unroll
          for (int n = cKo[PI][k]; n < cKo[PI][k + 1]; ++n)
            t += xc[n - nA] * yv[cNJ[n]];
          acc2[zz][k] += wv * t;
        }
      }
    }
  }
}

__global__ __launch_bounds__(256) void k_uvu(
    const float* __restrict__ x, const float* __restrict__ W, float* __restrict__ out)
{
  __shared__ __align__(16) float x_t[16 * 288];
  int tid = threadIdx.x;
  int z0 = blockIdx.x * 16;
  for (int idx = tid; idx < 16 * 72; idx += 256) {
    int r = idx / 72, f = idx - r * 72;
    *(float4*)&x_t[r * 288 + f * 4] = *(const float4*)&x[(z0 + r) * 288 + f * 4];
  }
  __syncthreads();
  int u = tid & 31, zq = tid >> 5;
  float acc0[2] = {0.f, 0.f};
  float acc2[2][5] = {};
  uvu_path<0>(x_t, W,            u, zq, acc0, acc2);   // PL_UVU order {0,4,5,9,10}
  uvu_path<4>(x_t, W + 1 * 1024, u, zq, acc0, acc2);
  uvu_path<5>(x_t, W + 2 * 1024, u, zq, acc0, acc2);
  uvu_path<9>(x_t, W + 3 * 1024, u, zq, acc0, acc2);
  uvu_path<10>(x_t, W + 4 * 1024, u, zq, acc0, acc2);
  #pragma unroll
  for (int zz = 0; zz < 2; ++zz) {
    int zg = z0 + zq + (zz << 3);
    float* orow = out + zg * 288;
    orow[u] += INV_SQM * acc0[zz];
    #pragma unroll
    for (int kk = 0; kk < 5; ++kk) orow[128 + u * 5 + kk] += INV_SQM * acc2[zz][kk];
  }
}

// ---------- final lin chains + self connection ----------
__device__ __forceinline__ void lin_row(float* dst, const float* src, const float* Wm, int w)
{
  {
    float s = 0.f;
    for (int u = 0; u < 32; ++u) s += src[u] * Wm[(u << 5) + w];
    dst[w] = s * INV_SQM;
  }
  #pragma unroll
  for (int i = 0; i < 3; ++i) {
    float s = 0.f;
    for (int u = 0; u < 32; ++u) s += src[32 + u * 3 + i] * Wm[1024 + (u << 5) + w];
    dst[32 + w * 3 + i] = s * INV_SQM;
  }
  #pragma unroll
  for (int i = 0; i < 5; ++i) {
    float s = 0.f;
    for (int u = 0; u < 32; ++u) s += src[128 + u * 5 + i] * Wm[2048 + (u << 5) + w];
    dst[128 + w * 5 + i] = s * INV_SQM;
  }
}

__device__ __forceinline__ void lin_acc(float* msg, const float* src, const float* Wm, int w)
{
  {
    float s = 0.f;
    for (int u = 0; u < 32; ++u) s += src[u] * Wm[(u << 5) + w];
    msg[0] += s * INV_SQM;
  }
  #pragma unroll
  for (int i = 0; i < 3; ++i) {
    float s = 0.f;
    for (int u = 0; u < 32; ++u) s += src[32 + u * 3 + i] * Wm[1024 + (u << 5) + w];
    msg[1 + i] += s * INV_SQM;
  }
  #pragma unroll
  for (int i = 0; i < 5; ++i) {
    float s = 0.f;
    for (int u = 0; u < 32; ++u) s += src[128 + u * 5 + i] * Wm[2048 + (u << 5) + w];
    msg[4 + i] += s * INV_SQM;
  }
}

__global__ __launch_bounds__(256) void k_finalize(
    const float* __restrict__ a, const float* __restrict__ b2, const float* __restrict__ b3,
    const float* __restrict__ selfc, const float* __restrict__ lin_o1,
    const float* __restrict__ mix_w, const float* __restrict__ comb_w,
    float* __restrict__ out)
{
  __shared__ float bufA[8 * 288];
  __shared__ float bufB[8 * 288];
  int tid = threadIdx.x;
  int w = tid & 31, zl = tid >> 5;
  int z = blockIdx.x * 8 + zl;
  float msg[9];
  #pragma unroll
  for (int s = 0; s < 9; ++s) msg[s] = 0.f;
  float* rowA = &bufA[zl * 288];
  float* rowB = &bufB[zl * 288];
  lin_row(rowA, a + z * 288, lin_o1, w);
  __syncthreads();
  lin_row(rowB, rowA, mix_w, w);
  __syncthreads();
  lin_acc(msg, rowB, comb_w, w);
  __syncthreads();
  lin_row(rowA, b2 + z * 288, mix_w + 3072, w);
  __syncthreads();
  lin_acc(msg, rowA, comb_w + 3072, w);
  __syncthreads();
  lin_row(rowA, b3 + z * 288, mix_w + 6144, w);
  __syncthreads();
  lin_acc(msg, rowA, comb_w + 6144, w);

  float sc = selfc[(z << 5) + w];
  float* orow = out + z * 288;
  orow[w] = msg[0] + sc;
  #pragma unroll
  for (int i = 0; i < 3; ++i) orow[32 + w * 3 + i] = msg[1 + i];
  #pragma unroll
  for (int i = 0; i < 5; ++i) orow[128 + w * 5 + i] = msg[4 + i];
}

extern "C" void kernel_launch(void* const* d_in, const int* in_sizes, int n_in,
                              void* d_out, int out_size, void* d_ws, size_t ws_size,
                              hipStream_t stream)
{
  (void)in_sizes; (void)n_in; (void)out_size; (void)ws_size;
  const float* nf   = (const float*)d_in[0];
  const int*   ei   = (const int*)d_in[1];
  const float* sh   = (const float*)d_in[2];
  const float* re   = (const float*)d_in[3];
  const float* ea   = (const float*)d_in[4];
  const float* rw1  = (const float*)d_in[5];
  const float* rb1  = (const float*)d_in[6];
  const float* rw2  = (const float*)d_in[7];
  const float* rb2  = (const float*)d_in[8];
  const float* rw3  = (const float*)d_in[9];
  const float* rb3  = (const float*)d_in[10];
  const float* aw   = (const float*)d_in[11];
  const float* ab   = (const float*)d_in[12];
  const float* embw = (const float*)d_in[13];
  const float* lino1= (const float*)d_in[14];
  const float* o2uvw= (const float*)d_in[15];
  const float* o2uvu= (const float*)d_in[16];
  const float* o3a  = (const float*)d_in[17];
  const float* o3b  = (const float*)d_in[18];
  const float* mixw = (const float*)d_in[19];
  const float* combw= (const float*)d_in[20];
  const float* selfw= (const float*)d_in[21];
  float* out = (float*)d_out;
  float* ws  = (float*)d_ws;

  // workspace layout (floats). High-water mark = 10,915,600 floats
  // (43,662,400 B) — R3's proven-safe footprint. bthi/btlo alias the cint
  // region (dead until k_pairwise o3a, after k_edge_mfma consumed them).
  float* h     = ws;                // 320000
  float* selfc = ws + 320000;       // 320000
  float* rfb   = ws + 640000;       // 4096000  (rf; reused as b2 afterwards)
  float* a     = ws + 4736000;      // 2880000
  float* cnt   = ws + 7616000;      // 10000
  float* cint  = ws + 7626000;      // 2880000  (b3 computed in-place)
  float* b2 = rfb;
  float* b3 = cint;
  unsigned short* wt_o2  = (unsigned short*)(ws + 10506000); //  98304 ush
  unsigned short* wt_o3a = wt_o2 + 98304;                    // 360448 ush
  unsigned short* wt_o3b = wt_o3a + 360448;                  // 360448 ush -> ends at float 10915600
  unsigned short* bthi   = (unsigned short*)cint;            // 199680 ush, aliases cint
  unsigned short* btlo   = bthi + 199680;                    // 199680 ush, inside cint

  hipMemsetAsync(a, 0, (2880000 + 10000) * sizeof(float), stream);
  k_prepb<<<96, 256, 0, stream>>>(aw, ab, bthi, btlo);
  k_prepw<<<96, 256, 0, stream>>>(o2uvw, wt_o2);
  k_prepw<<<352, 256, 0, stream>>>(o3a, wt_o3a);
  k_prepw<<<352, 256, 0, stream>>>(o3b, wt_o3b);
  k_embed<<<1250, 256, 0, stream>>>(nf, embw, selfw, h, selfc);
  k_radial<<<2000, 256, 0, stream>>>(re, ea, rw1, rb1, rw2, rb2, rw3, rb3, rfb);
  k_edge_mfma<<<500, 256, 0, stream>>>(rfb, h, ei, sh, bthi, btlo, a, cnt);
  k_div<<<10000, 256, 0, stream>>>(a, cnt);
  k_pairwise_mfma<1><<<625, 256, 0, stream>>>(a, a, wt_o2, b2, INV_MUL);
  k_uvu<<<625, 256, 0, stream>>>(a, o2uvu, b2);
  k_pairwise_mfma<0><<<625, 256, 0, stream>>>(a, a, wt_o3a, cint, INV_MUL);
  k_pairwise_mfma<0><<<625, 256, 0, stream>>>(cint, a, wt_o3b, b3, INV_MUL);
  k_finalize<<<1250, 256, 0, stream>>>(a, b2, b3, selfc, lino1, mixw, combw, out);
}

// Round 8
// 961.128 us; speedup vs baseline: 6.7836x; 1.1321x over previous
//
#include <hip/hip_runtime.h>

#define NN 10000
#define NE 64000
#define INV_SQM 0.17677669529663687f   // 1/sqrt(32)
#define INV_MUL 0.03125f               // 1/32

typedef __attribute__((ext_vector_type(8))) short bfrag;   // 8 bf16 (4 VGPRs)
typedef __attribute__((ext_vector_type(4))) float ffrag;   // 4 fp32 acc

__device__ __forceinline__ short f2bf(float f) {
  unsigned u = __float_as_uint(f);
  unsigned r = (u + 0x7FFFu + ((u >> 16) & 1u)) >> 16;  // RNE
  return (short)r;
}

// ---------- compile-time Clebsch-Gordan sparse tables ----------
constexpr int cIP[11] = {0,0,0,1,1,1,1,2,2,2,2};
constexpr int cJP[11] = {0,1,2,0,1,1,2,0,1,2,2};
constexpr int cKP[11] = {0,1,2,1,0,2,1,2,1,0,2};
constexpr int cKo[11][6] = {
  {0,1,1,1,1,1},{1,2,3,4,4,4},{4,5,6,7,8,9},{9,10,11,12,12,12},
  {12,15,15,15,15,15},{15,17,19,22,24,26},{26,30,34,37,37,37},
  {37,38,39,40,41,42},{42,46,50,53,53,53},{53,58,58,58,58,58},
  {58,62,68,73,79,83}};
constexpr int cDL[3]  = {1,3,5};
constexpr int cOF[3]  = {0,32,128};
constexpr int cNI[83] = {
  0, 0,0,0, 0,0,0,0,0, 0,1,2, 0,1,2,
  0,1,1,2,0,1,2,0,2,0,1,
  1,0,2,0,0,2,1,1,1,2,0,
  0,1,2,3,4,
  0,2,3,4,0,1,2,4,1,2,3,
  0,1,2,3,4,
  0,2,1,3,0,3,1,2,1,4,0,1,2,3,4,0,1,2,3,3,4,1,2,4,3};
constexpr int cNJ[83] = {
  0, 0,1,2, 0,1,2,3,4, 0,0,0, 0,1,2,
  1,0,2,1,0,1,2,2,0,0,1,
  0,2,3,4,0,1,2,4,1,2,3,
  0,0,0,0,0,
  1,0,2,0,0,2,1,1,1,2,0,
  0,1,2,3,4,
  2,0,3,1,3,0,2,1,4,1,0,1,2,3,4,1,0,3,2,4,3,1,4,2,3};
constexpr float cNV[83] = {
  1.0f,
  0.57735027f,0.57735027f,0.57735027f,
  0.44721360f,0.44721360f,0.44721360f,0.44721360f,0.44721360f,
  0.57735027f,0.57735027f,0.57735027f,
  0.57735027f,0.57735027f,0.57735027f,
  0.31622777f,0.31622777f,0.31622777f,0.31622777f,-0.18257419f,-0.18257419f,
  0.36514837f,0.31622777f,0.31622777f,0.31622777f,-0.31622777f,
  0.31622777f,-0.18257419f,0.31622777f,0.31622777f,0.31622777f,0.31622777f,
  -0.18257419f,-0.31622777f,0.31622777f,0.36514837f,0.31622777f,
  0.44721360f,0.44721360f,0.44721360f,0.44721360f,0.44721360f,
  0.31622777f,-0.18257419f,0.31622777f,0.31622777f,0.31622777f,0.31622777f,
  -0.18257419f,-0.31622777f,0.31622777f,0.36514837f,0.31622777f,
  0.44721360f,0.44721360f,0.44721360f,0.44721360f,0.44721360f,
  -0.23904572f,-0.23904572f,0.20702483f,0.20702483f,
  0.20702483f,0.20702483f,0.11952286f,0.11952286f,-0.20702483f,-0.20702483f,
  -0.23904572f,0.11952286f,0.23904572f,0.11952286f,-0.23904572f,
  0.20702483f,0.20702483f,0.11952286f,0.11952286f,0.20702483f,0.20702483f,
  -0.20702483f,-0.23904572f,-0.23904572f,0.20702483f};

// ---------- h = nf@emb_w/SQM ; selfc = nf@self_w/SQM ----------
__global__ __launch_bounds__(256) void k_embed(const float* __restrict__ nf,
    const float* __restrict__ emb_w, const float* __restrict__ self_w,
    float* __restrict__ h, float* __restrict__ selfc)
{
  __shared__ float We[1024], Wsf[1024];
  int tid = threadIdx.x;
  for (int i = tid; i < 1024; i += 256) { We[i] = emb_w[i]; Wsf[i] = self_w[i]; }
  __syncthreads();
  int z = blockIdx.x * 8 + (tid >> 5);
  int u = tid & 31;
  if (z >= NN) return;
  const float* row = nf + z * 32;
  float ah = 0.f, as = 0.f;
  #pragma unroll 8
  for (int v = 0; v < 32; ++v) {
    float xv = row[v];
    ah += xv * We[(v << 5) + u];
    as += xv * Wsf[(v << 5) + u];
  }
  h[(z << 5) + u]     = ah * INV_SQM;
  selfc[(z << 5) + u] = as * INV_SQM;
}

// ---------- per-edge radial MLP -> rf[64], 32 edges/block ----------
__global__ __launch_bounds__(256) void k_radial(
    const float* __restrict__ re, const float* __restrict__ ea,
    const float* __restrict__ w1, const float* __restrict__ b1,
    const float* __restrict__ w2, const float* __restrict__ b2,
    const float* __restrict__ w3, const float* __restrict__ b3,
    float* __restrict__ rf)
{
  __shared__ float W1[24 * 64];
  __shared__ float W2[64 * 64];
  __shared__ float W3[64 * 64];
  __shared__ float rin[32][25];
  __shared__ float t1[32][65], t2[32][65];
  int t = threadIdx.x;
  for (int i = t; i < 24 * 64; i += 256) W1[i] = w1[i];
  for (int i = t; i < 4096; i += 256) { W2[i] = w2[i]; W3[i] = w3[i]; }
  int e0 = blockIdx.x * 32;
  for (int idx = t; idx < 768; idx += 256) {
    int el = idx / 24, i = idx - el * 24;
    int e = e0 + el;
    rin[el][i] = (i < 8) ? re[e * 8 + i] : ea[e * 16 + (i - 8)];
  }
  __syncthreads();
  #pragma unroll
  for (int g = 0; g < 8; ++g) {
    int idx = g * 256 + t, el = idx >> 6, o = idx & 63;
    float acc = b1[o];
    #pragma unroll 8
    for (int i = 0; i < 24; ++i) acc += rin[el][i] * W1[i * 64 + o];
    t1[el][o] = acc / (1.f + __expf(-acc));
  }
  __syncthreads();
  #pragma unroll
  for (int g = 0; g < 8; ++g) {
    int idx = g * 256 + t, el = idx >> 6, o = idx & 63;
    float acc = b2[o];
    #pragma unroll 8
    for (int c = 0; c < 64; ++c) acc += t1[el][c] * W2[(c << 6) + o];
    t2[el][o] = acc / (1.f + __expf(-acc));
  }
  __syncthreads();
  #pragma unroll
  for (int g = 0; g < 8; ++g) {
    int idx = g * 256 + t, el = idx >> 6, o = idx & 63;
    float acc = b3[o];
    #pragma unroll 8
    for (int c = 0; c < 64; ++c) acc += t2[el][c] * W3[(c << 6) + o];
    rf[(e0 + el) * 64 + o] = acc;
  }
}

// ---------- Bt hi/lo split (3xBF16 scheme) ----------
__global__ __launch_bounds__(256) void k_prepb(const float* __restrict__ aw,
    const float* __restrict__ ab, unsigned short* __restrict__ Bthi,
    unsigned short* __restrict__ Btlo)
{
  int n = blockIdx.x;          // 0..95
  int l = n >> 5, w = n & 31;
  for (int k = threadIdx.x; k < 2080; k += 256) {
    float v = (k < 2048) ? aw[(k >> 5) * 3072 + l * 1024 + (k & 31) * 32 + w]
                         : ab[l * 1024 + (k - 2048) * 32 + w];
    unsigned u = __float_as_uint(v);
    float hif = __uint_as_float(u & 0xffff0000u);
    float lo = v - hif;
    Bthi[n * 2080 + k] = (unsigned short)(u >> 16);
    Btlo[n * 2080 + k] = (unsigned short)(__float_as_uint(lo) >> 16);
  }
}

// ================= deterministic CSR build (counting sort by dst) =========
// 250 chunks x 256 edges. All integer ops + fixed-rank assignment -> fully
// deterministic slot order (slot rank = original edge order within node).
__global__ __launch_bounds__(256) void k_hist(const int* __restrict__ ei,
                                              int* __restrict__ hch)
{
  __shared__ int lh[NN];
  int tid = threadIdx.x;
  for (int i = tid; i < NN; i += 256) lh[i] = 0;
  __syncthreads();
  atomicAdd(&lh[ei[NE + blockIdx.x * 256 + tid]], 1);
  __syncthreads();
  for (int i = tid; i < NN; i += 256) hch[blockIdx.x * NN + i] = lh[i];
}

__global__ __launch_bounds__(256) void k_tot(const int* __restrict__ hch,
                                             int* __restrict__ tot)
{
  int n = blockIdx.x * 256 + threadIdx.x;
  if (n >= NN) return;
  int s = 0;
  for (int c = 0; c < 250; ++c) s += hch[c * NN + n];
  tot[n] = s;
}

__global__ __launch_bounds__(256) void k_scan(const int* __restrict__ tot,
                                              int* __restrict__ off)
{
  __shared__ int part[256];
  int tid = threadIdx.x;
  int base = tid * 40;                    // 256*40 = 10240 >= NN
  int s = 0;
  for (int i = 0; i < 40; ++i) { int idx = base + i; if (idx < NN) s += tot[idx]; }
  part[tid] = s;
  __syncthreads();
  if (tid == 0) {
    int acc = 0;
    for (int i = 0; i < 256; ++i) { int t = part[i]; part[i] = acc; acc += t; }
  }
  __syncthreads();
  int acc = part[tid];
  for (int i = 0; i < 40; ++i) {
    int idx = base + i;
    if (idx < NN) { off[idx] = acc; acc += tot[idx]; }
  }
  if (tid == 255) off[NN] = NE;
}

__global__ __launch_bounds__(256) void k_base(const int* __restrict__ off,
    const int* __restrict__ hch, int* __restrict__ basec)
{
  int n = blockIdx.x * 256 + threadIdx.x;
  if (n >= NN) return;
  int acc = off[n];
  for (int c = 0; c < 250; ++c) { basec[c * NN + n] = acc; acc += hch[c * NN + n]; }
}

__global__ __launch_bounds__(256) void k_assign(const int* __restrict__ ei,
    const int* __restrict__ basec, int* __restrict__ eord, int* __restrict__ s2n)
{
  __shared__ int lcnt[NN];
  __shared__ int dstl[256];
  int tid = threadIdx.x, c = blockIdx.x;
  for (int i = tid; i < NN; i += 256) lcnt[i] = 0;
  dstl[tid] = ei[NE + c * 256 + tid];
  __syncthreads();
  int wave = tid >> 6, lane = tid & 63;
  for (int b = 0; b < 4; ++b) {
    if (wave == b) {
      int el = b * 64 + lane;
      int d = dstl[el];
      int rank = 0, last = 1;
      for (int j = 0; j < 64; ++j) {
        int dj = dstl[b * 64 + j];
        if (dj == d) { if (j < lane) rank++; else if (j > lane) last = 0; }
      }
      int slot = basec[c * NN + d] + lcnt[d] + rank;   // wave-lockstep: all reads
      eord[slot] = c * 256 + el;                       // precede the write below
      s2n[slot] = d;
      if (last) lcnt[d] += rank + 1;
    }
    __syncthreads();
  }
}

// ---------- edge GEMM on MFMA (split-precision), CSR order, fused LDS gather
// mixed[e][n] = sum_k g[e,k]*Bt[n][k], then per-node reduce in LDS and emit
// ONE write per (node,coef) per block: plain store (interior) or atomicAdd
// (boundary, <=2 contributors -> order-independent -> deterministic).
__global__ __launch_bounds__(256, 2) void k_edge_mfma(
    const float* __restrict__ rf, const float* __restrict__ h,
    const int* __restrict__ ei, const float* __restrict__ sh,
    const unsigned short* __restrict__ Bthi, const unsigned short* __restrict__ Btlo,
    const int* __restrict__ eord, const int* __restrict__ s2n,
    const int* __restrict__ off, float* __restrict__ aout)
{
  __shared__ float smem[12800];      // phase1: rf_s[128*65]; phase2: mix[128*100]
  __shared__ float sh_s[128 * 9];
  __shared__ int ge[128], srcl[128], snl[128];
  int tid = threadIdx.x;
  int s0 = blockIdx.x * 128;
  if (tid < 128) {
    int g = eord[s0 + tid];
    ge[tid] = g;
    srcl[tid] = ei[g];
    snl[tid] = s2n[s0 + tid];
  }
  __syncthreads();
  float* rf_s = smem;
  for (int idx = tid; idx < 128 * 64; idx += 256) {
    int e = idx >> 6, c = idx & 63;
    rf_s[e * 65 + c] = rf[ge[e] * 64 + c];
  }
  for (int idx = tid; idx < 128 * 9; idx += 256) {
    int e = idx / 9, i = idx - e * 9;
    sh_s[idx] = sh[ge[e] * 9 + i];
  }
  __syncthreads();

  int lane = tid & 63, wave = tid >> 6;
  int col = lane & 15, quad = lane >> 4;
  int eA = wave * 32 + col;          // m-tile 0 local slot (row = col in A)
  int eB = eA + 16;                  // m-tile 1
  const float* hpA = h + srcl[eA] * 32 + quad * 8;
  const float* hpB = h + srcl[eB] * 32 + quad * 8;
  float4 a0 = *(const float4*)hpA, a1 = *(const float4*)(hpA + 4);
  float4 b0 = *(const float4*)hpB, b1 = *(const float4*)(hpB + 4);
  float ha[8] = {a0.x, a0.y, a0.z, a0.w, a1.x, a1.y, a1.z, a1.w};
  float hb[8] = {b0.x, b0.y, b0.z, b0.w, b1.x, b1.y, b1.z, b1.w};

  ffrag acc[2][6] = {};
  const unsigned short* bhib = Bthi + col * 2080 + quad * 8;
  const unsigned short* blob = Btlo + col * 2080 + quad * 8;

  for (int s = 0; s < 65; ++s) {        // s==64: bias block (ko=2048), r=1
    float rA = (s < 64) ? rf_s[eA * 65 + s] : 1.0f;
    float rB = (s < 64) ? rf_s[eB * 65 + s] : 1.0f;
    bfrag hA, lA, hB, lB;
    #pragma unroll
    for (int j = 0; j < 8; ++j) {
      float gA = rA * ha[j];
      unsigned uA = __float_as_uint(gA);
      hA[j] = (short)(uA >> 16);
      float loA = gA - __uint_as_float(uA & 0xffff0000u);
      lA[j] = (short)(__float_as_uint(loA) >> 16);
      float gB = rB * hb[j];
      unsigned uB = __float_as_uint(gB);
      hB[j] = (short)(uB >> 16);
      float loB = gB - __uint_as_float(uB & 0xffff0000u);
      lB[j] = (short)(__float_as_uint(loB) >> 16);
    }
    int ko = s << 5;
    #pragma unroll
    for (int t = 0; t < 6; ++t) {
      bfrag bh = *(const bfrag*)(bhib + t * 16 * 2080 + ko);
      bfrag bl = *(const bfrag*)(blob + t * 16 * 2080 + ko);
      acc[0][t] = __builtin_amdgcn_mfma_f32_16x16x32_bf16(hA, bh, acc[0][t], 0, 0, 0);
      acc[1][t] = __builtin_amdgcn_mfma_f32_16x16x32_bf16(hB, bh, acc[1][t], 0, 0, 0);
      acc[0][t] = __builtin_amdgcn_mfma_f32_16x16x32_bf16(lA, bh, acc[0][t], 0, 0, 0);
      acc[1][t] = __builtin_amdgcn_mfma_f32_16x16x32_bf16(lB, bh, acc[1][t], 0, 0, 0);
      acc[0][t] = __builtin_amdgcn_mfma_f32_16x16x32_bf16(hA, bl, acc[0][t], 0, 0, 0);
      acc[1][t] = __builtin_amdgcn_mfma_f32_16x16x32_bf16(hB, bl, acc[1][t], 0, 0, 0);
    }
  }

  __syncthreads();                   // rf_s dead; smem becomes mix[128][100]
  float* mix = smem;
  #pragma unroll
  for (int mt = 0; mt < 2; ++mt)
    #pragma unroll
    for (int r = 0; r < 4; ++r) {
      int el = wave * 32 + mt * 16 + quad * 4 + r;
      #pragma unroll
      for (int t = 0; t < 6; ++t) {
        int m = ((t >> 1) << 5) + ((t & 1) << 4) + col;
        mix[el * 100 + m] = acc[mt][t][r] * INV_SQM;
      }
    }
  __syncthreads();

  // ---- per-node gather: thread owns coef c (and c+256 for tid<32) ----
  int m_[2], shi_[2];
  float nrm_[2];
  int ncid = (tid < 32) ? 2 : 1;
  #pragma unroll
  for (int q = 0; q < 2; ++q) {
    int c = q ? 256 + tid : tid;
    int l, w, i;
    if (c < 32) { l = 0; w = c; i = 0; }
    else if (c < 128) { l = 1; w = (c - 32) / 3; i = (c - 32) % 3; }
    else { l = 2; w = (c - 128) / 5; i = (c - 128) % 5; }
    m_[q] = l * 32 + w;
    shi_[q] = (l == 0) ? 0 : ((l == 1) ? 1 + i : 4 + i);
    nrm_[q] = (l == 0) ? 1.0f : ((l == 1) ? 0.57735027f : 0.44721360f);
  }
  int s = 0;
  while (s < 128) {
    int n = snl[s];
    int e2 = s + 1;
    while (e2 < 128 && snl[e2] == n) ++e2;
    int o0 = off[n], o1 = off[n + 1];
    float inv = 1.0f / (float)(o1 - o0);
    bool interior = (o0 == s0 + s) && (o1 == s0 + e2);
    float v[2] = {0.f, 0.f};
    for (int el = s; el < e2; ++el) {
      v[0] += mix[el * 100 + m_[0]] * sh_s[el * 9 + shi_[0]];
      if (ncid == 2) v[1] += mix[el * 100 + m_[1]] * sh_s[el * 9 + shi_[1]];
    }
    #pragma unroll
    for (int q = 0; q < 2; ++q) {
      if (q >= ncid) break;
      float val = v[q] * nrm_[q] * inv;
      int c = q ? 256 + tid : tid;
      if (interior) aout[n * 288 + c] = val;
      else atomicAdd(&aout[n * 288 + c], val);
    }
    s = e2;
  }
}

// ---------- W[p][u][v][w] f32  ->  Wt[p][u][w][v] bf16 (one (p,u) slice/block) ----------
__global__ __launch_bounds__(256) void k_prepw(const float* __restrict__ W,
                                               unsigned short* __restrict__ Wt)
{
  __shared__ float buf[32 * 33];
  int tid = threadIdx.x;
  long base = (long)blockIdx.x * 1024;
  #pragma unroll
  for (int it = 0; it < 4; ++it) {
    int idx = it * 256 + tid;
    int w = idx & 31, v = idx >> 5;
    buf[w * 33 + v] = W[base + v * 32 + w];
  }
  __syncthreads();
  unsigned* out32 = (unsigned*)(Wt + base);
  #pragma unroll
  for (int it = 0; it < 2; ++it) {
    int idx = it * 256 + tid;
    int w = idx >> 4, vp = idx & 15;
    float f0 = buf[w * 33 + vp * 2], f1 = buf[w * 33 + vp * 2 + 1];
    unsigned pk = (unsigned)(unsigned short)f2bf(f0) |
                  ((unsigned)(unsigned short)f2bf(f1) << 16);
    out32[w * 16 + vp] = pk;
  }
}

// ---------- one TP path on MFMA ----------
template<int PI, int WIDX>
__device__ __forceinline__ void process_path(const float* __restrict__ x_s,
    const float* __restrict__ y_s, const unsigned short* __restrict__ wt,
    int lane, int wave, ffrag acc[9][2])
{
  constexpr int ip = cIP[PI], jp = cJP[PI], kp = cKP[PI];
  constexpr int di = cDL[ip], dj = cDL[jp], dk = cDL[kp];
  constexpr int xb = cOF[ip], yb = cOF[jp];
  constexpr int ks0 = (kp == 0) ? 0 : ((kp == 1) ? 1 : 4);
  constexpr int nA = cKo[PI][0];
  constexpr int nB = cKo[PI][dk];
  const int z = lane & 15, quad = lane >> 4;

  float yreg[8][dj];
  #pragma unroll
  for (int vi = 0; vi < 8; ++vi)
    #pragma unroll
    for (int j = 0; j < dj; ++j)
      yreg[vi][j] = y_s[z * 292 + yb + (quad * 8 + vi) * dj + j];

  for (int uu = 0; uu < 8; ++uu) {
    int u = wave * 8 + uu;
    const unsigned short* wb = wt + (((WIDX * 32 + u) * 32) << 5) + quad * 8;
    bfrag b0 = *(const bfrag*)(wb + (z << 5));          // w = lane&15
    bfrag b1 = *(const bfrag*)(wb + ((16 + z) << 5));   // w = 16 + lane&15
    float xv[di];
    #pragma unroll
    for (int i = 0; i < di; ++i) xv[i] = x_s[z * 292 + xb + u * di + i];
    float xc[nB - nA];
    #pragma unroll
    for (int n = nA; n < nB; ++n) xc[n - nA] = xv[cNI[n]] * cNV[n];
    bfrag fa[dk];
    #pragma unroll
    for (int vi = 0; vi < 8; ++vi) {
      float T[dk];
      #pragma unroll
      for (int k = 0; k < dk; ++k) T[k] = 0.f;
      #pragma unroll
      for (int k = 0; k < dk; ++k)
        #pragma unroll
        for (int n = cKo[PI][k]; n < cKo[PI][k + 1]; ++n)
          T[k] += xc[n - nA] * yreg[vi][cNJ[n]];
      #pragma unroll
      for (int k = 0; k < dk; ++k) fa[k][vi] = f2bf(T[k]);
    }
    #pragma unroll
    for (int k = 0; k < dk; ++k) {
      acc[ks0 + k][0] = __builtin_amdgcn_mfma_f32_16x16x32_bf16(fa[k], b0, acc[ks0 + k][0], 0, 0, 0);
      acc[ks0 + k][1] = __builtin_amdgcn_mfma_f32_16x16x32_bf16(fa[k], b1, acc[ks0 + k][1], 0, 0, 0);
    }
  }
}

// MODE 0: all 11 paths (o3a/o3b). MODE 1: o2_uvw paths {1,2,6}.
template<int MODE>
__global__ __launch_bounds__(256, 2) void k_pairwise_mfma(
    const float* __restrict__ x, const float* __restrict__ y,
    const unsigned short* __restrict__ wt, float* __restrict__ out, float scale)
{
  __shared__ float smem[9504];        // x_s[16*292] | y_s[16*292]; 2 red slices of 4752
  float* x_s = smem;
  float* y_s = smem + 4672;
  int tid = threadIdx.x;
  int z0 = blockIdx.x * 16;
  for (int idx = tid; idx < 16 * 72; idx += 256) {
    int r = idx / 72, f = (idx - r * 72) * 4;
    *(float4*)&x_s[r * 292 + f] = *(const float4*)&x[(z0 + r) * 288 + f];
    *(float4*)&y_s[r * 292 + f] = *(const float4*)&y[(z0 + r) * 288 + f];
  }
  __syncthreads();
  int lane = tid & 63, wave = tid >> 6;
  ffrag acc[9][2] = {};

  if constexpr (MODE == 0) {
    process_path<0, 0>(x_s, y_s, wt, lane, wave, acc);
    process_path<1, 1>(x_s, y_s, wt, lane, wave, acc);
    process_path<2, 2>(x_s, y_s, wt, lane, wave, acc);
    process_path<3, 3>(x_s, y_s, wt, lane, wave, acc);
    process_path<4, 4>(x_s, y_s, wt, lane, wave, acc);
    process_path<5, 5>(x_s, y_s, wt, lane, wave, acc);
    process_path<6, 6>(x_s, y_s, wt, lane, wave, acc);
    process_path<7, 7>(x_s, y_s, wt, lane, wave, acc);
    process_path<8, 8>(x_s, y_s, wt, lane, wave, acc);
    process_path<9, 9>(x_s, y_s, wt, lane, wave, acc);
    process_path<10, 10>(x_s, y_s, wt, lane, wave, acc);
  } else {
    process_path<1, 0>(x_s, y_s, wt, lane, wave, acc);
    process_path<2, 1>(x_s, y_s, wt, lane, wave, acc);
    process_path<6, 2>(x_s, y_s, wt, lane, wave, acc);
  }

  // ---- deterministic cross-wave reduction: (w0 + w2) + (w1 + w3) ----
  float* slice0 = smem;          // 4752 floats, row stride 33
  float* slice1 = smem + 4752;   // 4752 floats
  int n15 = lane & 15, quad = lane >> 4;
  __syncthreads();
  if (wave >= 2) {
    float* sl = (wave == 2) ? slice0 : slice1;
    #pragma unroll
    for (int s = 0; s < 9; ++s)
      #pragma unroll
      for (int wh = 0; wh < 2; ++wh)
        #pragma unroll
        for (int r = 0; r < 4; ++r)
          sl[(s * 16 + quad * 4 + r) * 33 + wh * 16 + n15] = acc[s][wh][r];
  }
  __syncthreads();
  if (wave < 2) {
    float* sl = (wave == 0) ? slice0 : slice1;
    #pragma unroll
    for (int s = 0; s < 9; ++s)
      #pragma unroll
      for (int wh = 0; wh < 2; ++wh)
        #pragma unroll
        for (int r = 0; r < 4; ++r)
          acc[s][wh][r] += sl[(s * 16 + quad * 4 + r) * 33 + wh * 16 + n15];
  }
  __syncthreads();
  if (wave == 1) {
    #pragma unroll
    for (int s = 0; s < 9; ++s)
      #pragma unroll
      for (int wh = 0; wh < 2; ++wh)
        #pragma unroll
        for (int r = 0; r < 4; ++r)
          slice1[(s * 16 + quad * 4 + r) * 33 + wh * 16 + n15] = acc[s][wh][r];
  }
  __syncthreads();
  if (wave == 0) {
    #pragma unroll
    for (int s = 0; s < 9; ++s)
      #pragma unroll
      for (int wh = 0; wh < 2; ++wh)
        #pragma unroll
        for (int r = 0; r < 4; ++r) {
          int o = (s * 16 + quad * 4 + r) * 33 + wh * 16 + n15;
          slice0[o] = acc[s][wh][r] + slice1[o];
        }
  }
  __syncthreads();
  for (int idx = tid; idx < 4608; idx += 256) {
    int w = idx & 31, rest = idx >> 5;
    int zz = rest & 15, ks = rest >> 4;
    int c = (ks == 0) ? w : (ks < 4 ? 32 + w * 3 + (ks - 1) : 128 + w * 5 + (ks - 4));
    out[(z0 + zz) * 288 + c] = scale * slice0[(ks * 16 + zz) * 33 + w];
  }
}

// ---------- uvu part of order2: compile-time templated paths ----------
template<int PI>
__device__ __forceinline__ void uvu_path(const float* __restrict__ x_t,
    const float* __restrict__ Wg, int u, int zq, float acc0[2], float acc2[2][5])
{
  constexpr int ip = cIP[PI], jp = cJP[PI], kp = cKP[PI];
  constexpr int di = cDL[ip], dj = cDL[jp], dk = cDL[kp];
  constexpr int xb = cOF[ip], yb = cOF[jp];
  constexpr int nA = cKo[PI][0];
  constexpr int nB = cKo[PI][dk];
  float wrow[32];
  #pragma unroll
  for (int vq = 0; vq < 8; ++vq)
    *(float4*)&wrow[vq * 4] = *(const float4*)&Wg[u * 32 + vq * 4];
  #pragma unroll
  for (int zz = 0; zz < 2; ++zz) {
    int z = zq + (zz << 3);
    float xv[di];
    #pragma unroll
    for (int i = 0; i < di; ++i) xv[i] = x_t[z * 288 + xb + u * di + i];
    float xc[nB - nA];
    #pragma unroll
    for (int n = nA; n < nB; ++n) xc[n - nA] = xv[cNI[n]] * cNV[n];
    const float* yrb = &x_t[z * 288 + yb];
    #pragma unroll 8
    for (int v = 0; v < 32; ++v) {
      float yv[dj];
      #pragma unroll
      for (int j = 0; j < dj; ++j) yv[j] = yrb[v * dj + j];
      float wv = wrow[v];
      if constexpr (kp == 0) {
        float t = 0.f;
        #pragma unroll
        for (int n = nA; n < nB; ++n) t += xc[n - nA] * yv[cNJ[n]];
        acc0[zz] += wv * t;
      } else {
        #pragma unroll
        for (int k = 0; k < 5; ++k) {
          float t = 0.f;
          #pragma unroll
          for (int n = cKo[PI][k]; n < cKo[PI][k + 1]; ++n)
            t += xc[n - nA] * yv[cNJ[n]];
          acc2[zz][k] += wv * t;
        }
      }
    }
  }
}

__global__ __launch_bounds__(256) void k_uvu(
    const float* __restrict__ x, const float* __restrict__ W, float* __restrict__ out)
{
  __shared__ __align__(16) float x_t[16 * 288];
  int tid = threadIdx.x;
  int z0 = blockIdx.x * 16;
  for (int idx = tid; idx < 16 * 72; idx += 256) {
    int r = idx / 72, f = idx - r * 72;
    *(float4*)&x_t[r * 288 + f * 4] = *(const float4*)&x[(z0 + r) * 288 + f * 4];
  }
  __syncthreads();
  int u = tid & 31, zq = tid >> 5;
  float acc0[2] = {0.f, 0.f};
  float acc2[2][5] = {};
  uvu_path<0>(x_t, W,            u, zq, acc0, acc2);   // PL_UVU order {0,4,5,9,10}
  uvu_path<4>(x_t, W + 1 * 1024, u, zq, acc0, acc2);
  uvu_path<5>(x_t, W + 2 * 1024, u, zq, acc0, acc2);
  uvu_path<9>(x_t, W + 3 * 1024, u, zq, acc0, acc2);
  uvu_path<10>(x_t, W + 4 * 1024, u, zq, acc0, acc2);
  #pragma unroll
  for (int zz = 0; zz < 2; ++zz) {
    int zg = z0 + zq + (zz << 3);
    float* orow = out + zg * 288;
    orow[u] += INV_SQM * acc0[zz];
    #pragma unroll
    for (int kk = 0; kk < 5; ++kk) orow[128 + u * 5 + kk] += INV_SQM * acc2[zz][kk];
  }
}

// ---------- final lin chains + self connection ----------
__device__ __forceinline__ void lin_row(float* dst, const float* src, const float* Wm, int w)
{
  {
    float s = 0.f;
    for (int u = 0; u < 32; ++u) s += src[u] * Wm[(u << 5) + w];
    dst[w] = s * INV_SQM;
  }
  #pragma unroll
  for (int i = 0; i < 3; ++i) {
    float s = 0.f;
    for (int u = 0; u < 32; ++u) s += src[32 + u * 3 + i] * Wm[1024 + (u << 5) + w];
    dst[32 + w * 3 + i] = s * INV_SQM;
  }
  #pragma unroll
  for (int i = 0; i < 5; ++i) {
    float s = 0.f;
    for (int u = 0; u < 32; ++u) s += src[128 + u * 5 + i] * Wm[2048 + (u << 5) + w];
    dst[128 + w * 5 + i] = s * INV_SQM;
  }
}

__device__ __forceinline__ void lin_acc(float* msg, const float* src, const float* Wm, int w)
{
  {
    float s = 0.f;
    for (int u = 0; u < 32; ++u) s += src[u] * Wm[(u << 5) + w];
    msg[0] += s * INV_SQM;
  }
  #pragma unroll
  for (int i = 0; i < 3; ++i) {
    float s = 0.f;
    for (int u = 0; u < 32; ++u) s += src[32 + u * 3 + i] * Wm[1024 + (u << 5) + w];
    msg[1 + i] += s * INV_SQM;
  }
  #pragma unroll
  for (int i = 0; i < 5; ++i) {
    float s = 0.f;
    for (int u = 0; u < 32; ++u) s += src[128 + u * 5 + i] * Wm[2048 + (u << 5) + w];
    msg[4 + i] += s * INV_SQM;
  }
}

__global__ __launch_bounds__(256) void k_finalize(
    const float* __restrict__ a, const float* __restrict__ b2, const float* __restrict__ b3,
    const float* __restrict__ selfc, const float* __restrict__ lin_o1,
    const float* __restrict__ mix_w, const float* __restrict__ comb_w,
    float* __restrict__ out)
{
  __shared__ float bufA[8 * 288];
  __shared__ float bufB[8 * 288];
  int tid = threadIdx.x;
  int w = tid & 31, zl = tid >> 5;
  int z = blockIdx.x * 8 + zl;
  float msg[9];
  #pragma unroll
  for (int s = 0; s < 9; ++s) msg[s] = 0.f;
  float* rowA = &bufA[zl * 288];
  float* rowB = &bufB[zl * 288];
  lin_row(rowA, a + z * 288, lin_o1, w);
  __syncthreads();
  lin_row(rowB, rowA, mix_w, w);
  __syncthreads();
  lin_acc(msg, rowB, comb_w, w);
  __syncthreads();
  lin_row(rowA, b2 + z * 288, mix_w + 3072, w);
  __syncthreads();
  lin_acc(msg, rowA, comb_w + 3072, w);
  __syncthreads();
  lin_row(rowA, b3 + z * 288, mix_w + 6144, w);
  __syncthreads();
  lin_acc(msg, rowA, comb_w + 6144, w);

  float sc = selfc[(z << 5) + w];
  float* orow = out + z * 288;
  orow[w] = msg[0] + sc;
  #pragma unroll
  for (int i = 0; i < 3; ++i) orow[32 + w * 3 + i] = msg[1 + i];
  #pragma unroll
  for (int i = 0; i < 5; ++i) orow[128 + w * 5 + i] = msg[4 + i];
}

extern "C" void kernel_launch(void* const* d_in, const int* in_sizes, int n_in,
                              void* d_out, int out_size, void* d_ws, size_t ws_size,
                              hipStream_t stream)
{
  (void)in_sizes; (void)n_in; (void)out_size; (void)ws_size;
  const float* nf   = (const float*)d_in[0];
  const int*   ei   = (const int*)d_in[1];
  const float* sh   = (const float*)d_in[2];
  const float* re   = (const float*)d_in[3];
  const float* ea   = (const float*)d_in[4];
  const float* rw1  = (const float*)d_in[5];
  const float* rb1  = (const float*)d_in[6];
  const float* rw2  = (const float*)d_in[7];
  const float* rb2  = (const float*)d_in[8];
  const float* rw3  = (const float*)d_in[9];
  const float* rb3  = (const float*)d_in[10];
  const float* aw   = (const float*)d_in[11];
  const float* ab   = (const float*)d_in[12];
  const float* embw = (const float*)d_in[13];
  const float* lino1= (const float*)d_in[14];
  const float* o2uvw= (const float*)d_in[15];
  const float* o2uvu= (const float*)d_in[16];
  const float* o3a  = (const float*)d_in[17];
  const float* o3b  = (const float*)d_in[18];
  const float* mixw = (const float*)d_in[19];
  const float* combw= (const float*)d_in[20];
  const float* selfw= (const float*)d_in[21];
  float* out = (float*)d_out;
  float* ws  = (float*)d_ws;

  // workspace layout (floats). High-water = 10,915,600 floats (43.66 MB) ==
  // R3-proven footprint. CSR scratch aliases dead regions:
  //  - h_chunk (250*NN ints) -> front of `a` (dead until k_edge output;
  //    consumed by k_base; memset(a) happens after k_assign)
  //  - base   (250*NN ints) -> cint + 200000 (after bthi/btlo)
  //  - eord/s2n/off         -> cint tail; all dead before k_pairwise<0>
  float* h     = ws;                // 320000
  float* selfc = ws + 320000;       // 320000
  float* rfb   = ws + 640000;       // 4096000  (rf; reused as b2 afterwards)
  float* a     = ws + 4736000;      // 2880000
  int*   tot   = (int*)(ws + 7616000); // 10000 ints (old cnt region)
  float* cint  = ws + 7626000;      // 2880000  (b3 computed in-place)
  float* b2 = rfb;
  float* b3 = cint;
  unsigned short* wt_o2  = (unsigned short*)(ws + 10506000); //  98304 ush
  unsigned short* wt_o3a = wt_o2 + 98304;                    // 360448 ush
  unsigned short* wt_o3b = wt_o3a + 360448;                  // 360448 ush -> ends at float 10915600
  unsigned short* bthi   = (unsigned short*)cint;            // 199680 ush
  unsigned short* btlo   = bthi + 199680;                    // 199680 ush (ends at cint+199680 fl)
  int* h_chunk = (int*)a;                                    // 2,500,000 ints
  int* basec   = (int*)(cint + 200000);                      // 2,500,000 ints
  int* eord    = (int*)(cint + 2700000);                     // 64000 ints
  int* s2n     = (int*)(cint + 2764000);                     // 64000 ints
  int* off     = (int*)(cint + 2828000);                     // 10001 ints (ends 2838001 < 2880000)

  k_prepb<<<96, 256, 0, stream>>>(aw, ab, bthi, btlo);
  k_prepw<<<96, 256, 0, stream>>>(o2uvw, wt_o2);
  k_prepw<<<352, 256, 0, stream>>>(o3a, wt_o3a);
  k_prepw<<<352, 256, 0, stream>>>(o3b, wt_o3b);
  k_embed<<<1250, 256, 0, stream>>>(nf, embw, selfw, h, selfc);
  k_radial<<<2000, 256, 0, stream>>>(re, ea, rw1, rb1, rw2, rb2, rw3, rb3, rfb);
  // deterministic CSR build
  k_hist<<<250, 256, 0, stream>>>(ei, h_chunk);
  k_tot<<<40, 256, 0, stream>>>(h_chunk, tot);
  k_scan<<<1, 256, 0, stream>>>(tot, off);
  k_base<<<40, 256, 0, stream>>>(off, h_chunk, basec);
  k_assign<<<250, 256, 0, stream>>>(ei, basec, eord, s2n);
  hipMemsetAsync(a, 0, 2880000 * sizeof(float), stream);   // after k_assign (h_chunk dead)
  k_edge_mfma<<<500, 256, 0, stream>>>(rfb, h, ei, sh, bthi, btlo, eord, s2n, off, a);
  k_pairwise_mfma<1><<<625, 256, 0, stream>>>(a, a, wt_o2, b2, INV_MUL);
  k_uvu<<<625, 256, 0, stream>>>(a, o2uvu, b2);
  k_pairwise_mfma<0><<<625, 256, 0, stream>>>(a, a, wt_o3a, cint, INV_MUL);
  k_pairwise_mfma<0><<<625, 256, 0, stream>>>(cint, a, wt_o3b, b3, INV_MUL);
  k_finalize<<<1250, 256, 0, stream>>>(a, b2, b3, selfc, lino1, mixw, combw, out);
}

// Round 10
// 811.834 us; speedup vs baseline: 8.0311x; 1.1839x over previous
//
#include <hip/hip_runtime.h>

#define NN 10000
#define NE 64000
#define INV_SQM 0.17677669529663687f   // 1/sqrt(32)
#define INV_MUL 0.03125f               // 1/32

typedef __attribute__((ext_vector_type(8))) short bfrag;   // 8 bf16 (4 VGPRs)
typedef __attribute__((ext_vector_type(4))) float ffrag;   // 4 fp32 acc

__device__ __forceinline__ short f2bf(float f) {
  unsigned u = __float_as_uint(f);
  unsigned r = (u + 0x7FFFu + ((u >> 16) & 1u)) >> 16;  // RNE
  return (short)r;
}

// ---------- compile-time Clebsch-Gordan sparse tables ----------
constexpr int cIP[11] = {0,0,0,1,1,1,1,2,2,2,2};
constexpr int cJP[11] = {0,1,2,0,1,1,2,0,1,2,2};
constexpr int cKP[11] = {0,1,2,1,0,2,1,2,1,0,2};
constexpr int cKo[11][6] = {
  {0,1,1,1,1,1},{1,2,3,4,4,4},{4,5,6,7,8,9},{9,10,11,12,12,12},
  {12,15,15,15,15,15},{15,17,19,22,24,26},{26,30,34,37,37,37},
  {37,38,39,40,41,42},{42,46,50,53,53,53},{53,58,58,58,58,58},
  {58,62,68,73,79,83}};
constexpr int cDL[3]  = {1,3,5};
constexpr int cOF[3]  = {0,32,128};
constexpr int cNI[83] = {
  0, 0,0,0, 0,0,0,0,0, 0,1,2, 0,1,2,
  0,1,1,2,0,1,2,0,2,0,1,
  1,0,2,0,0,2,1,1,1,2,0,
  0,1,2,3,4,
  0,2,3,4,0,1,2,4,1,2,3,
  0,1,2,3,4,
  0,2,1,3,0,3,1,2,1,4,0,1,2,3,4,0,1,2,3,3,4,1,2,4,3};
constexpr int cNJ[83] = {
  0, 0,1,2, 0,1,2,3,4, 0,0,0, 0,1,2,
  1,0,2,1,0,1,2,2,0,0,1,
  0,2,3,4,0,1,2,4,1,2,3,
  0,0,0,0,0,
  1,0,2,0,0,2,1,1,1,2,0,
  0,1,2,3,4,
  2,0,3,1,3,0,2,1,4,1,0,1,2,3,4,1,0,3,2,4,3,1,4,2,3};
constexpr float cNV[83] = {
  1.0f,
  0.57735027f,0.57735027f,0.57735027f,
  0.44721360f,0.44721360f,0.44721360f,0.44721360f,0.44721360f,
  0.57735027f,0.57735027f,0.57735027f,
  0.57735027f,0.57735027f,0.57735027f,
  0.31622777f,0.31622777f,0.31622777f,0.31622777f,-0.18257419f,-0.18257419f,
  0.36514837f,0.31622777f,0.31622777f,0.31622777f,-0.31622777f,
  0.31622777f,-0.18257419f,0.31622777f,0.31622777f,0.31622777f,0.31622777f,
  -0.18257419f,-0.31622777f,0.31622777f,0.36514837f,0.31622777f,
  0.44721360f,0.44721360f,0.44721360f,0.44721360f,0.44721360f,
  0.31622777f,-0.18257419f,0.31622777f,0.31622777f,0.31622777f,0.31622777f,
  -0.18257419f,-0.31622777f,0.31622777f,0.36514837f,0.31622777f,
  0.44721360f,0.44721360f,0.44721360f,0.44721360f,0.44721360f,
  -0.23904572f,-0.23904572f,0.20702483f,0.20702483f,
  0.20702483f,0.20702483f,0.11952286f,0.11952286f,-0.20702483f,-0.20702483f,
  -0.23904572f,0.11952286f,0.23904572f,0.11952286f,-0.23904572f,
  0.20702483f,0.20702483f,0.11952286f,0.11952286f,0.20702483f,0.20702483f,
  -0.20702483f,-0.23904572f,-0.23904572f,0.20702483f};

// ---------- h = nf@emb_w/SQM ; selfc = nf@self_w/SQM ----------
__global__ __launch_bounds__(256) void k_embed(const float* __restrict__ nf,
    const float* __restrict__ emb_w, const float* __restrict__ self_w,
    float* __restrict__ h, float* __restrict__ selfc)
{
  __shared__ float We[1024], Wsf[1024];
  int tid = threadIdx.x;
  for (int i = tid; i < 1024; i += 256) { We[i] = emb_w[i]; Wsf[i] = self_w[i]; }
  __syncthreads();
  int z = blockIdx.x * 8 + (tid >> 5);
  int u = tid & 31;
  if (z >= NN) return;
  const float* row = nf + z * 32;
  float ah = 0.f, as = 0.f;
  #pragma unroll 8
  for (int v = 0; v < 32; ++v) {
    float xv = row[v];
    ah += xv * We[(v << 5) + u];
    as += xv * Wsf[(v << 5) + u];
  }
  h[(z << 5) + u]     = ah * INV_SQM;
  selfc[(z << 5) + u] = as * INV_SQM;
}

// ---------- per-edge radial MLP -> rf[64], 32 edges/block ----------
__global__ __launch_bounds__(256) void k_radial(
    const float* __restrict__ re, const float* __restrict__ ea,
    const float* __restrict__ w1, const float* __restrict__ b1,
    const float* __restrict__ w2, const float* __restrict__ b2,
    const float* __restrict__ w3, const float* __restrict__ b3,
    float* __restrict__ rf)
{
  __shared__ float W1[24 * 64];
  __shared__ float W2[64 * 64];
  __shared__ float W3[64 * 64];
  __shared__ float rin[32][25];
  __shared__ float t1[32][65], t2[32][65];
  int t = threadIdx.x;
  for (int i = t; i < 24 * 64; i += 256) W1[i] = w1[i];
  for (int i = t; i < 4096; i += 256) { W2[i] = w2[i]; W3[i] = w3[i]; }
  int e0 = blockIdx.x * 32;
  for (int idx = t; idx < 768; idx += 256) {
    int el = idx / 24, i = idx - el * 24;
    int e = e0 + el;
    rin[el][i] = (i < 8) ? re[e * 8 + i] : ea[e * 16 + (i - 8)];
  }
  __syncthreads();
  #pragma unroll
  for (int g = 0; g < 8; ++g) {
    int idx = g * 256 + t, el = idx >> 6, o = idx & 63;
    float acc = b1[o];
    #pragma unroll 8
    for (int i = 0; i < 24; ++i) acc += rin[el][i] * W1[i * 64 + o];
    t1[el][o] = acc / (1.f + __expf(-acc));
  }
  __syncthreads();
  #pragma unroll
  for (int g = 0; g < 8; ++g) {
    int idx = g * 256 + t, el = idx >> 6, o = idx & 63;
    float acc = b2[o];
    #pragma unroll 8
    for (int c = 0; c < 64; ++c) acc += t1[el][c] * W2[(c << 6) + o];
    t2[el][o] = acc / (1.f + __expf(-acc));
  }
  __syncthreads();
  #pragma unroll
  for (int g = 0; g < 8; ++g) {
    int idx = g * 256 + t, el = idx >> 6, o = idx & 63;
    float acc = b3[o];
    #pragma unroll 8
    for (int c = 0; c < 64; ++c) acc += t2[el][c] * W3[(c << 6) + o];
    rf[(e0 + el) * 64 + o] = acc;
  }
}

// ---------- Bt hi/lo split (3xBF16 scheme) ----------
__global__ __launch_bounds__(256) void k_prepb(const float* __restrict__ aw,
    const float* __restrict__ ab, unsigned short* __restrict__ Bthi,
    unsigned short* __restrict__ Btlo)
{
  int n = blockIdx.x;          // 0..95
  int l = n >> 5, w = n & 31;
  for (int k = threadIdx.x; k < 2080; k += 256) {
    float v = (k < 2048) ? aw[(k >> 5) * 3072 + l * 1024 + (k & 31) * 32 + w]
                         : ab[l * 1024 + (k - 2048) * 32 + w];
    unsigned u = __float_as_uint(v);
    float hif = __uint_as_float(u & 0xffff0000u);
    float lo = v - hif;
    Bthi[n * 2080 + k] = (unsigned short)(u >> 16);
    Btlo[n * 2080 + k] = (unsigned short)(__float_as_uint(lo) >> 16);
  }
}

// ================= deterministic CSR build (counting sort by dst) =========
__global__ __launch_bounds__(256) void k_hist(const int* __restrict__ ei,
                                              int* __restrict__ hch)
{
  __shared__ int lh[NN];
  int tid = threadIdx.x;
  for (int i = tid; i < NN; i += 256) lh[i] = 0;
  __syncthreads();
  atomicAdd(&lh[ei[NE + blockIdx.x * 256 + tid]], 1);
  __syncthreads();
  for (int i = tid; i < NN; i += 256) hch[blockIdx.x * NN + i] = lh[i];
}

__global__ __launch_bounds__(256) void k_tot(const int* __restrict__ hch,
                                             int* __restrict__ tot)
{
  int n = blockIdx.x * 256 + threadIdx.x;
  if (n >= NN) return;
  int s = 0;
  for (int c = 0; c < 250; ++c) s += hch[c * NN + n];
  tot[n] = s;
}

__global__ __launch_bounds__(256) void k_scan(const int* __restrict__ tot,
                                              int* __restrict__ off)
{
  __shared__ int part[256];
  int tid = threadIdx.x;
  int base = tid * 40;                    // 256*40 = 10240 >= NN
  int s = 0;
  for (int i = 0; i < 40; ++i) { int idx = base + i; if (idx < NN) s += tot[idx]; }
  part[tid] = s;
  __syncthreads();
  if (tid == 0) {
    int acc = 0;
    for (int i = 0; i < 256; ++i) { int t = part[i]; part[i] = acc; acc += t; }
  }
  __syncthreads();
  int acc = part[tid];
  for (int i = 0; i < 40; ++i) {
    int idx = base + i;
    if (idx < NN) { off[idx] = acc; acc += tot[idx]; }
  }
  if (tid == 255) off[NN] = NE;
}

__global__ __launch_bounds__(256) void k_base(const int* __restrict__ off,
    const int* __restrict__ hch, int* __restrict__ basec)
{
  int n = blockIdx.x * 256 + threadIdx.x;
  if (n >= NN) return;
  int acc = off[n];
  for (int c = 0; c < 250; ++c) { basec[c * NN + n] = acc; acc += hch[c * NN + n]; }
}

__global__ __launch_bounds__(256) void k_assign(const int* __restrict__ ei,
    const int* __restrict__ basec, int* __restrict__ eord, int* __restrict__ s2n)
{
  __shared__ int lcnt[NN];
  __shared__ int dstl[256];
  int tid = threadIdx.x, c = blockIdx.x;
  for (int i = tid; i < NN; i += 256) lcnt[i] = 0;
  dstl[tid] = ei[NE + c * 256 + tid];
  __syncthreads();
  int wave = tid >> 6, lane = tid & 63;
  for (int b = 0; b < 4; ++b) {
    if (wave == b) {
      int el = b * 64 + lane;
      int d = dstl[el];
      int rank = 0, last = 1;
      for (int j = 0; j < 64; ++j) {
        int dj = dstl[b * 64 + j];
        if (dj == d) { if (j < lane) rank++; else if (j > lane) last = 0; }
      }
      int slot = basec[c * NN + d] + lcnt[d] + rank;   // wave-lockstep: all reads
      eord[slot] = c * 256 + el;                       // precede the write below
      s2n[slot] = d;
      if (last) lcnt[d] += rank + 1;
    }
    __syncthreads();
  }
}

// ---------- edge GEMM on MFMA (split-precision), CSR order, fused LDS gather
// R9 post-mortem: tripwire tripped with boundary fp32 atomicAdds as the only
// schedule-sensitive ops left. Now ZERO fp atomics: boundary runs store their
// partial to bpart[block][head/tail][288] (single writer), and k_fix sums the
// <=2 partials per block boundary in FIXED order -> bitwise deterministic.
__global__ __launch_bounds__(256, 2) void k_edge_mfma(
    const float* __restrict__ rf, const float* __restrict__ h,
    const int* __restrict__ ei, const float* __restrict__ sh,
    const unsigned short* __restrict__ Bthi, const unsigned short* __restrict__ Btlo,
    const int* __restrict__ eord, const int* __restrict__ s2n,
    const int* __restrict__ off, float* __restrict__ aout,
    float* __restrict__ bpart)
{
  __shared__ float smem[12800];      // phase1: rf_s[128*65]; phase2: mix[128*100]
  __shared__ float sh_s[128 * 9];
  __shared__ int ge[128], srcl[128], snl[128];
  int tid = threadIdx.x;
  int s0 = blockIdx.x * 128;
  if (tid < 128) {
    int g = eord[s0 + tid];
    ge[tid] = g;
    srcl[tid] = ei[g];
    snl[tid] = s2n[s0 + tid];
  }
  __syncthreads();
  float* rf_s = smem;
  for (int idx = tid; idx < 128 * 64; idx += 256) {
    int e = idx >> 6, c = idx & 63;
    rf_s[e * 65 + c] = rf[ge[e] * 64 + c];
  }
  for (int idx = tid; idx < 128 * 9; idx += 256) {
    int e = idx / 9, i = idx - e * 9;
    sh_s[idx] = sh[ge[e] * 9 + i];
  }
  __syncthreads();

  int lane = tid & 63, wave = tid >> 6;
  int col = lane & 15, quad = lane >> 4;
  int eA = wave * 32 + col;          // m-tile 0 local slot (row = col in A)
  int eB = eA + 16;                  // m-tile 1
  const float* hpA = h + srcl[eA] * 32 + quad * 8;
  const float* hpB = h + srcl[eB] * 32 + quad * 8;
  float4 a0 = *(const float4*)hpA, a1 = *(const float4*)(hpA + 4);
  float4 b0 = *(const float4*)hpB, b1 = *(const float4*)(hpB + 4);
  float ha[8] = {a0.x, a0.y, a0.z, a0.w, a1.x, a1.y, a1.z, a1.w};
  float hb[8] = {b0.x, b0.y, b0.z, b0.w, b1.x, b1.y, b1.z, b1.w};

  ffrag acc[2][6] = {};
  const unsigned short* bhib = Bthi + col * 2080 + quad * 8;
  const unsigned short* blob = Btlo + col * 2080 + quad * 8;

  for (int s = 0; s < 65; ++s) {        // s==64: bias block (ko=2048), r=1
    float rA = (s < 64) ? rf_s[eA * 65 + s] : 1.0f;
    float rB = (s < 64) ? rf_s[eB * 65 + s] : 1.0f;
    bfrag hA, lA, hB, lB;
    #pragma unroll
    for (int j = 0; j < 8; ++j) {
      float gA = rA * ha[j];
      unsigned uA = __float_as_uint(gA);
      hA[j] = (short)(uA >> 16);
      float loA = gA - __uint_as_float(uA & 0xffff0000u);
      lA[j] = (short)(__float_as_uint(loA) >> 16);
      float gB = rB * hb[j];
      unsigned uB = __float_as_uint(gB);
      hB[j] = (short)(uB >> 16);
      float loB = gB - __uint_as_float(uB & 0xffff0000u);
      lB[j] = (short)(__float_as_uint(loB) >> 16);
    }
    int ko = s << 5;
    #pragma unroll
    for (int t = 0; t < 6; ++t) {
      bfrag bh = *(const bfrag*)(bhib + t * 16 * 2080 + ko);
      bfrag bl = *(const bfrag*)(blob + t * 16 * 2080 + ko);
      acc[0][t] = __builtin_amdgcn_mfma_f32_16x16x32_bf16(hA, bh, acc[0][t], 0, 0, 0);
      acc[1][t] = __builtin_amdgcn_mfma_f32_16x16x32_bf16(hB, bh, acc[1][t], 0, 0, 0);
      acc[0][t] = __builtin_amdgcn_mfma_f32_16x16x32_bf16(lA, bh, acc[0][t], 0, 0, 0);
      acc[1][t] = __builtin_amdgcn_mfma_f32_16x16x32_bf16(lB, bh, acc[1][t], 0, 0, 0);
      acc[0][t] = __builtin_amdgcn_mfma_f32_16x16x32_bf16(hA, bl, acc[0][t], 0, 0, 0);
      acc[1][t] = __builtin_amdgcn_mfma_f32_16x16x32_bf16(hB, bl, acc[1][t], 0, 0, 0);
    }
  }

  __syncthreads();                   // rf_s dead; smem becomes mix[128][100]
  float* mix = smem;
  #pragma unroll
  for (int mt = 0; mt < 2; ++mt)
    #pragma unroll
    for (int r = 0; r < 4; ++r) {
      int el = wave * 32 + mt * 16 + quad * 4 + r;
      #pragma unroll
      for (int t = 0; t < 6; ++t) {
        int m = ((t >> 1) << 5) + ((t & 1) << 4) + col;
        mix[el * 100 + m] = acc[mt][t][r] * INV_SQM;
      }
    }
  __syncthreads();

  // ---- per-node gather: thread owns coef c (and c+256 for tid<32) ----
  int m_[2], shi_[2];
  float nrm_[2];
  int ncid = (tid < 32) ? 2 : 1;
  #pragma unroll
  for (int q = 0; q < 2; ++q) {
    int c = q ? 256 + tid : tid;
    int l, w, i;
    if (c < 32) { l = 0; w = c; i = 0; }
    else if (c < 128) { l = 1; w = (c - 32) / 3; i = (c - 32) % 3; }
    else { l = 2; w = (c - 128) / 5; i = (c - 128) % 5; }
    m_[q] = l * 32 + w;
    shi_[q] = (l == 0) ? 0 : ((l == 1) ? 1 + i : 4 + i);
    nrm_[q] = (l == 0) ? 1.0f : ((l == 1) ? 0.57735027f : 0.44721360f);
  }
  int s = 0;
  while (s < 128) {
    int n = snl[s];
    int e2 = s + 1;
    while (e2 < 128 && snl[e2] == n) ++e2;
    int o0 = off[n], o1 = off[n + 1];
    float inv = 1.0f / (float)(o1 - o0);
    bool headcut = (o0 < s0 + s);        // run continues from previous block
    bool tailcut = (o1 > s0 + e2);       // run continues into next block
    float v[2] = {0.f, 0.f};
    for (int el = s; el < e2; ++el) {
      v[0] += mix[el * 100 + m_[0]] * sh_s[el * 9 + shi_[0]];
      if (ncid == 2) v[1] += mix[el * 100 + m_[1]] * sh_s[el * 9 + shi_[1]];
    }
    #pragma unroll
    for (int q = 0; q < 2; ++q) {
      if (q >= ncid) break;
      float val = v[q] * nrm_[q] * inv;
      int c = q ? 256 + tid : tid;
      if (!headcut && !tailcut) aout[n * 288 + c] = val;                 // sole writer
      else bpart[(blockIdx.x * 2 + (headcut ? 0 : 1)) * 288 + c] = val;  // partial, sole writer
    }
    s = e2;
  }
}

// ---------- deterministic boundary fixup: one block per block-boundary ----
// Node crossing boundary i (slots 128(i+1)): full value = tail-partial of
// block i + head-partial of block i+1, summed in FIXED order. Sole writer.
__global__ __launch_bounds__(256) void k_fix(const int* __restrict__ s2n,
    const int* __restrict__ off, const float* __restrict__ bpart,
    float* __restrict__ aout)
{
  int i = blockIdx.x;                  // 0..498
  int slot = (i + 1) * 128;
  int n = s2n[slot];
  if (off[n] == slot) return;          // no node crosses this boundary
  for (int c = threadIdx.x; c < 288; c += 256)
    aout[n * 288 + c] = bpart[(i * 2 + 1) * 288 + c]
                      + bpart[((i + 1) * 2 + 0) * 288 + c];
}

// ---------- W[p][u][v][w] f32  ->  Wt[p][u][w][v] bf16 (one (p,u) slice/block) ----------
__global__ __launch_bounds__(256) void k_prepw(const float* __restrict__ W,
                                               unsigned short* __restrict__ Wt)
{
  __shared__ float buf[32 * 33];
  int tid = threadIdx.x;
  long base = (long)blockIdx.x * 1024;
  #pragma unroll
  for (int it = 0; it < 4; ++it) {
    int idx = it * 256 + tid;
    int w = idx & 31, v = idx >> 5;
    buf[w * 33 + v] = W[base + v * 32 + w];
  }
  __syncthreads();
  unsigned* out32 = (unsigned*)(Wt + base);
  #pragma unroll
  for (int it = 0; it < 2; ++it) {
    int idx = it * 256 + tid;
    int w = idx >> 4, vp = idx & 15;
    float f0 = buf[w * 33 + vp * 2], f1 = buf[w * 33 + vp * 2 + 1];
    unsigned pk = (unsigned)(unsigned short)f2bf(f0) |
                  ((unsigned)(unsigned short)f2bf(f1) << 16);
    out32[w * 16 + vp] = pk;
  }
}

// ---------- fuse lin chains: Wc[0][l]=lino1[l]@mixw[0][l]@combw[0][l]/SQM^3,
//            Wc[o][l]=mixw[o][l]@combw[o][l]/SQM^2 (o=1,2). 9 blocks. ----------
__global__ __launch_bounds__(256) void k_prepc(const float* __restrict__ lino1,
    const float* __restrict__ mixw, const float* __restrict__ combw,
    float* __restrict__ wc)
{
  __shared__ float A[1024], B[1024], T[1024];
  int o = blockIdx.x / 3, l = blockIdx.x - o * 3;
  int tid = threadIdx.x;
  const float* M = mixw + (o * 3 + l) * 1024;
  const float* C = combw + (o * 3 + l) * 1024;
  if (o == 0) {
    for (int i = tid; i < 1024; i += 256) { A[i] = lino1[l * 1024 + i]; B[i] = M[i]; }
    __syncthreads();
    #pragma unroll
    for (int it = 0; it < 4; ++it) {
      int idx = it * 256 + tid;
      int u = idx >> 5, w = idx & 31;
      float s = 0.f;
      for (int v = 0; v < 32; ++v) s += A[(u << 5) + v] * B[(v << 5) + w];
      T[idx] = s;
    }
  } else {
    for (int i = tid; i < 1024; i += 256) T[i] = M[i];
  }
  __syncthreads();           // T done; A free to reuse
  for (int i = tid; i < 1024; i += 256) A[i] = C[i];
  __syncthreads();
  float scale = (o == 0) ? INV_SQM * INV_SQM * INV_SQM : INV_SQM * INV_SQM;
  #pragma unroll
  for (int it = 0; it < 4; ++it) {
    int idx = it * 256 + tid;
    int u = idx >> 5, w = idx & 31;
    float s = 0.f;
    for (int v = 0; v < 32; ++v) s += T[(u << 5) + v] * A[(v << 5) + w];
    wc[(o * 3 + l) * 1024 + idx] = s * scale;
  }
}

// ---------- one TP path on MFMA ----------
template<int PI, int WIDX>
__device__ __forceinline__ void process_path(const float* __restrict__ x_s,
    const float* __restrict__ y_s, const unsigned short* __restrict__ wt,
    int lane, int wave, ffrag acc[9][2])
{
  constexpr int ip = cIP[PI], jp = cJP[PI], kp = cKP[PI];
  constexpr int di = cDL[ip], dj = cDL[jp], dk = cDL[kp];
  constexpr int xb = cOF[ip], yb = cOF[jp];
  constexpr int ks0 = (kp == 0) ? 0 : ((kp == 1) ? 1 : 4);
  constexpr int nA = cKo[PI][0];
  constexpr int nB = cKo[PI][dk];
  const int z = lane & 15, quad = lane >> 4;

  float yreg[8][dj];
  #pragma unroll
  for (int vi = 0; vi < 8; ++vi)
    #pragma unroll
    for (int j = 0; j < dj; ++j)
      yreg[vi][j] = y_s[z * 292 + yb + (quad * 8 + vi) * dj + j];

  for (int uu = 0; uu < 8; ++uu) {
    int u = wave * 8 + uu;
    const unsigned short* wb = wt + (((WIDX * 32 + u) * 32) << 5) + quad * 8;
    bfrag b0 = *(const bfrag*)(wb + (z << 5));          // w = lane&15
    bfrag b1 = *(const bfrag*)(wb + ((16 + z) << 5));   // w = 16 + lane&15
    float xv[di];
    #pragma unroll
    for (int i = 0; i < di; ++i) xv[i] = x_s[z * 292 + xb + u * di + i];
    float xc[nB - nA];
    #pragma unroll
    for (int n = nA; n < nB; ++n) xc[n - nA] = xv[cNI[n]] * cNV[n];
    bfrag fa[dk];
    #pragma unroll
    for (int vi = 0; vi < 8; ++vi) {
      float T[dk];
      #pragma unroll
      for (int k = 0; k < dk; ++k) T[k] = 0.f;
      #pragma unroll
      for (int k = 0; k < dk; ++k)
        #pragma unroll
        for (int n = cKo[PI][k]; n < cKo[PI][k + 1]; ++n)
          T[k] += xc[n - nA] * yreg[vi][cNJ[n]];
      #pragma unroll
      for (int k = 0; k < dk; ++k) fa[k][vi] = f2bf(T[k]);
    }
    #pragma unroll
    for (int k = 0; k < dk; ++k) {
      acc[ks0 + k][0] = __builtin_amdgcn_mfma_f32_16x16x32_bf16(fa[k], b0, acc[ks0 + k][0], 0, 0, 0);
      acc[ks0 + k][1] = __builtin_amdgcn_mfma_f32_16x16x32_bf16(fa[k], b1, acc[ks0 + k][1], 0, 0, 0);
    }
  }
}

// MODE 0: all 11 paths (o3a/o3b). MODE 1: o2_uvw paths {1,2,6}.
template<int MODE>
__global__ __launch_bounds__(256, 2) void k_pairwise_mfma(
    const float* __restrict__ x, const float* __restrict__ y,
    const unsigned short* __restrict__ wt, float* __restrict__ out, float scale)
{
  __shared__ float smem[9504];        // x_s[16*292] | y_s[16*292]; 2 red slices of 4752
  float* x_s = smem;
  float* y_s = smem + 4672;
  int tid = threadIdx.x;
  int z0 = blockIdx.x * 16;
  for (int idx = tid; idx < 16 * 72; idx += 256) {
    int r = idx / 72, f = (idx - r * 72) * 4;
    *(float4*)&x_s[r * 292 + f] = *(const float4*)&x[(z0 + r) * 288 + f];
    *(float4*)&y_s[r * 292 + f] = *(const float4*)&y[(z0 + r) * 288 + f];
  }
  __syncthreads();
  int lane = tid & 63, wave = tid >> 6;
  ffrag acc[9][2] = {};

  if constexpr (MODE == 0) {
    process_path<0, 0>(x_s, y_s, wt, lane, wave, acc);
    process_path<1, 1>(x_s, y_s, wt, lane, wave, acc);
    process_path<2, 2>(x_s, y_s, wt, lane, wave, acc);
    process_path<3, 3>(x_s, y_s, wt, lane, wave, acc);
    process_path<4, 4>(x_s, y_s, wt, lane, wave, acc);
    process_path<5, 5>(x_s, y_s, wt, lane, wave, acc);
    process_path<6, 6>(x_s, y_s, wt, lane, wave, acc);
    process_path<7, 7>(x_s, y_s, wt, lane, wave, acc);
    process_path<8, 8>(x_s, y_s, wt, lane, wave, acc);
    process_path<9, 9>(x_s, y_s, wt, lane, wave, acc);
    process_path<10, 10>(x_s, y_s, wt, lane, wave, acc);
  } else {
    process_path<1, 0>(x_s, y_s, wt, lane, wave, acc);
    process_path<2, 1>(x_s, y_s, wt, lane, wave, acc);
    process_path<6, 2>(x_s, y_s, wt, lane, wave, acc);
  }

  // ---- deterministic cross-wave reduction: (w0 + w2) + (w1 + w3) ----
  float* slice0 = smem;          // 4752 floats, row stride 33
  float* slice1 = smem + 4752;   // 4752 floats
  int n15 = lane & 15, quad = lane >> 4;
  __syncthreads();
  if (wave >= 2) {
    float* sl = (wave == 2) ? slice0 : slice1;
    #pragma unroll
    for (int s = 0; s < 9; ++s)
      #pragma unroll
      for (int wh = 0; wh < 2; ++wh)
        #pragma unroll
        for (int r = 0; r < 4; ++r)
          sl[(s * 16 + quad * 4 + r) * 33 + wh * 16 + n15] = acc[s][wh][r];
  }
  __syncthreads();
  if (wave < 2) {
    float* sl = (wave == 0) ? slice0 : slice1;
    #pragma unroll
    for (int s = 0; s < 9; ++s)
      #pragma unroll
      for (int wh = 0; wh < 2; ++wh)
        #pragma unroll
        for (int r = 0; r < 4; ++r)
          acc[s][wh][r] += sl[(s * 16 + quad * 4 + r) * 33 + wh * 16 + n15];
  }
  __syncthreads();
  if (wave == 1) {
    #pragma unroll
    for (int s = 0; s < 9; ++s)
      #pragma unroll
      for (int wh = 0; wh < 2; ++wh)
        #pragma unroll
        for (int r = 0; r < 4; ++r)
          slice1[(s * 16 + quad * 4 + r) * 33 + wh * 16 + n15] = acc[s][wh][r];
  }
  __syncthreads();
  if (wave == 0) {
    #pragma unroll
    for (int s = 0; s < 9; ++s)
      #pragma unroll
      for (int wh = 0; wh < 2; ++wh)
        #pragma unroll
        for (int r = 0; r < 4; ++r) {
          int o = (s * 16 + quad * 4 + r) * 33 + wh * 16 + n15;
          slice0[o] = acc[s][wh][r] + slice1[o];
        }
  }
  __syncthreads();
  for (int idx = tid; idx < 4608; idx += 256) {
    int w = idx & 31, rest = idx >> 5;
    int zz = rest & 15, ks = rest >> 4;
    int c = (ks == 0) ? w : (ks < 4 ? 32 + w * 3 + (ks - 1) : 128 + w * 5 + (ks - 4));
    out[(z0 + zz) * 288 + c] = scale * slice0[(ks * 16 + zz) * 33 + w];
  }
}

// ---------- uvu part of order2: compile-time templated paths ----------
template<int PI>
__device__ __forceinline__ void uvu_path(const float* __restrict__ x_t,
    const float* __restrict__ Wg, int u, int zq, float acc0[2], float acc2[2][5])
{
  constexpr int ip = cIP[PI], jp = cJP[PI], kp = cKP[PI];
  constexpr int di = cDL[ip], dj = cDL[jp], dk = cDL[kp];
  constexpr int xb = cOF[ip], yb = cOF[jp];
  constexpr int nA = cKo[PI][0];
  constexpr int nB = cKo[PI][dk];
  float wrow[32];
  #pragma unroll
  for (int vq = 0; vq < 8; ++vq)
    *(float4*)&wrow[vq * 4] = *(const float4*)&Wg[u * 32 + vq * 4];
  #pragma unroll
  for (int zz = 0; zz < 2; ++zz) {
    int z = zq + (zz << 3);
    float xv[di];
    #pragma unroll
    for (int i = 0; i < di; ++i) xv[i] = x_t[z * 288 + xb + u * di + i];
    float xc[nB - nA];
    #pragma unroll
    for (int n = nA; n < nB; ++n) xc[n - nA] = xv[cNI[n]] * cNV[n];
    const float* yrb = &x_t[z * 288 + yb];
    #pragma unroll 8
    for (int v = 0; v < 32; ++v) {
      float yv[dj];
      #pragma unroll
      for (int j = 0; j < dj; ++j) yv[j] = yrb[v * dj + j];
      float wv = wrow[v];
      if constexpr (kp == 0) {
        float t = 0.f;
        #pragma unroll
        for (int n = nA; n < nB; ++n) t += xc[n - nA] * yv[cNJ[n]];
        acc0[zz] += wv * t;
      } else {
        #pragma unroll
        for (int k = 0; k < 5; ++k) {
          float t = 0.f;
          #pragma unroll
          for (int n = cKo[PI][k]; n < cKo[PI][k + 1]; ++n)
            t += xc[n - nA] * yv[cNJ[n]];
          acc2[zz][k] += wv * t;
        }
      }
    }
  }
}

__global__ __launch_bounds__(256) void k_uvu(
    const float* __restrict__ x, const float* __restrict__ W, float* __restrict__ out)
{
  __shared__ __align__(16) float x_t[16 * 288];
  int tid = threadIdx.x;
  int z0 = blockIdx.x * 16;
  for (int idx = tid; idx < 16 * 72; idx += 256) {
    int r = idx / 72, f = idx - r * 72;
    *(float4*)&x_t[r * 288 + f * 4] = *(const float4*)&x[(z0 + r) * 288 + f * 4];
  }
  __syncthreads();
  int u = tid & 31, zq = tid >> 5;
  float acc0[2] = {0.f, 0.f};
  float acc2[2][5] = {};
  uvu_path<0>(x_t, W,            u, zq, acc0, acc2);   // PL_UVU order {0,4,5,9,10}
  uvu_path<4>(x_t, W + 1 * 1024, u, zq, acc0, acc2);
  uvu_path<5>(x_t, W + 2 * 1024, u, zq, acc0, acc2);
  uvu_path<9>(x_t, W + 3 * 1024, u, zq, acc0, acc2);
  uvu_path<10>(x_t, W + 4 * 1024, u, zq, acc0, acc2);
  #pragma unroll
  for (int zz = 0; zz < 2; ++zz) {
    int zg = z0 + zq + (zz << 3);
    float* orow = out + zg * 288;
    orow[u] += INV_SQM * acc0[zz];
    #pragma unroll
    for (int kk = 0; kk < 5; ++kk) orow[128 + u * 5 + kk] += INV_SQM * acc2[zz][kk];
  }
}

// ---------- fused finalize: msg = a@Wc0 + b2@Wc1 + b3@Wc2 (+ selfc) ----------
__global__ __launch_bounds__(256) void k_finalize(
    const float* __restrict__ a, const float* __restrict__ b2,
    const float* __restrict__ b3, const float* __restrict__ selfc,
    const float* __restrict__ wc, float* __restrict__ out)
{
  __shared__ float W[9216];          // Wc[3][3][32*32], [u*32+w]
  __shared__ float S[6912];          // [o][zl][288]
  int tid = threadIdx.x;
  int z0 = blockIdx.x * 8;
  for (int i = tid; i < 9216; i += 256) W[i] = wc[i];
  const float* srcs[3] = {a, b2, b3};
  for (int o = 0; o < 3; ++o)
    for (int idx = tid; idx < 8 * 72; idx += 256) {
      int r = idx / 72, f = (idx - r * 72) * 4;
      *(float4*)&S[o * 2304 + r * 288 + f] = *(const float4*)&srcs[o][(z0 + r) * 288 + f];
    }
  __syncthreads();
  int w = tid & 31, zl = tid >> 5;
  float msg[9];
  #pragma unroll
  for (int s = 0; s < 9; ++s) msg[s] = 0.f;
  #pragma unroll
  for (int o = 0; o < 3; ++o) {
    const float* src = &S[o * 2304 + zl * 288];
    const float* W0 = &W[(o * 3 + 0) * 1024];
    const float* W1 = &W[(o * 3 + 1) * 1024];
    const float* W2 = &W[(o * 3 + 2) * 1024];
    #pragma unroll
    for (int u = 0; u < 32; ++u) {
      float w0 = W0[(u << 5) + w];
      msg[0] += src[u] * w0;
      float w1 = W1[(u << 5) + w];
      #pragma unroll
      for (int i = 0; i < 3; ++i) msg[1 + i] += src[32 + u * 3 + i] * w1;
      float w2 = W2[(u << 5) + w];
      #pragma unroll
      for (int i = 0; i < 5; ++i) msg[4 + i] += src[128 + u * 5 + i] * w2;
    }
  }
  int z = z0 + zl;
  float sc = selfc[(z << 5) + w];
  float* orow = out + z * 288;
  orow[w] = msg[0] + sc;
  #pragma unroll
  for (int i = 0; i < 3; ++i) orow[32 + w * 3 + i] = msg[1 + i];
  #pragma unroll
  for (int i = 0; i < 5; ++i) orow[128 + w * 5 + i] = msg[4 + i];
}

extern "C" void kernel_launch(void* const* d_in, const int* in_sizes, int n_in,
                              void* d_out, int out_size, void* d_ws, size_t ws_size,
                              hipStream_t stream)
{
  (void)in_sizes; (void)n_in; (void)out_size; (void)ws_size;
  const float* nf   = (const float*)d_in[0];
  const int*   ei   = (const int*)d_in[1];
  const float* sh   = (const float*)d_in[2];
  const float* re   = (const float*)d_in[3];
  const float* ea   = (const float*)d_in[4];
  const float* rw1  = (const float*)d_in[5];
  const float* rb1  = (const float*)d_in[6];
  const float* rw2  = (const float*)d_in[7];
  const float* rb2  = (const float*)d_in[8];
  const float* rw3  = (const float*)d_in[9];
  const float* rb3  = (const float*)d_in[10];
  const float* aw   = (const float*)d_in[11];
  const float* ab   = (const float*)d_in[12];
  const float* embw = (const float*)d_in[13];
  const float* lino1= (const float*)d_in[14];
  const float* o2uvw= (const float*)d_in[15];
  const float* o2uvu= (const float*)d_in[16];
  const float* o3a  = (const float*)d_in[17];
  const float* o3b  = (const float*)d_in[18];
  const float* mixw = (const float*)d_in[19];
  const float* combw= (const float*)d_in[20];
  const float* selfw= (const float*)d_in[21];
  float* out = (float*)d_out;
  float* ws  = (float*)d_ws;

  // workspace layout (floats). High-water = 10,915,600 floats (43.66 MB) ==
  // R3-proven footprint. CSR scratch aliases dead regions; wc aliases tot
  // (dead after k_scan); bpart aliases basec (dead after k_assign).
  float* h     = ws;                // 320000
  float* selfc = ws + 320000;       // 320000
  float* rfb   = ws + 640000;       // 4096000  (rf; reused as b2 afterwards)
  float* a     = ws + 4736000;      // 2880000
  int*   tot   = (int*)(ws + 7616000); // 10000 ints
  float* wc    = ws + 7616000;      // 9216 floats, aliases tot
  float* cint  = ws + 7626000;      // 2880000  (b3 computed in-place)
  float* b2 = rfb;
  float* b3 = cint;
  unsigned short* wt_o2  = (unsigned short*)(ws + 10506000); //  98304 ush
  unsigned short* wt_o3a = wt_o2 + 98304;                    // 360448 ush
  unsigned short* wt_o3b = wt_o3a + 360448;                  // 360448 ush -> ends at float 10915600
  unsigned short* bthi   = (unsigned short*)cint;            // 199680 ush
  unsigned short* btlo   = bthi + 199680;                    // 199680 ush (ends cint+199680 fl)
  int* h_chunk = (int*)a;                                    // 2,500,000 ints
  int* basec   = (int*)(cint + 200000);                      // 2,500,000 ints (dead after k_assign)
  float* bpart = cint + 200000;                              // 288000 fl, aliases basec
  int* eord    = (int*)(cint + 2700000);                     // 64000 ints
  int* s2n     = (int*)(cint + 2764000);                     // 64000 ints
  int* off     = (int*)(cint + 2828000);                     // 10001 ints

  k_prepb<<<96, 256, 0, stream>>>(aw, ab, bthi, btlo);
  k_prepw<<<96, 256, 0, stream>>>(o2uvw, wt_o2);
  k_prepw<<<352, 256, 0, stream>>>(o3a, wt_o3a);
  k_prepw<<<352, 256, 0, stream>>>(o3b, wt_o3b);
  k_embed<<<1250, 256, 0, stream>>>(nf, embw, selfw, h, selfc);
  k_radial<<<2000, 256, 0, stream>>>(re, ea, rw1, rb1, rw2, rb2, rw3, rb3, rfb);
  // deterministic CSR build
  k_hist<<<250, 256, 0, stream>>>(ei, h_chunk);
  k_tot<<<40, 256, 0, stream>>>(h_chunk, tot);
  k_scan<<<1, 256, 0, stream>>>(tot, off);
  k_base<<<40, 256, 0, stream>>>(off, h_chunk, basec);
  k_assign<<<250, 256, 0, stream>>>(ei, basec, eord, s2n);
  k_prepc<<<9, 256, 0, stream>>>(lino1, mixw, combw, wc);    // after k_scan: tot dead
  hipMemsetAsync(a, 0, 2880000 * sizeof(float), stream);     // after k_assign (h_chunk dead)
  k_edge_mfma<<<500, 256, 0, stream>>>(rfb, h, ei, sh, bthi, btlo, eord, s2n, off, a, bpart);
  k_fix<<<499, 256, 0, stream>>>(s2n, off, bpart, a);
  k_pairwise_mfma<1><<<625, 256, 0, stream>>>(a, a, wt_o2, b2, INV_MUL);
  k_uvu<<<625, 256, 0, stream>>>(a, o2uvu, b2);
  k_pairwise_mfma<0><<<625, 256, 0, stream>>>(a, a, wt_o3a, cint, INV_MUL);
  k_pairwise_mfma<0><<<625, 256, 0, stream>>>(cint, a, wt_o3b, b3, INV_MUL);
  k_finalize<<<1250, 256, 0, stream>>>(a, b2, b3, selfc, wc, out);
}